// Round 5
// baseline (1684.769 us; speedup 1.0000x reference)
//
#include <hip/hip_runtime.h>
#include <hip/hip_bf16.h>

#define BB 8
#define CC_ 256
#define HH 56
#define WW 56
#define HWSZ (HH*WW)
#define RR_ 2
#define HID 64

typedef __hip_bfloat16 bf16;
__device__ __forceinline__ float b2f(bf16 v){ return __bfloat162float(v); }
__device__ __forceinline__ bf16 f2b(float v){ return __float2bfloat16(v); }

// K1: decoupler 1x1 conv + softmax(R=2); writes scale factors sc[i][b][yx] = 1 + M_i.
__global__ void k_scales(const float* __restrict__ F, const float* __restrict__ dec_w,
                         const float* __restrict__ dec_b, float* __restrict__ sc){
    __shared__ float w0[CC_], w1[CC_];
    int tid = threadIdx.x; // 64
    for (int c = tid; c < CC_; c += 64){ w0[c] = dec_w[c]; w1[c] = dec_w[CC_+c]; }
    __syncthreads();
    int pid = blockIdx.x*64 + tid;           // grid is exactly BB*HWSZ/64
    int b = pid / HWSZ, yx = pid % HWSZ;
    const float* base = F + (size_t)b*CC_*HWSZ + yx;
    float a0 = dec_b[0], a1 = dec_b[1];
    for (int c = 0; c < CC_; ++c){ float v = base[(size_t)c*HWSZ]; a0 += v*w0[c]; a1 += v*w1[c]; }
    float m = fmaxf(a0,a1);
    float e0 = __expf(a0-m), e1 = __expf(a1-m);
    float inv = 1.0f/(e0+e1);
    sc[pid]                  = 1.0f + e0*inv;
    sc[(size_t)BB*HWSZ+pid]  = 1.0f + e1*inv;
}

// K2: conv3x3 C=256 -> 64, pad 1, + bias + relu, on F_i = F * sc_i (fold at tile load).
__global__ __launch_bounds__(256) void k_conv1(const float* __restrict__ Fc, const float* __restrict__ sc_i,
                                               const float* __restrict__ wgt, const float* __restrict__ bias,
                                               bf16* __restrict__ hout){
    __shared__ float tile[16][3][60];
    int bx = blockIdx.x; int b = bx / HH, y = bx % HH;
    int tid = threadIdx.x; int oc = tid >> 2, xq = tid & 3; int x0 = xq*14;
    float acc[14];
    #pragma unroll
    for (int j=0;j<14;++j) acc[j]=0.f;
    const float* Fb = Fc + (size_t)b*CC_*HWSZ;
    const float* si = sc_i + (size_t)b*HWSZ;
    for (int cc = 0; cc < CC_; cc += 16){
        for (int idx = tid; idx < 16*3*58; idx += 256){
            int ch = idx / 174; int rem = idx % 174; int rr = rem / 58; int xx = rem % 58 - 1;
            int gy = y + rr - 1;
            float v = 0.f;
            if ((unsigned)gy < HH && (unsigned)xx < WW)
                v = Fb[(size_t)(cc+ch)*HWSZ + gy*WW + xx] * si[gy*WW + xx];
            tile[ch][rr][xx+1] = v;
        }
        __syncthreads();
        const float* wp = wgt + ((size_t)oc*CC_ + cc)*9;
        for (int ic = 0; ic < 16; ++ic){
            float w[9];
            #pragma unroll
            for (int k=0;k<9;++k) w[k] = wp[ic*9+k];
            #pragma unroll
            for (int ky=0;ky<3;++ky){
                const float* rowp = &tile[ic][ky][x0];
                #pragma unroll
                for (int kx=0;kx<3;++kx){
                    float wv = w[ky*3+kx];
                    #pragma unroll
                    for (int j=0;j<14;++j) acc[j] += wv * rowp[j+kx];
                }
            }
        }
        __syncthreads();
    }
    float bv = bias[oc];
    bf16* op = hout + ((size_t)b*HID + oc)*HWSZ + y*WW + x0;
    #pragma unroll
    for (int j=0;j<14;++j) op[j] = f2b(fmaxf(acc[j]+bv, 0.f));
}

// K3: conv3x3 64 -> 18, pad 1, + bias. Thread per output.
__global__ void k_conv2(const bf16* __restrict__ h, const float* __restrict__ wgt,
                        const float* __restrict__ bias, float* __restrict__ p){
    int n = blockIdx.x*256 + threadIdx.x;
    if (n >= BB*18*HWSZ) return;
    int b = n / (18*HWSZ); int rr = n % (18*HWSZ); int oc = rr / HWSZ;
    int yx = rr % HWSZ; int y = yx / WW, x = yx % WW;
    float acc = bias[oc];
    const bf16* hb = h + (size_t)b*HID*HWSZ;
    const float* wp = wgt + (size_t)oc*HID*9;
    for (int ic = 0; ic < HID; ++ic){
        const bf16* hc = hb + (size_t)ic*HWSZ;
        #pragma unroll
        for (int ky=0;ky<3;++ky){
            int gy = y+ky-1; if ((unsigned)gy >= HH) continue;
            #pragma unroll
            for (int kx=0;kx<3;++kx){
                int gx = x+kx-1; if ((unsigned)gx >= WW) continue;
                acc += b2f(hc[gy*WW+gx]) * wp[ic*9+ky*3+kx];
            }
        }
    }
    p[n] = acc;
}

// K4a: 8x8 avg pool (56->7) on F_i = F*sc_i, depthwise 3x3 + relu, global mean -> s[b,c].
__global__ void k_akg_pool(const float* __restrict__ Fc, const float* __restrict__ sc_i,
                           const float* __restrict__ dw, float* __restrict__ s){
    int bc = blockIdx.x; int b = bc / CC_; int c = bc % CC_;
    int l = threadIdx.x; // 64
    __shared__ float sm[49];
    __shared__ float red[64];
    const float* fb = Fc + (size_t)bc*HWSZ;
    const float* si = sc_i + (size_t)b*HWSZ;
    if (l < 49){
        int u = l/7, v = l%7;
        float sum = 0.f;
        for (int r=0;r<8;++r){
            const float* rp = fb + (u*8+r)*WW + v*8;
            const float* sp = si + (u*8+r)*WW + v*8;
            #pragma unroll
            for (int q=0;q<8;++q) sum += rp[q] * sp[q];
        }
        sm[l] = sum * (1.f/64.f);
    }
    __syncthreads();
    float rv = 0.f;
    if (l < 49){
        float w[9];
        #pragma unroll
        for (int k=0;k<9;++k) w[k] = dw[c*9+k];
        int u=l/7, v=l%7; float acc=0.f;
        #pragma unroll
        for (int ky=0;ky<3;++ky){ int uu=u+ky-1; if((unsigned)uu>=7u) continue;
            #pragma unroll
            for (int kx=0;kx<3;++kx){ int vv=v+kx-1; if((unsigned)vv>=7u) continue;
                acc += sm[uu*7+vv]*w[ky*3+kx]; } }
        rv = fmaxf(acc, 0.f);
    }
    red[l] = rv;
    __syncthreads();
    if (l==0){ float t=0.f; for(int i2=0;i2<64;++i2) t+=red[i2]; s[bc] = t*(1.f/49.f); }
}

// K4b: head 1x1 (C*9 x C) matvec + bias + tanh -> Kw (B, C*9), o = c*9+t.
__global__ void k_akg_head(const float* __restrict__ s, const float* __restrict__ hw,
                           const float* __restrict__ hb, float* __restrict__ Kw){
    int b = blockIdx.x / 9; int og = blockIdx.x % 9;
    __shared__ float sv[CC_];
    int tid = threadIdx.x; // 256
    sv[tid] = s[b*CC_ + tid];
    __syncthreads();
    int o = og*256 + tid;
    const float* wp = hw + (size_t)o*CC_;
    float acc = hb[o];
    for (int c2=0;c2<CC_;++c2) acc += wp[c2]*sv[c2];
    Kw[(size_t)b*2304 + o] = tanhf(acc);
}

// K5: deformable depthwise, per-sample dynamic 3x3 kernels on F_i = F*sc_i.
// sc_i at each (clipped) corner folds exactly into the stored bilinear weight.
__global__ __launch_bounds__(224) void k_deform(const float* __restrict__ Fc, const float* __restrict__ sc_i,
                                                const float* __restrict__ p, const float* __restrict__ Kw,
                                                bf16* __restrict__ outs, int creg){
    __shared__ int   siy[504*4];
    __shared__ float sw[504*4];
    int bx = blockIdx.x; int b = bx / HH, y = bx % HH;
    int tid = threadIdx.x;
    const float* si = sc_i + (size_t)b*HWSZ;
    for (int e = tid; e < 504; e += 224){
        int t = e / 56, x = e % 56;
        int ky = t / 3, kx = t % 3;
        float dy = p[((size_t)b*18 + 2*t  )*HWSZ + y*WW + x];
        float dx = p[((size_t)b*18 + 2*t+1)*HWSZ + y*WW + x];
        float py = (float)(y - 1 + ky) + dy;
        float px = (float)(x - 1 + kx) + dx;
        float y0f = floorf(py), x0f = floorf(px);
        float wy1 = py - y0f, wx1 = px - x0f;
        float wy0 = 1.f - wy1, wx0 = 1.f - wx1;
        // per-corner validity (torchvision semantics): mask weight, clip index
        float vy0 = (y0f >= 0.f  && y0f <= 55.f) ? 1.f : 0.f;
        float vy1 = (y0f >= -1.f && y0f <= 54.f) ? 1.f : 0.f;
        float vx0 = (x0f >= 0.f  && x0f <= 55.f) ? 1.f : 0.f;
        float vx1 = (x0f >= -1.f && x0f <= 54.f) ? 1.f : 0.f;
        int y0 = (int)y0f, x0 = (int)x0f;
        int iy0 = min(max(y0,0),55),   iy1 = min(max(y0+1,0),55);
        int ix0 = min(max(x0,0),55),   ix1 = min(max(x0+1,0),55);
        int o00 = iy0*WW+ix0, o01 = iy0*WW+ix1, o10 = iy1*WW+ix0, o11 = iy1*WW+ix1;
        siy[e*4+0]=o00; siy[e*4+1]=o01; siy[e*4+2]=o10; siy[e*4+3]=o11;
        sw[e*4+0] = wy0*wx0*vy0*vx0 * si[o00];
        sw[e*4+1] = wy0*wx1*vy0*vx1 * si[o01];
        sw[e*4+2] = wy1*wx0*vy1*vx0 * si[o10];
        sw[e*4+3] = wy1*wx1*vy1*vx1 * si[o11];
    }
    __syncthreads();
    int xl = tid % 56, cs = tid / 56; // cs 0..3
    const float* Kb = Kw + (size_t)b*2304;
    for (int chunk = 0; chunk < 8; ++chunk){
        float acc[8];
        #pragma unroll
        for (int j=0;j<8;++j) acc[j]=0.f;
        #pragma unroll 1
        for (int t=0;t<9;++t){
            int e = t*56+xl;
            int o00=siy[e*4+0], o01=siy[e*4+1], o10=siy[e*4+2], o11=siy[e*4+3];
            float w00=sw[e*4+0], w01=sw[e*4+1], w10=sw[e*4+2], w11=sw[e*4+3];
            #pragma unroll
            for (int j=0;j<8;++j){
                int c = (chunk*8+j)*4 + cs;
                const float* fb = Fc + ((size_t)b*CC_ + c)*HWSZ;
                float v = w00*fb[o00] + w01*fb[o01] + w10*fb[o10] + w11*fb[o11];
                acc[j] += Kb[c*9+t]*v;
            }
        }
        #pragma unroll
        for (int j=0;j<8;++j){
            int c = (chunk*8+j)*4 + cs;
            outs[((size_t)b*2*CC_ + creg*CC_ + c)*HWSZ + y*WW + xl] = f2b(acc[j]);
        }
    }
}

// K6a: pw2 1x1 conv (512 -> 256) + bias, stats only (per-channel sum/sumsq atomics).
__global__ __launch_bounds__(256) void k_pw2_stats(const bf16* __restrict__ outs, const float* __restrict__ w,
                                                   const float* __restrict__ bias, float* __restrict__ stats){
    __shared__ float in[16][56];
    int bx = blockIdx.x;
    int octile = bx % 4; int by = bx / 4; int b = by / HH, y = by % HH;
    int tid = threadIdx.x; int ocl = tid >> 2; int xq = tid & 3;
    int oc = octile*64 + ocl; int x0 = xq*14;
    float acc[14];
    #pragma unroll
    for (int j=0;j<14;++j) acc[j]=0.f;
    for (int cc = 0; cc < 512; cc += 16){
        for (int idx = tid; idx < 16*56; idx += 256){
            int ic = idx / 56, x = idx % 56;
            in[ic][x] = b2f(outs[((size_t)b*512 + cc+ic)*HWSZ + y*WW + x]);
        }
        __syncthreads();
        const float* wp = w + (size_t)oc*512 + cc;
        for (int ic=0;ic<16;++ic){
            float wv = wp[ic];
            #pragma unroll
            for (int j=0;j<14;++j) acc[j] += wv*in[ic][x0+j];
        }
        __syncthreads();
    }
    float bv = bias[oc];
    float s1=0.f, s2=0.f;
    #pragma unroll
    for (int j=0;j<14;++j){ float v = acc[j]+bv; s1+=v; s2+=v*v; }
    s1 += __shfl_down(s1, 2, 4); s1 += __shfl_down(s1, 1, 4);
    s2 += __shfl_down(s2, 2, 4); s2 += __shfl_down(s2, 1, 4);
    if (xq==0){ atomicAdd(&stats[oc], s1); atomicAdd(&stats[CC_+oc], s2); }
}

// K6b: finalize BN stats.
__global__ void k_bnstat(const float* __restrict__ stats, float* __restrict__ bnp){
    int c = threadIdx.x;
    float n = (float)(BB*HWSZ);
    float mean = stats[c]/n;
    float var = stats[CC_+c]/n - mean*mean;
    var = fmaxf(var, 0.f);
    bnp[c] = mean; bnp[CC_+c] = rsqrtf(var + 1e-5f);
}

// K6c: pw2 recompute + BN apply, write fp32 out.
__global__ __launch_bounds__(256) void k_pw2_apply(const bf16* __restrict__ outs, const float* __restrict__ w,
                                                   const float* __restrict__ bias, const float* __restrict__ bnp,
                                                   const float* __restrict__ gamma, const float* __restrict__ beta,
                                                   float* __restrict__ out){
    __shared__ float in[16][56];
    int bx = blockIdx.x;
    int octile = bx % 4; int by = bx / 4; int b = by / HH, y = by % HH;
    int tid = threadIdx.x; int ocl = tid >> 2; int xq = tid & 3;
    int oc = octile*64 + ocl; int x0 = xq*14;
    float acc[14];
    #pragma unroll
    for (int j=0;j<14;++j) acc[j]=0.f;
    for (int cc = 0; cc < 512; cc += 16){
        for (int idx = tid; idx < 16*56; idx += 256){
            int ic = idx / 56, x = idx % 56;
            in[ic][x] = b2f(outs[((size_t)b*512 + cc+ic)*HWSZ + y*WW + x]);
        }
        __syncthreads();
        const float* wp = w + (size_t)oc*512 + cc;
        for (int ic=0;ic<16;++ic){
            float wv = wp[ic];
            #pragma unroll
            for (int j=0;j<14;++j) acc[j] += wv*in[ic][x0+j];
        }
        __syncthreads();
    }
    float bv = bias[oc];
    float mean = bnp[oc], rsq = bnp[CC_+oc];
    float g = gamma[oc], be = beta[oc];
    float* op = out + ((size_t)b*CC_ + oc)*HWSZ + y*WW + x0;
    #pragma unroll
    for (int j=0;j<14;++j){ float v = acc[j]+bv; op[j] = (v-mean)*rsq*g + be; }
}

extern "C" void kernel_launch(void* const* d_in, const int* in_sizes, int n_in,
                              void* d_out, int out_size, void* d_ws, size_t ws_size,
                              hipStream_t stream) {
    (void)in_sizes; (void)n_in; (void)out_size; (void)ws_size;
    // Inputs are fp32 (established round 4: bf16 reads -> NaN, fp32 path -> finite).
    const float* F_c    = (const float*)d_in[0];
    const float* dec_w  = (const float*)d_in[1];
    const float* dec_b  = (const float*)d_in[2];
    const float* off1_w = (const float*)d_in[3];
    const float* off1_b = (const float*)d_in[4];
    const float* off2_w = (const float*)d_in[5];
    const float* off2_b = (const float*)d_in[6];
    const float* akg_dw = (const float*)d_in[7];
    const float* akg_hw = (const float*)d_in[8];
    const float* akg_hb = (const float*)d_in[9];
    const float* pw2_w  = (const float*)d_in[10];
    const float* pw2_b  = (const float*)d_in[11];
    const float* gamma  = (const float*)d_in[12];
    const float* beta   = (const float*)d_in[13];
    float* out = (float*)d_out;   // reference output dtype is float32

    char* ws = (char*)d_ws;
    size_t off = 0;
    auto alloc = [&](size_t bytes)->char*{
        char* r = ws + off;
        off = (off + bytes + 255) & ~(size_t)255;
        return r;
    };
    const size_t NPC = (size_t)BB*CC_*HWSZ;
    // Workspace ~31 MB.
    float* sc    = (float*)alloc((size_t)2*BB*HWSZ*4);
    bf16*  h     = (bf16*) alloc((size_t)BB*HID*HWSZ*2);
    float* p     = (float*)alloc((size_t)BB*18*HWSZ*4);
    float* s     = (float*)alloc((size_t)BB*CC_*4);
    float* Kw    = (float*)alloc((size_t)BB*CC_*9*4);
    bf16*  outsb = (bf16*) alloc(NPC*2*2);
    float* stats = (float*)alloc(2*CC_*4);
    float* bnp   = (float*)alloc(2*CC_*4);

    hipMemsetAsync(stats, 0, 2*CC_*sizeof(float), stream);

    k_scales<<<dim3((BB*HWSZ)/64), dim3(64), 0, stream>>>(F_c, dec_w, dec_b, sc);

    for (int i = 0; i < RR_; ++i){
        const float* sc_i = sc + (size_t)i*BB*HWSZ;
        k_conv1<<<dim3(BB*HH), dim3(256), 0, stream>>>(
            F_c, sc_i, off1_w + (size_t)i*HID*CC_*9, off1_b + i*HID, h);
        k_conv2<<<dim3((BB*18*HWSZ)/256), dim3(256), 0, stream>>>(
            h, off2_w + (size_t)i*18*HID*9, off2_b + i*18, p);
        k_akg_pool<<<dim3(BB*CC_), dim3(64), 0, stream>>>(
            F_c, sc_i, akg_dw + (size_t)i*CC_*9, s);
        k_akg_head<<<dim3(BB*9), dim3(256), 0, stream>>>(
            s, akg_hw + (size_t)i*2304*CC_, akg_hb + (size_t)i*2304, Kw);
        k_deform<<<dim3(BB*HH), dim3(224), 0, stream>>>(F_c, sc_i, p, Kw, outsb, i);
    }

    k_pw2_stats<<<dim3(BB*HH*4), dim3(256), 0, stream>>>(outsb, pw2_w, pw2_b, stats);
    k_bnstat<<<dim3(1), dim3(256), 0, stream>>>(stats, bnp);
    k_pw2_apply<<<dim3(BB*HH*4), dim3(256), 0, stream>>>(outsb, pw2_w, pw2_b, bnp, gamma, beta, out);
}

// Round 6
// 1201.820 us; speedup vs baseline: 1.4018x; 1.4018x over previous
//
#include <hip/hip_runtime.h>
#include <hip/hip_bf16.h>

#define BB 8
#define CC_ 256
#define HH 56
#define WW 56
#define HWSZ (HH*WW)
#define RR_ 2
#define HID 64
#define FPR ((size_t)8*58*58*256)   // padded NHWC region elements

typedef __hip_bfloat16 bf16;
typedef __attribute__((ext_vector_type(8))) short short8;
typedef __attribute__((ext_vector_type(4))) float f32x4;

__device__ __forceinline__ float b2f(bf16 v){ return __bfloat162float(v); }
__device__ __forceinline__ bf16 f2b(float v){ return __float2bfloat16(v); }
__device__ __forceinline__ float bs2f(short s){ return __uint_as_float(((unsigned)(unsigned short)s)<<16); }

// K1: decoupler 1x1 conv + softmax(R=2); writes scale factors sc[r][b][yx] = 1 + M_r.
__global__ void k_scales(const float* __restrict__ F, const float* __restrict__ dec_w,
                         const float* __restrict__ dec_b, float* __restrict__ sc){
    __shared__ float w0[CC_], w1[CC_];
    int tid = threadIdx.x; // 64
    for (int c = tid; c < CC_; c += 64){ w0[c] = dec_w[c]; w1[c] = dec_w[CC_+c]; }
    __syncthreads();
    int pid = blockIdx.x*64 + tid;
    int b = pid / HWSZ, yx = pid % HWSZ;
    const float* base = F + (size_t)b*CC_*HWSZ + yx;
    float a0 = dec_b[0], a1 = dec_b[1];
    for (int c = 0; c < CC_; ++c){ float v = base[(size_t)c*HWSZ]; a0 += v*w0[c]; a1 += v*w1[c]; }
    float m = fmaxf(a0,a1);
    float e0 = __expf(a0-m), e1 = __expf(a1-m);
    float inv = 1.0f/(e0+e1);
    sc[pid]                  = 1.0f + e0*inv;
    sc[(size_t)BB*HWSZ+pid]  = 1.0f + e1*inv;
}

// K1b: pack Fp[r][b][gy+1][gx+1][c] = bf16(F[b][c][gy][gx] * sc_r). Borders pre-zeroed by memset.
__global__ __launch_bounds__(256) void k_pack(const float* __restrict__ F, const float* __restrict__ sc,
                                              bf16* __restrict__ Fp){
    __shared__ bf16 lds[2][56][258];
    int bx = blockIdx.x; int b = bx/HH, gy = bx%HH;
    int tid = threadIdx.x; int x = tid & 63; int cq = tid >> 6;
    if (x < 56){
        const float* frow = F + (size_t)b*CC_*HWSZ + gy*WW + x;
        float s0 = sc[(size_t)b*HWSZ + gy*WW + x];
        float s1 = sc[(size_t)BB*HWSZ + (size_t)b*HWSZ + gy*WW + x];
        for (int cc = 0; cc < 64; ++cc){
            int c = cc*4 + cq;
            float v = frow[(size_t)c*HWSZ];
            lds[0][x][c] = f2b(v*s0);
            lds[1][x][c] = f2b(v*s1);
        }
    }
    __syncthreads();
    for (int r = 0; r < 2; ++r){
        bf16* dst = Fp + (size_t)r*FPR + (((size_t)b*58 + gy+1)*58 + 1)*256 + tid;
        for (int x2 = 0; x2 < 56; ++x2) dst[(size_t)x2*256] = lds[r][x2][tid];
    }
}

// K1c: pack conv1 weights into MFMA B-fragment order.
// Bp[r][t][icc][nt][lane][j] = w[r][oc=nt*16+(lane&15)][ic=icc*32+(lane>>4)*8+j][t]
__global__ void k_bprep(const float* __restrict__ w, bf16* __restrict__ Bp){
    int id = blockIdx.x;               // 2*9*8*4 = 576
    int nt = id & 3; id >>= 2; int icc = id & 7; id >>= 3; int t = id % 9; int r = id / 9;
    int L = threadIdx.x;               // 64
    int oc = nt*16 + (L&15);
    const float* wr = w + (size_t)r*HID*CC_*9;
    bf16* out = Bp + (((((size_t)r*9 + t)*8 + icc)*4 + nt)*64 + L)*8;
    #pragma unroll
    for (int j = 0; j < 8; ++j){
        int ic = icc*32 + (L>>4)*8 + j;
        out[j] = f2b(wr[((size_t)oc*CC_ + ic)*9 + t]);
    }
}

// K2: conv3x3 256->64 via MFMA implicit GEMM. Block=(b,y), 4 waves = m-tiles x0 {0,16,32,40}.
// No LDS, no barriers. A-frags straight from padded NHWC Fp; B-frags from prepacked Bp.
__global__ __launch_bounds__(256) void k_conv1(const bf16* __restrict__ Fp, const bf16* __restrict__ Bp,
                                               const float* __restrict__ bias, bf16* __restrict__ hout){
    int bx = blockIdx.x; int b = bx / HH, y = bx % HH;
    int tid = threadIdx.x; int wave = tid>>6, lane = tid&63;
    int m = lane&15, q = lane>>4;
    int x0 = (wave==3) ? 40 : wave*16;
    f32x4 acc0 = {0,0,0,0}, acc1 = {0,0,0,0}, acc2 = {0,0,0,0}, acc3 = {0,0,0,0};
    const bf16* Fb = Fp + ((size_t)b*58*58)*256;
    #pragma unroll
    for (int t = 0; t < 9; ++t){
        int ty = t/3, tx = t%3;
        const bf16* arow = Fb + ((size_t)(y+ty)*58 + (x0+m+tx))*256 + q*8;
        const bf16* brow = Bp + ((size_t)t*8)*4*64*8 + lane*8;
        #pragma unroll
        for (int icc = 0; icc < 8; ++icc){
            short8 a  = *(const short8*)(arow + icc*32);
            const bf16* bb = brow + (size_t)icc*4*64*8;
            short8 b0 = *(const short8*)(bb);
            short8 b1 = *(const short8*)(bb + 64*8);
            short8 b2 = *(const short8*)(bb + 2*64*8);
            short8 b3 = *(const short8*)(bb + 3*64*8);
            acc0 = __builtin_amdgcn_mfma_f32_16x16x32_bf16(a, b0, acc0, 0, 0, 0);
            acc1 = __builtin_amdgcn_mfma_f32_16x16x32_bf16(a, b1, acc1, 0, 0, 0);
            acc2 = __builtin_amdgcn_mfma_f32_16x16x32_bf16(a, b2, acc2, 0, 0, 0);
            acc3 = __builtin_amdgcn_mfma_f32_16x16x32_bf16(a, b3, acc3, 0, 0, 0);
        }
    }
    // D layout: col = lane&15 -> oc within n-tile; row = q*4+r -> pixel within m-tile.
    f32x4 accs[4] = {acc0, acc1, acc2, acc3};
    #pragma unroll
    for (int nt = 0; nt < 4; ++nt){
        int oc = nt*16 + m;
        float bv = bias[oc];
        #pragma unroll
        for (int r2 = 0; r2 < 4; ++r2){
            int x = x0 + q*4 + r2;
            hout[((size_t)b*HID + oc)*HWSZ + y*WW + x] = f2b(fmaxf(accs[nt][r2] + bv, 0.f));
        }
    }
}

// K3: conv3x3 64 -> 18, pad 1, + bias. Thread per output.
__global__ void k_conv2(const bf16* __restrict__ h, const float* __restrict__ wgt,
                        const float* __restrict__ bias, float* __restrict__ p){
    int n = blockIdx.x*256 + threadIdx.x;
    if (n >= BB*18*HWSZ) return;
    int b = n / (18*HWSZ); int rr = n % (18*HWSZ); int oc = rr / HWSZ;
    int yx = rr % HWSZ; int y = yx / WW, x = yx % WW;
    float acc = bias[oc];
    const bf16* hb = h + (size_t)b*HID*HWSZ;
    const float* wp = wgt + (size_t)oc*HID*9;
    for (int ic = 0; ic < HID; ++ic){
        const bf16* hc = hb + (size_t)ic*HWSZ;
        #pragma unroll
        for (int ky=0;ky<3;++ky){
            int gy = y+ky-1; if ((unsigned)gy >= HH) continue;
            #pragma unroll
            for (int kx=0;kx<3;++kx){
                int gx = x+kx-1; if ((unsigned)gx >= WW) continue;
                acc += b2f(hc[gy*WW+gx]) * wp[ic*9+ky*3+kx];
            }
        }
    }
    p[n] = acc;
}

// K4a: 8x8 avg pool (56->7) on F_i = F*sc_i, depthwise 3x3 + relu, global mean -> s[b,c].
__global__ void k_akg_pool(const float* __restrict__ Fc, const float* __restrict__ sc_i,
                           const float* __restrict__ dw, float* __restrict__ s){
    int bc = blockIdx.x; int b = bc / CC_; int c = bc % CC_;
    int l = threadIdx.x; // 64
    __shared__ float sm[49];
    __shared__ float red[64];
    const float* fb = Fc + (size_t)bc*HWSZ;
    const float* si = sc_i + (size_t)b*HWSZ;
    if (l < 49){
        int u = l/7, v = l%7;
        float sum = 0.f;
        for (int r=0;r<8;++r){
            const float* rp = fb + (u*8+r)*WW + v*8;
            const float* sp = si + (u*8+r)*WW + v*8;
            #pragma unroll
            for (int q=0;q<8;++q) sum += rp[q] * sp[q];
        }
        sm[l] = sum * (1.f/64.f);
    }
    __syncthreads();
    float rv = 0.f;
    if (l < 49){
        float w[9];
        #pragma unroll
        for (int k=0;k<9;++k) w[k] = dw[c*9+k];
        int u=l/7, v=l%7; float acc=0.f;
        #pragma unroll
        for (int ky=0;ky<3;++ky){ int uu=u+ky-1; if((unsigned)uu>=7u) continue;
            #pragma unroll
            for (int kx=0;kx<3;++kx){ int vv=v+kx-1; if((unsigned)vv>=7u) continue;
                acc += sm[uu*7+vv]*w[ky*3+kx]; } }
        rv = fmaxf(acc, 0.f);
    }
    red[l] = rv;
    __syncthreads();
    if (l==0){ float t=0.f; for(int i2=0;i2<64;++i2) t+=red[i2]; s[bc] = t*(1.f/49.f); }
}

// K4b: head matvec + tanh -> Kw stored [b][t][c] (deform-friendly layout).
__global__ void k_akg_head(const float* __restrict__ s, const float* __restrict__ hw,
                           const float* __restrict__ hb, float* __restrict__ Kw){
    int b = blockIdx.x / 9; int og = blockIdx.x % 9;
    __shared__ float sv[CC_];
    int tid = threadIdx.x; // 256
    sv[tid] = s[b*CC_ + tid];
    __syncthreads();
    int o = og*256 + tid;              // o = c*9 + t
    const float* wp = hw + (size_t)o*CC_;
    float acc = hb[o];
    for (int c2=0;c2<CC_;++c2) acc += wp[c2]*sv[c2];
    int c = o / 9, t = o - 9*c;
    Kw[(size_t)b*2304 + t*256 + c] = tanhf(acc);
}

// K5: deformable depthwise on Fp (NHWC, sc pre-folded): 16B channel-vector gathers.
__global__ __launch_bounds__(256) void k_deform(const bf16* __restrict__ Fp_r, const float* __restrict__ p,
                                                const float* __restrict__ Kw, bf16* __restrict__ outs, int creg){
    __shared__ int   so[504][4];
    __shared__ float swt[504][4];
    int bx = blockIdx.x; int b = bx / HH, y = bx % HH;
    int tid = threadIdx.x;
    for (int e = tid; e < 504; e += 256){
        int t = e / 56, x = e % 56;
        int ky = t / 3, kx = t % 3;
        float dy = p[((size_t)b*18 + 2*t  )*HWSZ + y*WW + x];
        float dx = p[((size_t)b*18 + 2*t+1)*HWSZ + y*WW + x];
        float py = (float)(y - 1 + ky) + dy;
        float px = (float)(x - 1 + kx) + dx;
        float y0f = floorf(py), x0f = floorf(px);
        float wy1 = py - y0f, wx1 = px - x0f;
        float wy0 = 1.f - wy1, wx0 = 1.f - wx1;
        float vy0 = (y0f >= 0.f  && y0f <= 55.f) ? 1.f : 0.f;
        float vy1 = (y0f >= -1.f && y0f <= 54.f) ? 1.f : 0.f;
        float vx0 = (x0f >= 0.f  && x0f <= 55.f) ? 1.f : 0.f;
        float vx1 = (x0f >= -1.f && x0f <= 54.f) ? 1.f : 0.f;
        int y0 = (int)y0f, x0 = (int)x0f;
        int iy0 = min(max(y0,0),55),   iy1 = min(max(y0+1,0),55);
        int ix0 = min(max(x0,0),55),   ix1 = min(max(x0+1,0),55);
        so[e][0] = ((iy0+1)*58 + ix0+1)*256;
        so[e][1] = ((iy0+1)*58 + ix1+1)*256;
        so[e][2] = ((iy1+1)*58 + ix0+1)*256;
        so[e][3] = ((iy1+1)*58 + ix1+1)*256;
        swt[e][0] = wy0*wx0*vy0*vx0;
        swt[e][1] = wy0*wx1*vy0*vx1;
        swt[e][2] = wy1*wx0*vy1*vx0;
        swt[e][3] = wy1*wx1*vy1*vx1;
    }
    __syncthreads();
    if (tid >= 224) return;
    int xl = tid % 56, cs = tid / 56; // cs 0..3
    const bf16* Fb = Fp_r + (size_t)b*58*58*256;
    const float* Kb = Kw + (size_t)b*2304;
    for (int chunk = 0; chunk < 8; ++chunk){
        int c0 = cs*64 + chunk*8;
        float acc[8];
        #pragma unroll
        for (int j=0;j<8;++j) acc[j]=0.f;
        #pragma unroll 1
        for (int t=0;t<9;++t){
            int e = t*56+xl;
            short8 f00 = *(const short8*)(Fb + so[e][0] + c0);
            short8 f01 = *(const short8*)(Fb + so[e][1] + c0);
            short8 f10 = *(const short8*)(Fb + so[e][2] + c0);
            short8 f11 = *(const short8*)(Fb + so[e][3] + c0);
            float w00=swt[e][0], w01=swt[e][1], w10=swt[e][2], w11=swt[e][3];
            f32x4 ka = *(const f32x4*)(Kb + t*256 + c0);
            f32x4 kb = *(const f32x4*)(Kb + t*256 + c0 + 4);
            #pragma unroll
            for (int j=0;j<8;++j){
                float v = w00*bs2f(f00[j]) + w01*bs2f(f01[j]) + w10*bs2f(f10[j]) + w11*bs2f(f11[j]);
                float kv = (j<4)? ka[j] : kb[j-4];
                acc[j] += kv*v;
            }
        }
        #pragma unroll
        for (int j=0;j<8;++j){
            int c = c0+j;
            outs[((size_t)(b*2 + creg)*CC_ + c)*HWSZ + y*WW + xl] = f2b(acc[j]);
        }
    }
}

// K6a: pw2 1x1 conv (512 -> 256) + bias, stats only (per-channel sum/sumsq atomics).
__global__ __launch_bounds__(256) void k_pw2_stats(const bf16* __restrict__ outs, const float* __restrict__ w,
                                                   const float* __restrict__ bias, float* __restrict__ stats){
    __shared__ float in[16][56];
    int bx = blockIdx.x;
    int octile = bx % 4; int by = bx / 4; int b = by / HH, y = by % HH;
    int tid = threadIdx.x; int ocl = tid >> 2; int xq = tid & 3;
    int oc = octile*64 + ocl; int x0 = xq*14;
    float acc[14];
    #pragma unroll
    for (int j=0;j<14;++j) acc[j]=0.f;
    for (int cc = 0; cc < 512; cc += 16){
        for (int idx = tid; idx < 16*56; idx += 256){
            int ic = idx / 56, x = idx % 56;
            in[ic][x] = b2f(outs[((size_t)b*512 + cc+ic)*HWSZ + y*WW + x]);
        }
        __syncthreads();
        const float* wp = w + (size_t)oc*512 + cc;
        for (int ic=0;ic<16;++ic){
            float wv = wp[ic];
            #pragma unroll
            for (int j=0;j<14;++j) acc[j] += wv*in[ic][x0+j];
        }
        __syncthreads();
    }
    float bv = bias[oc];
    float s1=0.f, s2=0.f;
    #pragma unroll
    for (int j=0;j<14;++j){ float v = acc[j]+bv; s1+=v; s2+=v*v; }
    s1 += __shfl_down(s1, 2, 4); s1 += __shfl_down(s1, 1, 4);
    s2 += __shfl_down(s2, 2, 4); s2 += __shfl_down(s2, 1, 4);
    if (xq==0){ atomicAdd(&stats[oc], s1); atomicAdd(&stats[CC_+oc], s2); }
}

// K6b: finalize BN stats.
__global__ void k_bnstat(const float* __restrict__ stats, float* __restrict__ bnp){
    int c = threadIdx.x;
    float n = (float)(BB*HWSZ);
    float mean = stats[c]/n;
    float var = stats[CC_+c]/n - mean*mean;
    var = fmaxf(var, 0.f);
    bnp[c] = mean; bnp[CC_+c] = rsqrtf(var + 1e-5f);
}

// K6c: pw2 recompute + BN apply, write fp32 out.
__global__ __launch_bounds__(256) void k_pw2_apply(const bf16* __restrict__ outs, const float* __restrict__ w,
                                                   const float* __restrict__ bias, const float* __restrict__ bnp,
                                                   const float* __restrict__ gamma, const float* __restrict__ beta,
                                                   float* __restrict__ out){
    __shared__ float in[16][56];
    int bx = blockIdx.x;
    int octile = bx % 4; int by = bx / 4; int b = by / HH, y = by % HH;
    int tid = threadIdx.x; int ocl = tid >> 2; int xq = tid & 3;
    int oc = octile*64 + ocl; int x0 = xq*14;
    float acc[14];
    #pragma unroll
    for (int j=0;j<14;++j) acc[j]=0.f;
    for (int cc = 0; cc < 512; cc += 16){
        for (int idx = tid; idx < 16*56; idx += 256){
            int ic = idx / 56, x = idx % 56;
            in[ic][x] = b2f(outs[((size_t)b*512 + cc+ic)*HWSZ + y*WW + x]);
        }
        __syncthreads();
        const float* wp = w + (size_t)oc*512 + cc;
        for (int ic=0;ic<16;++ic){
            float wv = wp[ic];
            #pragma unroll
            for (int j=0;j<14;++j) acc[j] += wv*in[ic][x0+j];
        }
        __syncthreads();
    }
    float bv = bias[oc];
    float mean = bnp[oc], rsq = bnp[CC_+oc];
    float g = gamma[oc], be = beta[oc];
    float* op = out + ((size_t)b*CC_ + oc)*HWSZ + y*WW + x0;
    #pragma unroll
    for (int j=0;j<14;++j){ float v = acc[j]+bv; op[j] = (v-mean)*rsq*g + be; }
}

extern "C" void kernel_launch(void* const* d_in, const int* in_sizes, int n_in,
                              void* d_out, int out_size, void* d_ws, size_t ws_size,
                              hipStream_t stream) {
    (void)in_sizes; (void)n_in; (void)out_size; (void)ws_size;
    const float* F_c    = (const float*)d_in[0];
    const float* dec_w  = (const float*)d_in[1];
    const float* dec_b  = (const float*)d_in[2];
    const float* off1_w = (const float*)d_in[3];
    const float* off1_b = (const float*)d_in[4];
    const float* off2_w = (const float*)d_in[5];
    const float* off2_b = (const float*)d_in[6];
    const float* akg_dw = (const float*)d_in[7];
    const float* akg_hw = (const float*)d_in[8];
    const float* akg_hb = (const float*)d_in[9];
    const float* pw2_w  = (const float*)d_in[10];
    const float* pw2_b  = (const float*)d_in[11];
    const float* gamma  = (const float*)d_in[12];
    const float* beta   = (const float*)d_in[13];
    float* out = (float*)d_out;

    char* ws = (char*)d_ws;
    size_t off = 0;
    auto alloc = [&](size_t bytes)->char*{
        char* r = ws + off;
        off = (off + bytes + 255) & ~(size_t)255;
        return r;
    };
    const size_t NPC = (size_t)BB*CC_*HWSZ;
    // Workspace ~58 MB.
    bf16*  Fp    = (bf16*) alloc(2*FPR*2);                 // padded NHWC F*sc, both regions
    bf16*  Bp    = (bf16*) alloc((size_t)2*9*8*4*64*8*2);  // conv1 weight frags
    float* sc    = (float*)alloc((size_t)2*BB*HWSZ*4);
    bf16*  h     = (bf16*) alloc((size_t)BB*HID*HWSZ*2);
    float* p     = (float*)alloc((size_t)BB*18*HWSZ*4);
    float* s     = (float*)alloc((size_t)BB*CC_*4);
    float* Kw    = (float*)alloc((size_t)BB*CC_*9*4);
    bf16*  outsb = (bf16*) alloc(NPC*2*2);
    float* stats = (float*)alloc(2*CC_*4);
    float* bnp   = (float*)alloc(2*CC_*4);

    hipMemsetAsync(stats, 0, 2*CC_*sizeof(float), stream);
    hipMemsetAsync(Fp, 0, 2*FPR*2, stream);                // zero borders for pad

    k_scales<<<dim3((BB*HWSZ)/64), dim3(64), 0, stream>>>(F_c, dec_w, dec_b, sc);
    k_pack<<<dim3(BB*HH), dim3(256), 0, stream>>>(F_c, sc, Fp);
    k_bprep<<<dim3(576), dim3(64), 0, stream>>>(off1_w, Bp);

    for (int i = 0; i < RR_; ++i){
        const float* sc_i = sc + (size_t)i*BB*HWSZ;
        const bf16* Fp_i = Fp + (size_t)i*FPR;
        k_conv1<<<dim3(BB*HH), dim3(256), 0, stream>>>(
            Fp_i, Bp + (size_t)i*9*8*4*64*8, off1_b + i*HID, h);
        k_conv2<<<dim3((BB*18*HWSZ + 255)/256), dim3(256), 0, stream>>>(
            h, off2_w + (size_t)i*18*HID*9, off2_b + i*18, p);
        k_akg_pool<<<dim3(BB*CC_), dim3(64), 0, stream>>>(
            F_c, sc_i, akg_dw + (size_t)i*CC_*9, s);
        k_akg_head<<<dim3(BB*9), dim3(256), 0, stream>>>(
            s, akg_hw + (size_t)i*2304*CC_, akg_hb + (size_t)i*2304, Kw);
        k_deform<<<dim3(BB*HH), dim3(256), 0, stream>>>(Fp_i, p, Kw, outsb, i);
    }

    k_pw2_stats<<<dim3(BB*HH*4), dim3(256), 0, stream>>>(outsb, pw2_w, pw2_b, stats);
    k_bnstat<<<dim3(1), dim3(256), 0, stream>>>(stats, bnp);
    k_pw2_apply<<<dim3(BB*HH*4), dim3(256), 0, stream>>>(outsb, pw2_w, pw2_b, bnp, gamma, beta, out);
}

// Round 7
// 873.769 us; speedup vs baseline: 1.9282x; 1.3754x over previous
//
#include <hip/hip_runtime.h>
#include <hip/hip_bf16.h>

#define BB 8
#define CC_ 256
#define HH 56
#define WW 56
#define HWSZ (HH*WW)
#define RR_ 2
#define HID 64
#define FPR ((size_t)8*58*58*256)   // padded NHWC region elements
#define NPIX ((size_t)BB*HWSZ)      // 25088

typedef __hip_bfloat16 bf16;
typedef __attribute__((ext_vector_type(8))) short short8;
typedef __attribute__((ext_vector_type(4))) float f32x4;

__device__ __forceinline__ float b2f(bf16 v){ return __bfloat162float(v); }
__device__ __forceinline__ bf16 f2b(float v){ return __float2bfloat16(v); }
__device__ __forceinline__ float bs2f(short s){ return __uint_as_float(((unsigned)(unsigned short)s)<<16); }

// K1: decoupler 1x1 conv + softmax(R=2); writes scale factors sc[r][b][yx] = 1 + M_r.
__global__ void k_scales(const float* __restrict__ F, const float* __restrict__ dec_w,
                         const float* __restrict__ dec_b, float* __restrict__ sc){
    __shared__ float w0[CC_], w1[CC_];
    int tid = threadIdx.x; // 64
    for (int c = tid; c < CC_; c += 64){ w0[c] = dec_w[c]; w1[c] = dec_w[CC_+c]; }
    __syncthreads();
    int pid = blockIdx.x*64 + tid;
    int b = pid / HWSZ, yx = pid % HWSZ;
    const float* base = F + (size_t)b*CC_*HWSZ + yx;
    float a0 = dec_b[0], a1 = dec_b[1];
    for (int c = 0; c < CC_; ++c){ float v = base[(size_t)c*HWSZ]; a0 += v*w0[c]; a1 += v*w1[c]; }
    float m = fmaxf(a0,a1);
    float e0 = __expf(a0-m), e1 = __expf(a1-m);
    float inv = 1.0f/(e0+e1);
    sc[pid]                  = 1.0f + e0*inv;
    sc[(size_t)BB*HWSZ+pid]  = 1.0f + e1*inv;
}

// K1b: pack Fp[r][b][gy+1][gx+1][c] = bf16(F[b][c][gy][gx] * sc_r). Borders pre-zeroed by memset.
__global__ __launch_bounds__(256) void k_pack(const float* __restrict__ F, const float* __restrict__ sc,
                                              bf16* __restrict__ Fp){
    __shared__ bf16 lds[2][56][258];
    int bx = blockIdx.x; int b = bx/HH, gy = bx%HH;
    int tid = threadIdx.x; int x = tid & 63; int cq = tid >> 6;
    if (x < 56){
        const float* frow = F + (size_t)b*CC_*HWSZ + gy*WW + x;
        float s0 = sc[(size_t)b*HWSZ + gy*WW + x];
        float s1 = sc[(size_t)BB*HWSZ + (size_t)b*HWSZ + gy*WW + x];
        for (int cc = 0; cc < 64; ++cc){
            int c = cc*4 + cq;
            float v = frow[(size_t)c*HWSZ];
            lds[0][x][c] = f2b(v*s0);
            lds[1][x][c] = f2b(v*s1);
        }
    }
    __syncthreads();
    for (int r = 0; r < 2; ++r){
        bf16* dst = Fp + (size_t)r*FPR + (((size_t)b*58 + gy+1)*58 + 1)*256 + tid;
        for (int x2 = 0; x2 < 56; ++x2) dst[(size_t)x2*256] = lds[r][x2][tid];
    }
}

// K1c: pack conv1 weights into MFMA B-fragment order.
__global__ void k_bprep(const float* __restrict__ w, bf16* __restrict__ Bp){
    int id = blockIdx.x;               // 2*9*8*4 = 576
    int nt = id & 3; id >>= 2; int icc = id & 7; id >>= 3; int t = id % 9; int r = id / 9;
    int L = threadIdx.x;               // 64
    int oc = nt*16 + (L&15);
    const float* wr = w + (size_t)r*HID*CC_*9;
    bf16* out = Bp + (((((size_t)r*9 + t)*8 + icc)*4 + nt)*64 + L)*8;
    #pragma unroll
    for (int j = 0; j < 8; ++j){
        int ic = icc*32 + (L>>4)*8 + j;
        out[j] = f2b(wr[((size_t)oc*CC_ + ic)*9 + t]);
    }
}

// K1d: pack pw2 weights (256 x 512) into B-frag order: Bpw[kk][nt][lane][j].
__global__ void k_bprep_pw(const float* __restrict__ w, bf16* __restrict__ Bpw){
    int id = blockIdx.x;               // 16*16 = 256
    int kk = id >> 4, nt = id & 15;
    int L = threadIdx.x;               // 64
    int oc = nt*16 + (L&15);
    bf16* out = Bpw + (((size_t)(kk*16+nt))*64 + L)*8;
    #pragma unroll
    for (int j = 0; j < 8; ++j){
        int ic = kk*32 + (L>>4)*8 + j;
        out[j] = f2b(w[(size_t)oc*512 + ic]);
    }
}

// K2: conv3x3 256->64 via MFMA implicit GEMM. Block=(b,y), 4 waves = m-tiles x0 {0,16,32,40}.
__global__ __launch_bounds__(256) void k_conv1(const bf16* __restrict__ Fp, const bf16* __restrict__ Bp,
                                               const float* __restrict__ bias, bf16* __restrict__ hout){
    int bx = blockIdx.x; int b = bx / HH, y = bx % HH;
    int tid = threadIdx.x; int wave = tid>>6, lane = tid&63;
    int m = lane&15, q = lane>>4;
    int x0 = (wave==3) ? 40 : wave*16;
    f32x4 acc0 = {0,0,0,0}, acc1 = {0,0,0,0}, acc2 = {0,0,0,0}, acc3 = {0,0,0,0};
    const bf16* Fb = Fp + ((size_t)b*58*58)*256;
    #pragma unroll
    for (int t = 0; t < 9; ++t){
        int ty = t/3, tx = t%3;
        const bf16* arow = Fb + ((size_t)(y+ty)*58 + (x0+m+tx))*256 + q*8;
        const bf16* brow = Bp + ((size_t)t*8)*4*64*8 + lane*8;
        #pragma unroll
        for (int icc = 0; icc < 8; ++icc){
            short8 a  = *(const short8*)(arow + icc*32);
            const bf16* bb = brow + (size_t)icc*4*64*8;
            short8 b0 = *(const short8*)(bb);
            short8 b1 = *(const short8*)(bb + 64*8);
            short8 b2 = *(const short8*)(bb + 2*64*8);
            short8 b3 = *(const short8*)(bb + 3*64*8);
            acc0 = __builtin_amdgcn_mfma_f32_16x16x32_bf16(a, b0, acc0, 0, 0, 0);
            acc1 = __builtin_amdgcn_mfma_f32_16x16x32_bf16(a, b1, acc1, 0, 0, 0);
            acc2 = __builtin_amdgcn_mfma_f32_16x16x32_bf16(a, b2, acc2, 0, 0, 0);
            acc3 = __builtin_amdgcn_mfma_f32_16x16x32_bf16(a, b3, acc3, 0, 0, 0);
        }
    }
    f32x4 accs[4] = {acc0, acc1, acc2, acc3};
    #pragma unroll
    for (int nt = 0; nt < 4; ++nt){
        int oc = nt*16 + m;
        float bv = bias[oc];
        #pragma unroll
        for (int r2 = 0; r2 < 4; ++r2){
            int x = x0 + q*4 + r2;
            hout[((size_t)b*HID + oc)*HWSZ + y*WW + x] = f2b(fmaxf(accs[nt][r2] + bv, 0.f));
        }
    }
}

// K3: conv3x3 64 -> 18, pad 1, + bias. Thread per output.
__global__ void k_conv2(const bf16* __restrict__ h, const float* __restrict__ wgt,
                        const float* __restrict__ bias, float* __restrict__ p){
    int n = blockIdx.x*256 + threadIdx.x;
    if (n >= BB*18*HWSZ) return;
    int b = n / (18*HWSZ); int rr = n % (18*HWSZ); int oc = rr / HWSZ;
    int yx = rr % HWSZ; int y = yx / WW, x = yx % WW;
    float acc = bias[oc];
    const bf16* hb = h + (size_t)b*HID*HWSZ;
    const float* wp = wgt + (size_t)oc*HID*9;
    for (int ic = 0; ic < HID; ++ic){
        const bf16* hc = hb + (size_t)ic*HWSZ;
        #pragma unroll
        for (int ky=0;ky<3;++ky){
            int gy = y+ky-1; if ((unsigned)gy >= HH) continue;
            #pragma unroll
            for (int kx=0;kx<3;++kx){
                int gx = x+kx-1; if ((unsigned)gx >= WW) continue;
                acc += b2f(hc[gy*WW+gx]) * wp[ic*9+ky*3+kx];
            }
        }
    }
    p[n] = acc;
}

// K4a: 8x8 avg pool (56->7) on F_i = F*sc_i, depthwise 3x3 + relu, global mean -> s[b,c].
__global__ void k_akg_pool(const float* __restrict__ Fc, const float* __restrict__ sc_i,
                           const float* __restrict__ dw, float* __restrict__ s){
    int bc = blockIdx.x; int b = bc / CC_; int c = bc % CC_;
    int l = threadIdx.x; // 64
    __shared__ float sm[49];
    __shared__ float red[64];
    const float* fb = Fc + (size_t)bc*HWSZ;
    const float* si = sc_i + (size_t)b*HWSZ;
    if (l < 49){
        int u = l/7, v = l%7;
        float sum = 0.f;
        for (int r=0;r<8;++r){
            const float* rp = fb + (u*8+r)*WW + v*8;
            const float* sp = si + (u*8+r)*WW + v*8;
            #pragma unroll
            for (int q=0;q<8;++q) sum += rp[q] * sp[q];
        }
        sm[l] = sum * (1.f/64.f);
    }
    __syncthreads();
    float rv = 0.f;
    if (l < 49){
        float w[9];
        #pragma unroll
        for (int k=0;k<9;++k) w[k] = dw[c*9+k];
        int u=l/7, v=l%7; float acc=0.f;
        #pragma unroll
        for (int ky=0;ky<3;++ky){ int uu=u+ky-1; if((unsigned)uu>=7u) continue;
            #pragma unroll
            for (int kx=0;kx<3;++kx){ int vv=v+kx-1; if((unsigned)vv>=7u) continue;
                acc += sm[uu*7+vv]*w[ky*3+kx]; } }
        rv = fmaxf(acc, 0.f);
    }
    red[l] = rv;
    __syncthreads();
    if (l==0){ float t=0.f; for(int i2=0;i2<64;++i2) t+=red[i2]; s[bc] = t*(1.f/49.f); }
}

// K4b: head matvec + tanh -> Kw stored [b][t][c].
__global__ void k_akg_head(const float* __restrict__ s, const float* __restrict__ hw,
                           const float* __restrict__ hb, float* __restrict__ Kw){
    int b = blockIdx.x / 9; int og = blockIdx.x % 9;
    __shared__ float sv[CC_];
    int tid = threadIdx.x; // 256
    sv[tid] = s[b*CC_ + tid];
    __syncthreads();
    int o = og*256 + tid;              // o = c*9 + t
    const float* wp = hw + (size_t)o*CC_;
    float acc = hb[o];
    for (int c2=0;c2<CC_;++c2) acc += wp[c2]*sv[c2];
    int c = o / 9, t = o - 9*c;
    Kw[(size_t)b*2304 + t*256 + c] = tanhf(acc);
}

// K5: deformable depthwise on Fp; writes NHWC outs[b][yx][creg*256+c] (16B channel-vector stores).
__global__ __launch_bounds__(256) void k_deform(const bf16* __restrict__ Fp_r, const float* __restrict__ p,
                                                const float* __restrict__ Kw, bf16* __restrict__ outsN, int creg){
    __shared__ int   so[504][4];
    __shared__ float swt[504][4];
    int bx = blockIdx.x; int b = bx / HH, y = bx % HH;
    int tid = threadIdx.x;
    for (int e = tid; e < 504; e += 256){
        int t = e / 56, x = e % 56;
        int ky = t / 3, kx = t % 3;
        float dy = p[((size_t)b*18 + 2*t  )*HWSZ + y*WW + x];
        float dx = p[((size_t)b*18 + 2*t+1)*HWSZ + y*WW + x];
        float py = (float)(y - 1 + ky) + dy;
        float px = (float)(x - 1 + kx) + dx;
        float y0f = floorf(py), x0f = floorf(px);
        float wy1 = py - y0f, wx1 = px - x0f;
        float wy0 = 1.f - wy1, wx0 = 1.f - wx1;
        float vy0 = (y0f >= 0.f  && y0f <= 55.f) ? 1.f : 0.f;
        float vy1 = (y0f >= -1.f && y0f <= 54.f) ? 1.f : 0.f;
        float vx0 = (x0f >= 0.f  && x0f <= 55.f) ? 1.f : 0.f;
        float vx1 = (x0f >= -1.f && x0f <= 54.f) ? 1.f : 0.f;
        int y0 = (int)y0f, x0 = (int)x0f;
        int iy0 = min(max(y0,0),55),   iy1 = min(max(y0+1,0),55);
        int ix0 = min(max(x0,0),55),   ix1 = min(max(x0+1,0),55);
        so[e][0] = ((iy0+1)*58 + ix0+1)*256;
        so[e][1] = ((iy0+1)*58 + ix1+1)*256;
        so[e][2] = ((iy1+1)*58 + ix0+1)*256;
        so[e][3] = ((iy1+1)*58 + ix1+1)*256;
        swt[e][0] = wy0*wx0*vy0*vx0;
        swt[e][1] = wy0*wx1*vy0*vx1;
        swt[e][2] = wy1*wx0*vy1*vx0;
        swt[e][3] = wy1*wx1*vy1*vx1;
    }
    __syncthreads();
    if (tid >= 224) return;
    int xl = tid % 56, cs = tid / 56; // cs 0..3
    const bf16* Fb = Fp_r + (size_t)b*58*58*256;
    const float* Kb = Kw + (size_t)b*2304;
    bf16* orow = outsN + ((size_t)b*HWSZ + y*WW + xl)*512 + creg*256;
    for (int chunk = 0; chunk < 8; ++chunk){
        int c0 = cs*64 + chunk*8;
        float acc[8];
        #pragma unroll
        for (int j=0;j<8;++j) acc[j]=0.f;
        #pragma unroll 1
        for (int t=0;t<9;++t){
            int e = t*56+xl;
            short8 f00 = *(const short8*)(Fb + so[e][0] + c0);
            short8 f01 = *(const short8*)(Fb + so[e][1] + c0);
            short8 f10 = *(const short8*)(Fb + so[e][2] + c0);
            short8 f11 = *(const short8*)(Fb + so[e][3] + c0);
            float w00=swt[e][0], w01=swt[e][1], w10=swt[e][2], w11=swt[e][3];
            f32x4 ka = *(const f32x4*)(Kb + t*256 + c0);
            f32x4 kb = *(const f32x4*)(Kb + t*256 + c0 + 4);
            #pragma unroll
            for (int j=0;j<8;++j){
                float v = w00*bs2f(f00[j]) + w01*bs2f(f01[j]) + w10*bs2f(f10[j]) + w11*bs2f(f11[j]);
                float kv = (j<4)? ka[j] : kb[j-4];
                acc[j] += kv*v;
            }
        }
        __attribute__((aligned(16))) bf16 tmp[8];
        #pragma unroll
        for (int j=0;j<8;++j) tmp[j] = f2b(acc[j]);
        *(short8*)(orow + c0) = *(const short8*)tmp;
    }
}

// K6a: pw2 MFMA GEMM (M=25088,N=256,K=512), stats pass: per-block per-oc sum/sumsq partials.
__global__ __launch_bounds__(256) void k_pw2_mstats(const bf16* __restrict__ outsN, const bf16* __restrict__ Bpw,
                                                    const float* __restrict__ bias, float* __restrict__ partials){
    __shared__ float ls[2][2][256];
    int tid = threadIdx.x; int wave = tid>>6, lane = tid&63;
    int pixGroup = wave>>1, ntH = wave&1;
    int m = lane&15, q = lane>>4;
    size_t pb = (size_t)blockIdx.x*32 + pixGroup*16;
    const bf16* Ap = outsN + (pb + m)*512 + q*8;
    f32x4 acc[8];
    #pragma unroll
    for (int i=0;i<8;++i) acc[i] = (f32x4){0,0,0,0};
    #pragma unroll 1
    for (int kk = 0; kk < 16; ++kk){
        short8 a = *(const short8*)(Ap + kk*32);
        const bf16* Bk = Bpw + (((size_t)kk*16 + ntH*8)*64 + lane)*8;
        #pragma unroll
        for (int nt2 = 0; nt2 < 8; ++nt2){
            short8 b = *(const short8*)(Bk + (size_t)nt2*64*8);
            acc[nt2] = __builtin_amdgcn_mfma_f32_16x16x32_bf16(a, b, acc[nt2], 0, 0, 0);
        }
    }
    #pragma unroll
    for (int nt2 = 0; nt2 < 8; ++nt2){
        int oc = ntH*128 + nt2*16 + m;
        float bv = bias[oc];
        float s1 = 0.f, s2 = 0.f;
        #pragma unroll
        for (int r = 0; r < 4; ++r){ float v = acc[nt2][r] + bv; s1 += v; s2 += v*v; }
        s1 += __shfl_down(s1, 32); s1 += __shfl_down(s1, 16);
        s2 += __shfl_down(s2, 32); s2 += __shfl_down(s2, 16);
        if (q == 0){ ls[pixGroup][0][oc] = s1; ls[pixGroup][1][oc] = s2; }
    }
    __syncthreads();
    if (tid < 256){
        partials[(size_t)blockIdx.x*512 + tid]       = ls[0][0][tid] + ls[1][0][tid];
        partials[(size_t)blockIdx.x*512 + 256 + tid] = ls[0][1][tid] + ls[1][1][tid];
    }
}

// K6b: reduce partials -> bnp (mean, rsqrt).
__global__ void k_bnstat2(const float* __restrict__ partials, float* __restrict__ bnp){
    __shared__ float sm[512];
    int tid = threadIdx.x;           // 512
    float acc = 0.f;
    for (int blk = 0; blk < 784; ++blk) acc += partials[(size_t)blk*512 + tid];
    sm[tid] = acc;
    __syncthreads();
    if (tid < 256){
        float n = (float)NPIX;
        float mean = sm[tid] / n;
        float var = sm[256+tid] / n - mean*mean;
        var = fmaxf(var, 0.f);
        bnp[tid] = mean; bnp[256+tid] = rsqrtf(var + 1e-5f);
    }
}

// K6c: pw2 MFMA GEMM apply pass: recompute + BN, write fp32 NCHW out.
__global__ __launch_bounds__(256) void k_pw2_mapply(const bf16* __restrict__ outsN, const bf16* __restrict__ Bpw,
                                                    const float* __restrict__ bias, const float* __restrict__ bnp,
                                                    const float* __restrict__ gamma, const float* __restrict__ beta,
                                                    float* __restrict__ out){
    int tid = threadIdx.x; int wave = tid>>6, lane = tid&63;
    int pixGroup = wave>>1, ntH = wave&1;
    int m = lane&15, q = lane>>4;
    size_t pb = (size_t)blockIdx.x*32 + pixGroup*16;
    const bf16* Ap = outsN + (pb + m)*512 + q*8;
    f32x4 acc[8];
    #pragma unroll
    for (int i=0;i<8;++i) acc[i] = (f32x4){0,0,0,0};
    #pragma unroll 1
    for (int kk = 0; kk < 16; ++kk){
        short8 a = *(const short8*)(Ap + kk*32);
        const bf16* Bk = Bpw + (((size_t)kk*16 + ntH*8)*64 + lane)*8;
        #pragma unroll
        for (int nt2 = 0; nt2 < 8; ++nt2){
            short8 b = *(const short8*)(Bk + (size_t)nt2*64*8);
            acc[nt2] = __builtin_amdgcn_mfma_f32_16x16x32_bf16(a, b, acc[nt2], 0, 0, 0);
        }
    }
    int b_idx = (int)(pb / HWSZ);
    int yx0 = (int)(pb % HWSZ);
    #pragma unroll
    for (int nt2 = 0; nt2 < 8; ++nt2){
        int oc = ntH*128 + nt2*16 + m;
        float bv = bias[oc];
        float mean = bnp[oc], rsq = bnp[256+oc];
        float g = gamma[oc], be = beta[oc];
        float* op = out + ((size_t)b_idx*CC_ + oc)*HWSZ + yx0 + q*4;
        #pragma unroll
        for (int r = 0; r < 4; ++r){
            float v = acc[nt2][r] + bv;
            op[r] = (v - mean)*rsq*g + be;
        }
    }
}

extern "C" void kernel_launch(void* const* d_in, const int* in_sizes, int n_in,
                              void* d_out, int out_size, void* d_ws, size_t ws_size,
                              hipStream_t stream) {
    (void)in_sizes; (void)n_in; (void)out_size; (void)ws_size;
    const float* F_c    = (const float*)d_in[0];
    const float* dec_w  = (const float*)d_in[1];
    const float* dec_b  = (const float*)d_in[2];
    const float* off1_w = (const float*)d_in[3];
    const float* off1_b = (const float*)d_in[4];
    const float* off2_w = (const float*)d_in[5];
    const float* off2_b = (const float*)d_in[6];
    const float* akg_dw = (const float*)d_in[7];
    const float* akg_hw = (const float*)d_in[8];
    const float* akg_hb = (const float*)d_in[9];
    const float* pw2_w  = (const float*)d_in[10];
    const float* pw2_b  = (const float*)d_in[11];
    const float* gamma  = (const float*)d_in[12];
    const float* beta   = (const float*)d_in[13];
    float* out = (float*)d_out;

    char* ws = (char*)d_ws;
    size_t off = 0;
    auto alloc = [&](size_t bytes)->char*{
        char* r = ws + off;
        off = (off + bytes + 255) & ~(size_t)255;
        return r;
    };
    // Workspace ~61 MB.
    bf16*  Fp    = (bf16*) alloc(2*FPR*2);                 // padded NHWC F*sc, both regions
    bf16*  Bp    = (bf16*) alloc((size_t)2*9*8*4*64*8*2);  // conv1 weight frags
    bf16*  Bpw   = (bf16*) alloc((size_t)16*16*64*8*2);    // pw2 weight frags
    float* sc    = (float*)alloc((size_t)2*BB*HWSZ*4);
    bf16*  h     = (bf16*) alloc((size_t)BB*HID*HWSZ*2);
    float* p     = (float*)alloc((size_t)BB*18*HWSZ*4);
    float* s     = (float*)alloc((size_t)BB*CC_*4);
    float* Kw    = (float*)alloc((size_t)BB*CC_*9*4);
    bf16*  outsN = (bf16*) alloc(NPIX*512*2);              // NHWC, k = creg*256+c
    float* partials = (float*)alloc((size_t)784*512*4);
    float* bnp   = (float*)alloc(2*CC_*4);

    hipMemsetAsync(Fp, 0, 2*FPR*2, stream);                // zero borders for pad

    k_scales<<<dim3((BB*HWSZ)/64), dim3(64), 0, stream>>>(F_c, dec_w, dec_b, sc);
    k_pack<<<dim3(BB*HH), dim3(256), 0, stream>>>(F_c, sc, Fp);
    k_bprep<<<dim3(576), dim3(64), 0, stream>>>(off1_w, Bp);
    k_bprep_pw<<<dim3(256), dim3(64), 0, stream>>>(pw2_w, Bpw);

    for (int i = 0; i < RR_; ++i){
        const float* sc_i = sc + (size_t)i*BB*HWSZ;
        const bf16* Fp_i = Fp + (size_t)i*FPR;
        k_conv1<<<dim3(BB*HH), dim3(256), 0, stream>>>(
            Fp_i, Bp + (size_t)i*9*8*4*64*8, off1_b + i*HID, h);
        k_conv2<<<dim3((BB*18*HWSZ + 255)/256), dim3(256), 0, stream>>>(
            h, off2_w + (size_t)i*18*HID*9, off2_b + i*18, p);
        k_akg_pool<<<dim3(BB*CC_), dim3(64), 0, stream>>>(
            F_c, sc_i, akg_dw + (size_t)i*CC_*9, s);
        k_akg_head<<<dim3(BB*9), dim3(256), 0, stream>>>(
            s, akg_hw + (size_t)i*2304*CC_, akg_hb + (size_t)i*2304, Kw);
        k_deform<<<dim3(BB*HH), dim3(256), 0, stream>>>(Fp_i, p, Kw, outsN, i);
    }

    k_pw2_mstats<<<dim3(784), dim3(256), 0, stream>>>(outsN, Bpw, pw2_b, partials);
    k_bnstat2<<<dim3(1), dim3(512), 0, stream>>>(partials, bnp);
    k_pw2_mapply<<<dim3(784), dim3(256), 0, stream>>>(outsN, Bpw, pw2_b, bnp, gamma, beta, out);
}

// Round 8
// 671.063 us; speedup vs baseline: 2.5106x; 1.3021x over previous
//
#include <hip/hip_runtime.h>
#include <hip/hip_bf16.h>

#define BB 8
#define CC_ 256
#define HH 56
#define WW 56
#define HWSZ (HH*WW)
#define RR_ 2
#define HID 64
#define FPR ((size_t)8*58*58*256)   // padded NHWC region elements
#define NPIX ((size_t)BB*HWSZ)      // 25088

typedef __hip_bfloat16 bf16;
typedef __attribute__((ext_vector_type(8))) short short8;
typedef __attribute__((ext_vector_type(4))) float f32x4;

__device__ __forceinline__ float b2f(bf16 v){ return __bfloat162float(v); }
__device__ __forceinline__ bf16 f2b(float v){ return __float2bfloat16(v); }
__device__ __forceinline__ float bs2f(short s){ return __uint_as_float(((unsigned)(unsigned short)s)<<16); }

// K1: decoupler 1x1 conv + softmax(R=2); writes scale factors sc[r][b][yx] = 1 + M_r.
__global__ void k_scales(const float* __restrict__ F, const float* __restrict__ dec_w,
                         const float* __restrict__ dec_b, float* __restrict__ sc){
    __shared__ float w0[CC_], w1[CC_];
    int tid = threadIdx.x; // 64
    for (int c = tid; c < CC_; c += 64){ w0[c] = dec_w[c]; w1[c] = dec_w[CC_+c]; }
    __syncthreads();
    int pid = blockIdx.x*64 + tid;
    int b = pid / HWSZ, yx = pid % HWSZ;
    const float* base = F + (size_t)b*CC_*HWSZ + yx;
    float a0 = dec_b[0], a1 = dec_b[1];
    for (int c = 0; c < CC_; ++c){ float v = base[(size_t)c*HWSZ]; a0 += v*w0[c]; a1 += v*w1[c]; }
    float m = fmaxf(a0,a1);
    float e0 = __expf(a0-m), e1 = __expf(a1-m);
    float inv = 1.0f/(e0+e1);
    sc[pid]                  = 1.0f + e0*inv;
    sc[(size_t)BB*HWSZ+pid]  = 1.0f + e1*inv;
}

// K1b: pack Fp[r][b][gy+1][gx+1][c] = bf16(F[b][c][gy][gx] * sc_r). Borders pre-zeroed by memset.
__global__ __launch_bounds__(256) void k_pack(const float* __restrict__ F, const float* __restrict__ sc,
                                              bf16* __restrict__ Fp){
    __shared__ bf16 lds[2][56][258];
    int bx = blockIdx.x; int b = bx/HH, gy = bx%HH;
    int tid = threadIdx.x; int x = tid & 63; int cq = tid >> 6;
    if (x < 56){
        const float* frow = F + (size_t)b*CC_*HWSZ + gy*WW + x;
        float s0 = sc[(size_t)b*HWSZ + gy*WW + x];
        float s1 = sc[(size_t)BB*HWSZ + (size_t)b*HWSZ + gy*WW + x];
        for (int cc = 0; cc < 64; ++cc){
            int c = cc*4 + cq;
            float v = frow[(size_t)c*HWSZ];
            lds[0][x][c] = f2b(v*s0);
            lds[1][x][c] = f2b(v*s1);
        }
    }
    __syncthreads();
    for (int r = 0; r < 2; ++r){
        bf16* dst = Fp + (size_t)r*FPR + (((size_t)b*58 + gy+1)*58 + 1)*256 + tid;
        for (int x2 = 0; x2 < 56; ++x2) dst[(size_t)x2*256] = lds[r][x2][tid];
    }
}

// K1c: pack conv1 weights into MFMA B-fragment order.
__global__ void k_bprep(const float* __restrict__ w, bf16* __restrict__ Bp){
    int id = blockIdx.x;               // 2*9*8*4 = 576
    int nt = id & 3; id >>= 2; int icc = id & 7; id >>= 3; int t = id % 9; int r = id / 9;
    int L = threadIdx.x;               // 64
    int oc = nt*16 + (L&15);
    const float* wr = w + (size_t)r*HID*CC_*9;
    bf16* out = Bp + (((((size_t)r*9 + t)*8 + icc)*4 + nt)*64 + L)*8;
    #pragma unroll
    for (int j = 0; j < 8; ++j){
        int ic = icc*32 + (L>>4)*8 + j;
        out[j] = f2b(wr[((size_t)oc*CC_ + ic)*9 + t]);
    }
}

// K1d: pack pw2 weights (256 x 512) into B-frag order: Bpw[kk][nt][lane][j].
__global__ void k_bprep_pw(const float* __restrict__ w, bf16* __restrict__ Bpw){
    int id = blockIdx.x;               // 16*16 = 256
    int kk = id >> 4, nt = id & 15;
    int L = threadIdx.x;               // 64
    int oc = nt*16 + (L&15);
    bf16* out = Bpw + (((size_t)(kk*16+nt))*64 + L)*8;
    #pragma unroll
    for (int j = 0; j < 8; ++j){
        int ic = kk*32 + (L>>4)*8 + j;
        out[j] = f2b(w[(size_t)oc*512 + ic]);
    }
}

// K2: conv3x3 256->64 via MFMA implicit GEMM. Block=(b,y), 4 waves = m-tiles x0 {0,16,32,40}.
__global__ __launch_bounds__(256) void k_conv1(const bf16* __restrict__ Fp, const bf16* __restrict__ Bp,
                                               const float* __restrict__ bias, bf16* __restrict__ hout){
    int bx = blockIdx.x; int b = bx / HH, y = bx % HH;
    int tid = threadIdx.x; int wave = tid>>6, lane = tid&63;
    int m = lane&15, q = lane>>4;
    int x0 = (wave==3) ? 40 : wave*16;
    f32x4 acc0 = {0,0,0,0}, acc1 = {0,0,0,0}, acc2 = {0,0,0,0}, acc3 = {0,0,0,0};
    const bf16* Fb = Fp + ((size_t)b*58*58)*256;
    #pragma unroll
    for (int t = 0; t < 9; ++t){
        int ty = t/3, tx = t%3;
        const bf16* arow = Fb + ((size_t)(y+ty)*58 + (x0+m+tx))*256 + q*8;
        const bf16* brow = Bp + ((size_t)t*8)*4*64*8 + lane*8;
        #pragma unroll
        for (int icc = 0; icc < 8; ++icc){
            short8 a  = *(const short8*)(arow + icc*32);
            const bf16* bb = brow + (size_t)icc*4*64*8;
            short8 b0 = *(const short8*)(bb);
            short8 b1 = *(const short8*)(bb + 64*8);
            short8 b2 = *(const short8*)(bb + 2*64*8);
            short8 b3 = *(const short8*)(bb + 3*64*8);
            acc0 = __builtin_amdgcn_mfma_f32_16x16x32_bf16(a, b0, acc0, 0, 0, 0);
            acc1 = __builtin_amdgcn_mfma_f32_16x16x32_bf16(a, b1, acc1, 0, 0, 0);
            acc2 = __builtin_amdgcn_mfma_f32_16x16x32_bf16(a, b2, acc2, 0, 0, 0);
            acc3 = __builtin_amdgcn_mfma_f32_16x16x32_bf16(a, b3, acc3, 0, 0, 0);
        }
    }
    f32x4 accs[4] = {acc0, acc1, acc2, acc3};
    #pragma unroll
    for (int nt = 0; nt < 4; ++nt){
        int oc = nt*16 + m;
        float bv = bias[oc];
        #pragma unroll
        for (int r2 = 0; r2 < 4; ++r2){
            int x = x0 + q*4 + r2;
            hout[((size_t)b*HID + oc)*HWSZ + y*WW + x] = f2b(fmaxf(accs[nt][r2] + bv, 0.f));
        }
    }
}

// K3: conv3x3 64 -> 18, pad 1, + bias. Thread per output.
__global__ void k_conv2(const bf16* __restrict__ h, const float* __restrict__ wgt,
                        const float* __restrict__ bias, float* __restrict__ p){
    int n = blockIdx.x*256 + threadIdx.x;
    if (n >= BB*18*HWSZ) return;
    int b = n / (18*HWSZ); int rr = n % (18*HWSZ); int oc = rr / HWSZ;
    int yx = rr % HWSZ; int y = yx / WW, x = yx % WW;
    float acc = bias[oc];
    const bf16* hb = h + (size_t)b*HID*HWSZ;
    const float* wp = wgt + (size_t)oc*HID*9;
    for (int ic = 0; ic < HID; ++ic){
        const bf16* hc = hb + (size_t)ic*HWSZ;
        #pragma unroll
        for (int ky=0;ky<3;++ky){
            int gy = y+ky-1; if ((unsigned)gy >= HH) continue;
            #pragma unroll
            for (int kx=0;kx<3;++kx){
                int gx = x+kx-1; if ((unsigned)gx >= WW) continue;
                acc += b2f(hc[gy*WW+gx]) * wp[ic*9+ky*3+kx];
            }
        }
    }
    p[n] = acc;
}

// K4a: 8x8 avg pool (56->7) on F_i = F*sc_i, depthwise 3x3 + relu, global mean -> s[b,c].
__global__ void k_akg_pool(const float* __restrict__ Fc, const float* __restrict__ sc_i,
                           const float* __restrict__ dw, float* __restrict__ s){
    int bc = blockIdx.x; int b = bc / CC_; int c = bc % CC_;
    int l = threadIdx.x; // 64
    __shared__ float sm[49];
    __shared__ float red[64];
    const float* fb = Fc + (size_t)bc*HWSZ;
    const float* si = sc_i + (size_t)b*HWSZ;
    if (l < 49){
        int u = l/7, v = l%7;
        float sum = 0.f;
        for (int r=0;r<8;++r){
            const float* rp = fb + (u*8+r)*WW + v*8;
            const float* sp = si + (u*8+r)*WW + v*8;
            #pragma unroll
            for (int q=0;q<8;++q) sum += rp[q] * sp[q];
        }
        sm[l] = sum * (1.f/64.f);
    }
    __syncthreads();
    float rv = 0.f;
    if (l < 49){
        float w[9];
        #pragma unroll
        for (int k=0;k<9;++k) w[k] = dw[c*9+k];
        int u=l/7, v=l%7; float acc=0.f;
        #pragma unroll
        for (int ky=0;ky<3;++ky){ int uu=u+ky-1; if((unsigned)uu>=7u) continue;
            #pragma unroll
            for (int kx=0;kx<3;++kx){ int vv=v+kx-1; if((unsigned)vv>=7u) continue;
                acc += sm[uu*7+vv]*w[ky*3+kx]; } }
        rv = fmaxf(acc, 0.f);
    }
    red[l] = rv;
    __syncthreads();
    if (l==0){ float t=0.f; for(int i2=0;i2<64;++i2) t+=red[i2]; s[bc] = t*(1.f/49.f); }
}

// K4b: head matvec + tanh -> Kw stored [b][t][c].
__global__ void k_akg_head(const float* __restrict__ s, const float* __restrict__ hw,
                           const float* __restrict__ hb, float* __restrict__ Kw){
    int b = blockIdx.x / 9; int og = blockIdx.x % 9;
    __shared__ float sv[CC_];
    int tid = threadIdx.x; // 256
    sv[tid] = s[b*CC_ + tid];
    __syncthreads();
    int o = og*256 + tid;              // o = c*9 + t
    const float* wp = hw + (size_t)o*CC_;
    float acc = hb[o];
    for (int c2=0;c2<CC_;++c2) acc += wp[c2]*sv[c2];
    int c = o / 9, t = o - 9*c;
    Kw[(size_t)b*2304 + t*256 + c] = tanhf(acc);
}

// K5: deformable depthwise on Fp, restructured for cache locality + occupancy:
//  - t outer / channels inner: each lane streams 32 consecutive channels per corner once
//  - 512-thread blocks (8 waves): 56 xl x 8 cs-slices of 32 ch
//  - b = blockIdx&7: round-robin XCD placement pins each batch's 1.7MB Fp slab to one XCD's L2
__global__ __launch_bounds__(512) void k_deform(const bf16* __restrict__ Fp_r, const float* __restrict__ p,
                                                const float* __restrict__ Kw, bf16* __restrict__ outsN, int creg){
    __shared__ int   so[504][4];
    __shared__ float swt[504][4];
    int bx = blockIdx.x; int b = bx & 7, y = bx >> 3;
    int tid = threadIdx.x;
    if (tid < 504){
        int e = tid;
        int t = e / 56, x = e % 56;
        int ky = t / 3, kx = t % 3;
        float dy = p[((size_t)b*18 + 2*t  )*HWSZ + y*WW + x];
        float dx = p[((size_t)b*18 + 2*t+1)*HWSZ + y*WW + x];
        float py = (float)(y - 1 + ky) + dy;
        float px = (float)(x - 1 + kx) + dx;
        float y0f = floorf(py), x0f = floorf(px);
        float wy1 = py - y0f, wx1 = px - x0f;
        float wy0 = 1.f - wy1, wx0 = 1.f - wx1;
        float vy0 = (y0f >= 0.f  && y0f <= 55.f) ? 1.f : 0.f;
        float vy1 = (y0f >= -1.f && y0f <= 54.f) ? 1.f : 0.f;
        float vx0 = (x0f >= 0.f  && x0f <= 55.f) ? 1.f : 0.f;
        float vx1 = (x0f >= -1.f && x0f <= 54.f) ? 1.f : 0.f;
        int y0 = (int)y0f, x0 = (int)x0f;
        int iy0 = min(max(y0,0),55),   iy1 = min(max(y0+1,0),55);
        int ix0 = min(max(x0,0),55),   ix1 = min(max(x0+1,0),55);
        so[e][0] = ((iy0+1)*58 + ix0+1)*256;
        so[e][1] = ((iy0+1)*58 + ix1+1)*256;
        so[e][2] = ((iy1+1)*58 + ix0+1)*256;
        so[e][3] = ((iy1+1)*58 + ix1+1)*256;
        swt[e][0] = wy0*wx0*vy0*vx0;
        swt[e][1] = wy0*wx1*vy0*vx1;
        swt[e][2] = wy1*wx0*vy1*vx0;
        swt[e][3] = wy1*wx1*vy1*vx1;
    }
    __syncthreads();
    if (tid >= 448) return;
    int xl = tid % 56, cs = tid / 56; // cs 0..7, 32 channels each
    int c0 = cs*32;
    const bf16* Fb = Fp_r + (size_t)b*58*58*256;
    const float* Kb = Kw + (size_t)b*2304;
    float acc[32];
    #pragma unroll
    for (int j=0;j<32;++j) acc[j]=0.f;
    #pragma unroll 1
    for (int t=0;t<9;++t){
        int e = t*56+xl;
        int o00=so[e][0], o01=so[e][1], o10=so[e][2], o11=so[e][3];
        float w00=swt[e][0], w01=swt[e][1], w10=swt[e][2], w11=swt[e][3];
        const float* Kt = Kb + t*256 + c0;
        #pragma unroll
        for (int g=0; g<2; ++g){
            int cg = c0 + g*16;
            short8 a00 = *(const short8*)(Fb + o00 + cg);
            short8 a01 = *(const short8*)(Fb + o00 + cg + 8);
            short8 b00 = *(const short8*)(Fb + o01 + cg);
            short8 b01 = *(const short8*)(Fb + o01 + cg + 8);
            short8 c00 = *(const short8*)(Fb + o10 + cg);
            short8 c01 = *(const short8*)(Fb + o10 + cg + 8);
            short8 d00 = *(const short8*)(Fb + o11 + cg);
            short8 d01 = *(const short8*)(Fb + o11 + cg + 8);
            #pragma unroll
            for (int j=0;j<8;++j){
                float v = w00*bs2f(a00[j]) + w01*bs2f(b00[j]) + w10*bs2f(c00[j]) + w11*bs2f(d00[j]);
                acc[g*16+j] += Kt[g*16+j]*v;
            }
            #pragma unroll
            for (int j=0;j<8;++j){
                float v = w00*bs2f(a01[j]) + w01*bs2f(b01[j]) + w10*bs2f(c01[j]) + w11*bs2f(d01[j]);
                acc[g*16+8+j] += Kt[g*16+8+j]*v;
            }
        }
    }
    bf16* orow = outsN + ((size_t)b*HWSZ + y*WW + xl)*512 + creg*256 + c0;
    #pragma unroll
    for (int g=0; g<4; ++g){
        __attribute__((aligned(16))) bf16 tmp[8];
        #pragma unroll
        for (int j=0;j<8;++j) tmp[j] = f2b(acc[g*8+j]);
        *(short8*)(orow + g*8) = *(const short8*)tmp;
    }
}

// K6a: pw2 MFMA GEMM (M=25088,N=256,K=512), stats pass: per-block per-oc sum/sumsq partials.
__global__ __launch_bounds__(256) void k_pw2_mstats(const bf16* __restrict__ outsN, const bf16* __restrict__ Bpw,
                                                    const float* __restrict__ bias, float* __restrict__ partials){
    __shared__ float ls[2][2][256];
    int tid = threadIdx.x; int wave = tid>>6, lane = tid&63;
    int pixGroup = wave>>1, ntH = wave&1;
    int m = lane&15, q = lane>>4;
    size_t pb = (size_t)blockIdx.x*32 + pixGroup*16;
    const bf16* Ap = outsN + (pb + m)*512 + q*8;
    f32x4 acc[8];
    #pragma unroll
    for (int i=0;i<8;++i) acc[i] = (f32x4){0,0,0,0};
    #pragma unroll 1
    for (int kk = 0; kk < 16; ++kk){
        short8 a = *(const short8*)(Ap + kk*32);
        const bf16* Bk = Bpw + (((size_t)kk*16 + ntH*8)*64 + lane)*8;
        #pragma unroll
        for (int nt2 = 0; nt2 < 8; ++nt2){
            short8 b = *(const short8*)(Bk + (size_t)nt2*64*8);
            acc[nt2] = __builtin_amdgcn_mfma_f32_16x16x32_bf16(a, b, acc[nt2], 0, 0, 0);
        }
    }
    #pragma unroll
    for (int nt2 = 0; nt2 < 8; ++nt2){
        int oc = ntH*128 + nt2*16 + m;
        float bv = bias[oc];
        float s1 = 0.f, s2 = 0.f;
        #pragma unroll
        for (int r = 0; r < 4; ++r){ float v = acc[nt2][r] + bv; s1 += v; s2 += v*v; }
        s1 += __shfl_down(s1, 32); s1 += __shfl_down(s1, 16);
        s2 += __shfl_down(s2, 32); s2 += __shfl_down(s2, 16);
        if (q == 0){ ls[pixGroup][0][oc] = s1; ls[pixGroup][1][oc] = s2; }
    }
    __syncthreads();
    if (tid < 256){
        partials[(size_t)blockIdx.x*512 + tid]       = ls[0][0][tid] + ls[1][0][tid];
        partials[(size_t)blockIdx.x*512 + 256 + tid] = ls[0][1][tid] + ls[1][1][tid];
    }
}

// K6b: reduce partials -> bnp (mean, rsqrt).
__global__ void k_bnstat2(const float* __restrict__ partials, float* __restrict__ bnp){
    __shared__ float sm[512];
    int tid = threadIdx.x;           // 512
    float acc = 0.f;
    for (int blk = 0; blk < 784; ++blk) acc += partials[(size_t)blk*512 + tid];
    sm[tid] = acc;
    __syncthreads();
    if (tid < 256){
        float n = (float)NPIX;
        float mean = sm[tid] / n;
        float var = sm[256+tid] / n - mean*mean;
        var = fmaxf(var, 0.f);
        bnp[tid] = mean; bnp[256+tid] = rsqrtf(var + 1e-5f);
    }
}

// K6c: pw2 MFMA GEMM apply pass: recompute + BN, write fp32 NCHW out.
__global__ __launch_bounds__(256) void k_pw2_mapply(const bf16* __restrict__ outsN, const bf16* __restrict__ Bpw,
                                                    const float* __restrict__ bias, const float* __restrict__ bnp,
                                                    const float* __restrict__ gamma, const float* __restrict__ beta,
                                                    float* __restrict__ out){
    int tid = threadIdx.x; int wave = tid>>6, lane = tid&63;
    int pixGroup = wave>>1, ntH = wave&1;
    int m = lane&15, q = lane>>4;
    size_t pb = (size_t)blockIdx.x*32 + pixGroup*16;
    const bf16* Ap = outsN + (pb + m)*512 + q*8;
    f32x4 acc[8];
    #pragma unroll
    for (int i=0;i<8;++i) acc[i] = (f32x4){0,0,0,0};
    #pragma unroll 1
    for (int kk = 0; kk < 16; ++kk){
        short8 a = *(const short8*)(Ap + kk*32);
        const bf16* Bk = Bpw + (((size_t)kk*16 + ntH*8)*64 + lane)*8;
        #pragma unroll
        for (int nt2 = 0; nt2 < 8; ++nt2){
            short8 b = *(const short8*)(Bk + (size_t)nt2*64*8);
            acc[nt2] = __builtin_amdgcn_mfma_f32_16x16x32_bf16(a, b, acc[nt2], 0, 0, 0);
        }
    }
    int b_idx = (int)(pb / HWSZ);
    int yx0 = (int)(pb % HWSZ);
    #pragma unroll
    for (int nt2 = 0; nt2 < 8; ++nt2){
        int oc = ntH*128 + nt2*16 + m;
        float bv = bias[oc];
        float mean = bnp[oc], rsq = bnp[256+oc];
        float g = gamma[oc], be = beta[oc];
        float* op = out + ((size_t)b_idx*CC_ + oc)*HWSZ + yx0 + q*4;
        #pragma unroll
        for (int r = 0; r < 4; ++r){
            float v = acc[nt2][r] + bv;
            op[r] = (v - mean)*rsq*g + be;
        }
    }
}

extern "C" void kernel_launch(void* const* d_in, const int* in_sizes, int n_in,
                              void* d_out, int out_size, void* d_ws, size_t ws_size,
                              hipStream_t stream) {
    (void)in_sizes; (void)n_in; (void)out_size; (void)ws_size;
    const float* F_c    = (const float*)d_in[0];
    const float* dec_w  = (const float*)d_in[1];
    const float* dec_b  = (const float*)d_in[2];
    const float* off1_w = (const float*)d_in[3];
    const float* off1_b = (const float*)d_in[4];
    const float* off2_w = (const float*)d_in[5];
    const float* off2_b = (const float*)d_in[6];
    const float* akg_dw = (const float*)d_in[7];
    const float* akg_hw = (const float*)d_in[8];
    const float* akg_hb = (const float*)d_in[9];
    const float* pw2_w  = (const float*)d_in[10];
    const float* pw2_b  = (const float*)d_in[11];
    const float* gamma  = (const float*)d_in[12];
    const float* beta   = (const float*)d_in[13];
    float* out = (float*)d_out;

    char* ws = (char*)d_ws;
    size_t off = 0;
    auto alloc = [&](size_t bytes)->char*{
        char* r = ws + off;
        off = (off + bytes + 255) & ~(size_t)255;
        return r;
    };
    // Workspace ~61 MB.
    bf16*  Fp    = (bf16*) alloc(2*FPR*2);                 // padded NHWC F*sc, both regions
    bf16*  Bp    = (bf16*) alloc((size_t)2*9*8*4*64*8*2);  // conv1 weight frags
    bf16*  Bpw   = (bf16*) alloc((size_t)16*16*64*8*2);    // pw2 weight frags
    float* sc    = (float*)alloc((size_t)2*BB*HWSZ*4);
    bf16*  h     = (bf16*) alloc((size_t)BB*HID*HWSZ*2);
    float* p     = (float*)alloc((size_t)BB*18*HWSZ*4);
    float* s     = (float*)alloc((size_t)BB*CC_*4);
    float* Kw    = (float*)alloc((size_t)BB*CC_*9*4);
    bf16*  outsN = (bf16*) alloc(NPIX*512*2);              // NHWC, k = creg*256+c
    float* partials = (float*)alloc((size_t)784*512*4);
    float* bnp   = (float*)alloc(2*CC_*4);

    hipMemsetAsync(Fp, 0, 2*FPR*2, stream);                // zero borders for pad

    k_scales<<<dim3((BB*HWSZ)/64), dim3(64), 0, stream>>>(F_c, dec_w, dec_b, sc);
    k_pack<<<dim3(BB*HH), dim3(256), 0, stream>>>(F_c, sc, Fp);
    k_bprep<<<dim3(576), dim3(64), 0, stream>>>(off1_w, Bp);
    k_bprep_pw<<<dim3(256), dim3(64), 0, stream>>>(pw2_w, Bpw);

    for (int i = 0; i < RR_; ++i){
        const float* sc_i = sc + (size_t)i*BB*HWSZ;
        const bf16* Fp_i = Fp + (size_t)i*FPR;
        k_conv1<<<dim3(BB*HH), dim3(256), 0, stream>>>(
            Fp_i, Bp + (size_t)i*9*8*4*64*8, off1_b + i*HID, h);
        k_conv2<<<dim3((BB*18*HWSZ + 255)/256), dim3(256), 0, stream>>>(
            h, off2_w + (size_t)i*18*HID*9, off2_b + i*18, p);
        k_akg_pool<<<dim3(BB*CC_), dim3(64), 0, stream>>>(
            F_c, sc_i, akg_dw + (size_t)i*CC_*9, s);
        k_akg_head<<<dim3(BB*9), dim3(256), 0, stream>>>(
            s, akg_hw + (size_t)i*2304*CC_, akg_hb + (size_t)i*2304, Kw);
        k_deform<<<dim3(BB*HH), dim3(512), 0, stream>>>(Fp_i, p, Kw, outsN, i);
    }

    k_pw2_mstats<<<dim3(784), dim3(256), 0, stream>>>(outsN, Bpw, pw2_b, partials);
    k_bnstat2<<<dim3(1), dim3(512), 0, stream>>>(partials, bnp);
    k_pw2_mapply<<<dim3(784), dim3(256), 0, stream>>>(outsN, Bpw, pw2_b, bnp, gamma, beta, out);
}

// Round 9
// 473.280 us; speedup vs baseline: 3.5598x; 1.4179x over previous
//
#include <hip/hip_runtime.h>
#include <hip/hip_bf16.h>

#define BB 8
#define CC_ 256
#define HH 56
#define WW 56
#define HWSZ (HH*WW)
#define RR_ 2
#define HID 64
#define FPR ((size_t)8*58*58*256)   // padded NHWC region elements
#define HPR ((size_t)8*58*58*64)    // padded NHWC hidden elements
#define NPIX ((size_t)BB*HWSZ)      // 25088

typedef __hip_bfloat16 bf16;
typedef __attribute__((ext_vector_type(8))) short short8;
typedef __attribute__((ext_vector_type(4))) float f32x4;

__device__ __forceinline__ float b2f(bf16 v){ return __bfloat162float(v); }
__device__ __forceinline__ bf16 f2b(float v){ return __float2bfloat16(v); }
__device__ __forceinline__ float bs2f(short s){ return __uint_as_float(((unsigned)(unsigned short)s)<<16); }

// K1: decoupler 1x1 conv + softmax(R=2); writes scale factors sc[r][b][yx] = 1 + M_r.
__global__ void k_scales(const float* __restrict__ F, const float* __restrict__ dec_w,
                         const float* __restrict__ dec_b, float* __restrict__ sc){
    __shared__ float w0[CC_], w1[CC_];
    int tid = threadIdx.x; // 64
    for (int c = tid; c < CC_; c += 64){ w0[c] = dec_w[c]; w1[c] = dec_w[CC_+c]; }
    __syncthreads();
    int pid = blockIdx.x*64 + tid;
    int b = pid / HWSZ, yx = pid % HWSZ;
    const float* base = F + (size_t)b*CC_*HWSZ + yx;
    float a0 = dec_b[0], a1 = dec_b[1];
    for (int c = 0; c < CC_; ++c){ float v = base[(size_t)c*HWSZ]; a0 += v*w0[c]; a1 += v*w1[c]; }
    float m = fmaxf(a0,a1);
    float e0 = __expf(a0-m), e1 = __expf(a1-m);
    float inv = 1.0f/(e0+e1);
    sc[pid]                  = 1.0f + e0*inv;
    sc[(size_t)BB*HWSZ+pid]  = 1.0f + e1*inv;
}

// K1b: pack Fp[r][b][gy+1][gx+1][c] = bf16(F[b][c][gy][gx] * sc_r). Borders pre-zeroed by memset.
__global__ __launch_bounds__(256) void k_pack(const float* __restrict__ F, const float* __restrict__ sc,
                                              bf16* __restrict__ Fp){
    __shared__ bf16 lds[2][56][258];
    int bx = blockIdx.x; int b = bx/HH, gy = bx%HH;
    int tid = threadIdx.x; int x = tid & 63; int cq = tid >> 6;
    if (x < 56){
        const float* frow = F + (size_t)b*CC_*HWSZ + gy*WW + x;
        float s0 = sc[(size_t)b*HWSZ + gy*WW + x];
        float s1 = sc[(size_t)BB*HWSZ + (size_t)b*HWSZ + gy*WW + x];
        for (int cc = 0; cc < 64; ++cc){
            int c = cc*4 + cq;
            float v = frow[(size_t)c*HWSZ];
            lds[0][x][c] = f2b(v*s0);
            lds[1][x][c] = f2b(v*s1);
        }
    }
    __syncthreads();
    for (int r = 0; r < 2; ++r){
        bf16* dst = Fp + (size_t)r*FPR + (((size_t)b*58 + gy+1)*58 + 1)*256 + tid;
        for (int x2 = 0; x2 < 56; ++x2) dst[(size_t)x2*256] = lds[r][x2][tid];
    }
}

// K1c: pack conv1 weights into MFMA B-fragment order.
__global__ void k_bprep(const float* __restrict__ w, bf16* __restrict__ Bp){
    int id = blockIdx.x;               // 2*9*8*4 = 576
    int nt = id & 3; id >>= 2; int icc = id & 7; id >>= 3; int t = id % 9; int r = id / 9;
    int L = threadIdx.x;               // 64
    int oc = nt*16 + (L&15);
    const float* wr = w + (size_t)r*HID*CC_*9;
    bf16* out = Bp + (((((size_t)r*9 + t)*8 + icc)*4 + nt)*64 + L)*8;
    #pragma unroll
    for (int j = 0; j < 8; ++j){
        int ic = icc*32 + (L>>4)*8 + j;
        out[j] = f2b(wr[((size_t)oc*CC_ + ic)*9 + t]);
    }
}

// K1d: pack pw2 weights (256 x 512) into B-frag order: Bpw[kk][nt][lane][j].
__global__ void k_bprep_pw(const float* __restrict__ w, bf16* __restrict__ Bpw){
    int id = blockIdx.x;               // 16*16 = 256
    int kk = id >> 4, nt = id & 15;
    int L = threadIdx.x;               // 64
    int oc = nt*16 + (L&15);
    bf16* out = Bpw + (((size_t)(kk*16+nt))*64 + L)*8;
    #pragma unroll
    for (int j = 0; j < 8; ++j){
        int ic = kk*32 + (L>>4)*8 + j;
        out[j] = f2b(w[(size_t)oc*512 + ic]);
    }
}

// K1e: pack conv2 weights (18 x 64 x 3 x 3) into B-frag order, zero-padded to N=32.
// Bc[r][ks=t*2+chunk][nt(2)][lane][j]; oc = nt*16+(lane&15), ic = chunk*32+(lane>>4)*8+j.
__global__ void k_bprep_c2(const float* __restrict__ w, bf16* __restrict__ Bc){
    int id = blockIdx.x;               // 2*18*2 = 72
    int nt = id & 1; id >>= 1; int ks = id % 18; int r = id / 18;
    int t = ks >> 1, chunk = ks & 1;
    int L = threadIdx.x;               // 64
    int oc = nt*16 + (L&15);
    const float* wr = w + (size_t)r*18*HID*9;
    bf16* out = Bc + ((((size_t)r*18 + ks)*2 + nt)*64 + L)*8;
    #pragma unroll
    for (int j = 0; j < 8; ++j){
        int ic = chunk*32 + (L>>4)*8 + j;
        out[j] = (oc < 18) ? f2b(wr[((size_t)oc*HID + ic)*9 + t]) : f2b(0.f);
    }
}

// K2: conv3x3 256->64 via MFMA implicit GEMM. Block=(b,y), 4 waves = m-tiles x0 {0,16,32,40}.
// Writes h into zero-padded NHWC hp[b][y+1][x+1][64].
__global__ __launch_bounds__(256) void k_conv1(const bf16* __restrict__ Fp, const bf16* __restrict__ Bp,
                                               const float* __restrict__ bias, bf16* __restrict__ hp){
    int bx = blockIdx.x; int b = bx / HH, y = bx % HH;
    int tid = threadIdx.x; int wave = tid>>6, lane = tid&63;
    int m = lane&15, q = lane>>4;
    int x0 = (wave==3) ? 40 : wave*16;
    f32x4 acc0 = {0,0,0,0}, acc1 = {0,0,0,0}, acc2 = {0,0,0,0}, acc3 = {0,0,0,0};
    const bf16* Fb = Fp + ((size_t)b*58*58)*256;
    #pragma unroll
    for (int t = 0; t < 9; ++t){
        int ty = t/3, tx = t%3;
        const bf16* arow = Fb + ((size_t)(y+ty)*58 + (x0+m+tx))*256 + q*8;
        const bf16* brow = Bp + ((size_t)t*8)*4*64*8 + lane*8;
        #pragma unroll
        for (int icc = 0; icc < 8; ++icc){
            short8 a  = *(const short8*)(arow + icc*32);
            const bf16* bb = brow + (size_t)icc*4*64*8;
            short8 b0 = *(const short8*)(bb);
            short8 b1 = *(const short8*)(bb + 64*8);
            short8 b2 = *(const short8*)(bb + 2*64*8);
            short8 b3 = *(const short8*)(bb + 3*64*8);
            acc0 = __builtin_amdgcn_mfma_f32_16x16x32_bf16(a, b0, acc0, 0, 0, 0);
            acc1 = __builtin_amdgcn_mfma_f32_16x16x32_bf16(a, b1, acc1, 0, 0, 0);
            acc2 = __builtin_amdgcn_mfma_f32_16x16x32_bf16(a, b2, acc2, 0, 0, 0);
            acc3 = __builtin_amdgcn_mfma_f32_16x16x32_bf16(a, b3, acc3, 0, 0, 0);
        }
    }
    f32x4 accs[4] = {acc0, acc1, acc2, acc3};
    bf16* hrow = hp + (((size_t)b*58 + y+1)*58 + 1)*64;
    #pragma unroll
    for (int nt = 0; nt < 4; ++nt){
        int oc = nt*16 + m;
        float bv = bias[oc];
        #pragma unroll
        for (int r2 = 0; r2 < 4; ++r2){
            int x = x0 + q*4 + r2;
            hrow[(size_t)x*64 + oc] = f2b(fmaxf(accs[nt][r2] + bv, 0.f));
        }
    }
}

// K3: conv2 via MFMA implicit GEMM on padded NHWC hp. M=pixels, N=18(->32), K=576.
__global__ __launch_bounds__(256) void k_conv2m(const bf16* __restrict__ hp, const bf16* __restrict__ Bc,
                                                const float* __restrict__ bias, float* __restrict__ p){
    int bx = blockIdx.x; int b = bx / HH, y = bx % HH;
    int tid = threadIdx.x; int wave = tid>>6, lane = tid&63;
    int m = lane&15, q = lane>>4;
    int x0 = (wave==3) ? 40 : wave*16;
    f32x4 acc0 = {0,0,0,0}, acc1 = {0,0,0,0};
    const bf16* Hb = hp + ((size_t)b*58 + y)*58*64;
    #pragma unroll
    for (int t = 0; t < 9; ++t){
        int ty = t/3, tx = t%3;
        const bf16* arow = Hb + ((size_t)ty*58 + (x0+m+tx))*64 + q*8;
        #pragma unroll
        for (int chunk = 0; chunk < 2; ++chunk){
            short8 a = *(const short8*)(arow + chunk*32);
            const bf16* bb = Bc + (((size_t)(t*2+chunk))*2*64 + lane)*8;
            short8 b0 = *(const short8*)(bb);
            short8 b1 = *(const short8*)(bb + 64*8);
            acc0 = __builtin_amdgcn_mfma_f32_16x16x32_bf16(a, b0, acc0, 0, 0, 0);
            acc1 = __builtin_amdgcn_mfma_f32_16x16x32_bf16(a, b1, acc1, 0, 0, 0);
        }
    }
    #pragma unroll
    for (int r2 = 0; r2 < 4; ++r2){
        int x = x0 + q*4 + r2;
        {   // n-tile 0: oc = m (0..15)
            float v = acc0[r2] + bias[m];
            p[((size_t)b*18 + m)*HWSZ + y*WW + x] = v;
        }
        if (m < 2){ // n-tile 1: oc = 16+m
            float v = acc1[r2] + bias[16+m];
            p[((size_t)b*18 + 16+m)*HWSZ + y*WW + x] = v;
        }
    }
}

// K4a: 8x8 avg pool (56->7) on F_i = F*sc_i, depthwise 3x3 + relu, global mean -> s[b,c].
__global__ void k_akg_pool(const float* __restrict__ Fc, const float* __restrict__ sc_i,
                           const float* __restrict__ dw, float* __restrict__ s){
    int bc = blockIdx.x; int b = bc / CC_; int c = bc % CC_;
    int l = threadIdx.x; // 64
    __shared__ float sm[49];
    __shared__ float red[64];
    const float* fb = Fc + (size_t)bc*HWSZ;
    const float* si = sc_i + (size_t)b*HWSZ;
    if (l < 49){
        int u = l/7, v = l%7;
        float sum = 0.f;
        for (int r=0;r<8;++r){
            const float* rp = fb + (u*8+r)*WW + v*8;
            const float* sp = si + (u*8+r)*WW + v*8;
            #pragma unroll
            for (int q=0;q<8;++q) sum += rp[q] * sp[q];
        }
        sm[l] = sum * (1.f/64.f);
    }
    __syncthreads();
    float rv = 0.f;
    if (l < 49){
        float w[9];
        #pragma unroll
        for (int k=0;k<9;++k) w[k] = dw[c*9+k];
        int u=l/7, v=l%7; float acc=0.f;
        #pragma unroll
        for (int ky=0;ky<3;++ky){ int uu=u+ky-1; if((unsigned)uu>=7u) continue;
            #pragma unroll
            for (int kx=0;kx<3;++kx){ int vv=v+kx-1; if((unsigned)vv>=7u) continue;
                acc += sm[uu*7+vv]*w[ky*3+kx]; } }
        rv = fmaxf(acc, 0.f);
    }
    red[l] = rv;
    __syncthreads();
    if (l==0){ float t=0.f; for(int i2=0;i2<64;++i2) t+=red[i2]; s[bc] = t*(1.f/49.f); }
}

// K4b: head matvec + tanh -> Kw stored [b][t][c].
__global__ void k_akg_head(const float* __restrict__ s, const float* __restrict__ hw,
                           const float* __restrict__ hb, float* __restrict__ Kw){
    int b = blockIdx.x / 9; int og = blockIdx.x % 9;
    __shared__ float sv[CC_];
    int tid = threadIdx.x; // 256
    sv[tid] = s[b*CC_ + tid];
    __syncthreads();
    int o = og*256 + tid;              // o = c*9 + t
    const float* wp = hw + (size_t)o*CC_;
    float acc = hb[o];
    for (int c2=0;c2<CC_;++c2) acc += wp[c2]*sv[c2];
    int c = o / 9, t = o - 9*c;
    Kw[(size_t)b*2304 + t*256 + c] = tanhf(acc);
}

// K5: deformable depthwise on Fp (t outer / channels inner, 512 thr, b=blockIdx&7 XCD pinning).
__global__ __launch_bounds__(512) void k_deform(const bf16* __restrict__ Fp_r, const float* __restrict__ p,
                                                const float* __restrict__ Kw, bf16* __restrict__ outsN, int creg){
    __shared__ int   so[504][4];
    __shared__ float swt[504][4];
    int bx = blockIdx.x; int b = bx & 7, y = bx >> 3;
    int tid = threadIdx.x;
    if (tid < 504){
        int e = tid;
        int t = e / 56, x = e % 56;
        int ky = t / 3, kx = t % 3;
        float dy = p[((size_t)b*18 + 2*t  )*HWSZ + y*WW + x];
        float dx = p[((size_t)b*18 + 2*t+1)*HWSZ + y*WW + x];
        float py = (float)(y - 1 + ky) + dy;
        float px = (float)(x - 1 + kx) + dx;
        float y0f = floorf(py), x0f = floorf(px);
        float wy1 = py - y0f, wx1 = px - x0f;
        float wy0 = 1.f - wy1, wx0 = 1.f - wx1;
        float vy0 = (y0f >= 0.f  && y0f <= 55.f) ? 1.f : 0.f;
        float vy1 = (y0f >= -1.f && y0f <= 54.f) ? 1.f : 0.f;
        float vx0 = (x0f >= 0.f  && x0f <= 55.f) ? 1.f : 0.f;
        float vx1 = (x0f >= -1.f && x0f <= 54.f) ? 1.f : 0.f;
        int y0 = (int)y0f, x0 = (int)x0f;
        int iy0 = min(max(y0,0),55),   iy1 = min(max(y0+1,0),55);
        int ix0 = min(max(x0,0),55),   ix1 = min(max(x0+1,0),55);
        so[e][0] = ((iy0+1)*58 + ix0+1)*256;
        so[e][1] = ((iy0+1)*58 + ix1+1)*256;
        so[e][2] = ((iy1+1)*58 + ix0+1)*256;
        so[e][3] = ((iy1+1)*58 + ix1+1)*256;
        swt[e][0] = wy0*wx0*vy0*vx0;
        swt[e][1] = wy0*wx1*vy0*vx1;
        swt[e][2] = wy1*wx0*vy1*vx0;
        swt[e][3] = wy1*wx1*vy1*vx1;
    }
    __syncthreads();
    if (tid >= 448) return;
    int xl = tid % 56, cs = tid / 56; // cs 0..7, 32 channels each
    int c0 = cs*32;
    const bf16* Fb = Fp_r + (size_t)b*58*58*256;
    const float* Kb = Kw + (size_t)b*2304;
    float acc[32];
    #pragma unroll
    for (int j=0;j<32;++j) acc[j]=0.f;
    #pragma unroll 1
    for (int t=0;t<9;++t){
        int e = t*56+xl;
        int o00=so[e][0], o01=so[e][1], o10=so[e][2], o11=so[e][3];
        float w00=swt[e][0], w01=swt[e][1], w10=swt[e][2], w11=swt[e][3];
        const float* Kt = Kb + t*256 + c0;
        #pragma unroll
        for (int g=0; g<2; ++g){
            int cg = c0 + g*16;
            short8 a00 = *(const short8*)(Fb + o00 + cg);
            short8 a01 = *(const short8*)(Fb + o00 + cg + 8);
            short8 b00 = *(const short8*)(Fb + o01 + cg);
            short8 b01 = *(const short8*)(Fb + o01 + cg + 8);
            short8 c00 = *(const short8*)(Fb + o10 + cg);
            short8 c01 = *(const short8*)(Fb + o10 + cg + 8);
            short8 d00 = *(const short8*)(Fb + o11 + cg);
            short8 d01 = *(const short8*)(Fb + o11 + cg + 8);
            #pragma unroll
            for (int j=0;j<8;++j){
                float v = w00*bs2f(a00[j]) + w01*bs2f(b00[j]) + w10*bs2f(c00[j]) + w11*bs2f(d00[j]);
                acc[g*16+j] += Kt[g*16+j]*v;
            }
            #pragma unroll
            for (int j=0;j<8;++j){
                float v = w00*bs2f(a01[j]) + w01*bs2f(b01[j]) + w10*bs2f(c01[j]) + w11*bs2f(d01[j]);
                acc[g*16+8+j] += Kt[g*16+8+j]*v;
            }
        }
    }
    bf16* orow = outsN + ((size_t)b*HWSZ + y*WW + xl)*512 + creg*256 + c0;
    #pragma unroll
    for (int g=0; g<4; ++g){
        __attribute__((aligned(16))) bf16 tmp[8];
        #pragma unroll
        for (int j=0;j<8;++j) tmp[j] = f2b(acc[g*8+j]);
        *(short8*)(orow + g*8) = *(const short8*)tmp;
    }
}

// K6a: pw2 MFMA GEMM (M=25088,N=256,K=512), stats pass: per-block per-oc sum/sumsq partials.
__global__ __launch_bounds__(256) void k_pw2_mstats(const bf16* __restrict__ outsN, const bf16* __restrict__ Bpw,
                                                    const float* __restrict__ bias, float* __restrict__ partials){
    __shared__ float ls[2][2][256];
    int tid = threadIdx.x; int wave = tid>>6, lane = tid&63;
    int pixGroup = wave>>1, ntH = wave&1;
    int m = lane&15, q = lane>>4;
    size_t pb = (size_t)blockIdx.x*32 + pixGroup*16;
    const bf16* Ap = outsN + (pb + m)*512 + q*8;
    f32x4 acc[8];
    #pragma unroll
    for (int i=0;i<8;++i) acc[i] = (f32x4){0,0,0,0};
    #pragma unroll 1
    for (int kk = 0; kk < 16; ++kk){
        short8 a = *(const short8*)(Ap + kk*32);
        const bf16* Bk = Bpw + (((size_t)kk*16 + ntH*8)*64 + lane)*8;
        #pragma unroll
        for (int nt2 = 0; nt2 < 8; ++nt2){
            short8 b = *(const short8*)(Bk + (size_t)nt2*64*8);
            acc[nt2] = __builtin_amdgcn_mfma_f32_16x16x32_bf16(a, b, acc[nt2], 0, 0, 0);
        }
    }
    #pragma unroll
    for (int nt2 = 0; nt2 < 8; ++nt2){
        int oc = ntH*128 + nt2*16 + m;
        float bv = bias[oc];
        float s1 = 0.f, s2 = 0.f;
        #pragma unroll
        for (int r = 0; r < 4; ++r){ float v = acc[nt2][r] + bv; s1 += v; s2 += v*v; }
        s1 += __shfl_down(s1, 32); s1 += __shfl_down(s1, 16);
        s2 += __shfl_down(s2, 32); s2 += __shfl_down(s2, 16);
        if (q == 0){ ls[pixGroup][0][oc] = s1; ls[pixGroup][1][oc] = s2; }
    }
    __syncthreads();
    if (tid < 256){
        partials[(size_t)blockIdx.x*512 + tid]       = ls[0][0][tid] + ls[1][0][tid];
        partials[(size_t)blockIdx.x*512 + 256 + tid] = ls[0][1][tid] + ls[1][1][tid];
    }
}

// K6b: reduce partials -> bnp (mean, rsqrt).
__global__ void k_bnstat2(const float* __restrict__ partials, float* __restrict__ bnp){
    __shared__ float sm[512];
    int tid = threadIdx.x;           // 512
    float acc = 0.f;
    for (int blk = 0; blk < 784; ++blk) acc += partials[(size_t)blk*512 + tid];
    sm[tid] = acc;
    __syncthreads();
    if (tid < 256){
        float n = (float)NPIX;
        float mean = sm[tid] / n;
        float var = sm[256+tid] / n - mean*mean;
        var = fmaxf(var, 0.f);
        bnp[tid] = mean; bnp[256+tid] = rsqrtf(var + 1e-5f);
    }
}

// K6c: pw2 MFMA GEMM apply pass: recompute + BN, write fp32 NCHW out.
__global__ __launch_bounds__(256) void k_pw2_mapply(const bf16* __restrict__ outsN, const bf16* __restrict__ Bpw,
                                                    const float* __restrict__ bias, const float* __restrict__ bnp,
                                                    const float* __restrict__ gamma, const float* __restrict__ beta,
                                                    float* __restrict__ out){
    int tid = threadIdx.x; int wave = tid>>6, lane = tid&63;
    int pixGroup = wave>>1, ntH = wave&1;
    int m = lane&15, q = lane>>4;
    size_t pb = (size_t)blockIdx.x*32 + pixGroup*16;
    const bf16* Ap = outsN + (pb + m)*512 + q*8;
    f32x4 acc[8];
    #pragma unroll
    for (int i=0;i<8;++i) acc[i] = (f32x4){0,0,0,0};
    #pragma unroll 1
    for (int kk = 0; kk < 16; ++kk){
        short8 a = *(const short8*)(Ap + kk*32);
        const bf16* Bk = Bpw + (((size_t)kk*16 + ntH*8)*64 + lane)*8;
        #pragma unroll
        for (int nt2 = 0; nt2 < 8; ++nt2){
            short8 b = *(const short8*)(Bk + (size_t)nt2*64*8);
            acc[nt2] = __builtin_amdgcn_mfma_f32_16x16x32_bf16(a, b, acc[nt2], 0, 0, 0);
        }
    }
    int b_idx = (int)(pb / HWSZ);
    int yx0 = (int)(pb % HWSZ);
    #pragma unroll
    for (int nt2 = 0; nt2 < 8; ++nt2){
        int oc = ntH*128 + nt2*16 + m;
        float bv = bias[oc];
        float mean = bnp[oc], rsq = bnp[256+oc];
        float g = gamma[oc], be = beta[oc];
        float* op = out + ((size_t)b_idx*CC_ + oc)*HWSZ + yx0 + q*4;
        #pragma unroll
        for (int r = 0; r < 4; ++r){
            float v = acc[nt2][r] + bv;
            op[r] = (v - mean)*rsq*g + be;
        }
    }
}

extern "C" void kernel_launch(void* const* d_in, const int* in_sizes, int n_in,
                              void* d_out, int out_size, void* d_ws, size_t ws_size,
                              hipStream_t stream) {
    (void)in_sizes; (void)n_in; (void)out_size; (void)ws_size;
    const float* F_c    = (const float*)d_in[0];
    const float* dec_w  = (const float*)d_in[1];
    const float* dec_b  = (const float*)d_in[2];
    const float* off1_w = (const float*)d_in[3];
    const float* off1_b = (const float*)d_in[4];
    const float* off2_w = (const float*)d_in[5];
    const float* off2_b = (const float*)d_in[6];
    const float* akg_dw = (const float*)d_in[7];
    const float* akg_hw = (const float*)d_in[8];
    const float* akg_hb = (const float*)d_in[9];
    const float* pw2_w  = (const float*)d_in[10];
    const float* pw2_b  = (const float*)d_in[11];
    const float* gamma  = (const float*)d_in[12];
    const float* beta   = (const float*)d_in[13];
    float* out = (float*)d_out;

    char* ws = (char*)d_ws;
    size_t off = 0;
    auto alloc = [&](size_t bytes)->char*{
        char* r = ws + off;
        off = (off + bytes + 255) & ~(size_t)255;
        return r;
    };
    // Workspace ~61 MB.
    bf16*  Fp    = (bf16*) alloc(2*FPR*2);                 // padded NHWC F*sc, both regions
    bf16*  Bp    = (bf16*) alloc((size_t)2*9*8*4*64*8*2);  // conv1 weight frags
    bf16*  Bpw   = (bf16*) alloc((size_t)16*16*64*8*2);    // pw2 weight frags
    bf16*  Bc    = (bf16*) alloc((size_t)2*18*2*64*8*2);   // conv2 weight frags
    float* sc    = (float*)alloc((size_t)2*BB*HWSZ*4);
    bf16*  hp    = (bf16*) alloc(HPR*2);                   // padded NHWC hidden
    float* p     = (float*)alloc((size_t)BB*18*HWSZ*4);
    float* s     = (float*)alloc((size_t)BB*CC_*4);
    float* Kw    = (float*)alloc((size_t)BB*CC_*9*4);
    bf16*  outsN = (bf16*) alloc(NPIX*512*2);              // NHWC, k = creg*256+c
    float* partials = (float*)alloc((size_t)784*512*4);
    float* bnp   = (float*)alloc(2*CC_*4);

    hipMemsetAsync(Fp, 0, 2*FPR*2, stream);                // zero borders for pad
    hipMemsetAsync(hp, 0, HPR*2, stream);                  // zero borders for conv2 pad

    k_scales<<<dim3((BB*HWSZ)/64), dim3(64), 0, stream>>>(F_c, dec_w, dec_b, sc);
    k_pack<<<dim3(BB*HH), dim3(256), 0, stream>>>(F_c, sc, Fp);
    k_bprep<<<dim3(576), dim3(64), 0, stream>>>(off1_w, Bp);
    k_bprep_pw<<<dim3(256), dim3(64), 0, stream>>>(pw2_w, Bpw);
    k_bprep_c2<<<dim3(72), dim3(64), 0, stream>>>(off2_w, Bc);

    for (int i = 0; i < RR_; ++i){
        const float* sc_i = sc + (size_t)i*BB*HWSZ;
        const bf16* Fp_i = Fp + (size_t)i*FPR;
        k_conv1<<<dim3(BB*HH), dim3(256), 0, stream>>>(
            Fp_i, Bp + (size_t)i*9*8*4*64*8, off1_b + i*HID, hp);
        k_conv2m<<<dim3(BB*HH), dim3(256), 0, stream>>>(
            hp, Bc + (size_t)i*18*2*64*8, off2_b + i*18, p);
        k_akg_pool<<<dim3(BB*CC_), dim3(64), 0, stream>>>(
            F_c, sc_i, akg_dw + (size_t)i*CC_*9, s);
        k_akg_head<<<dim3(BB*9), dim3(256), 0, stream>>>(
            s, akg_hw + (size_t)i*2304*CC_, akg_hb + (size_t)i*2304, Kw);
        k_deform<<<dim3(BB*HH), dim3(512), 0, stream>>>(Fp_i, p, Kw, outsN, i);
    }

    k_pw2_mstats<<<dim3(784), dim3(256), 0, stream>>>(outsN, Bpw, pw2_b, partials);
    k_bnstat2<<<dim3(1), dim3(512), 0, stream>>>(partials, bnp);
    k_pw2_mapply<<<dim3(784), dim3(256), 0, stream>>>(outsN, Bpw, pw2_b, bnp, gamma, beta, out);
}

// Round 10
// 452.547 us; speedup vs baseline: 3.7229x; 1.0458x over previous
//
#include <hip/hip_runtime.h>
#include <hip/hip_bf16.h>

#define BB 8
#define CC_ 256
#define HH 56
#define WW 56
#define HWSZ (HH*WW)
#define RR_ 2
#define HID 64
#define FPR ((size_t)8*58*58*256)   // padded NHWC region elements
#define HPR ((size_t)8*58*58*64)    // padded NHWC hidden elements (per region)
#define NPIX ((size_t)BB*HWSZ)      // 25088

typedef __hip_bfloat16 bf16;
typedef __attribute__((ext_vector_type(8))) short short8;
typedef __attribute__((ext_vector_type(4))) float f32x4;

__device__ __forceinline__ float b2f(bf16 v){ return __bfloat162float(v); }
__device__ __forceinline__ bf16 f2b(float v){ return __float2bfloat16(v); }
__device__ __forceinline__ float bs2f(short s){ return __uint_as_float(((unsigned)(unsigned short)s)<<16); }

// K1: decoupler 1x1 conv + softmax(R=2); writes scale factors sc[r][b][yx] = 1 + M_r.
__global__ void k_scales(const float* __restrict__ F, const float* __restrict__ dec_w,
                         const float* __restrict__ dec_b, float* __restrict__ sc){
    __shared__ float w0[CC_], w1[CC_];
    int tid = threadIdx.x; // 64
    for (int c = tid; c < CC_; c += 64){ w0[c] = dec_w[c]; w1[c] = dec_w[CC_+c]; }
    __syncthreads();
    int pid = blockIdx.x*64 + tid;
    int b = pid / HWSZ, yx = pid % HWSZ;
    const float* base = F + (size_t)b*CC_*HWSZ + yx;
    float a0 = dec_b[0], a1 = dec_b[1];
    for (int c = 0; c < CC_; ++c){ float v = base[(size_t)c*HWSZ]; a0 += v*w0[c]; a1 += v*w1[c]; }
    float m = fmaxf(a0,a1);
    float e0 = __expf(a0-m), e1 = __expf(a1-m);
    float inv = 1.0f/(e0+e1);
    sc[pid]                  = 1.0f + e0*inv;
    sc[(size_t)BB*HWSZ+pid]  = 1.0f + e1*inv;
}

// K1b: pack Fp[r][b][gy+1][gx+1][c] = bf16(F[b][c][gy][gx] * sc_r). Borders pre-zeroed by memset.
__global__ __launch_bounds__(256) void k_pack(const float* __restrict__ F, const float* __restrict__ sc,
                                              bf16* __restrict__ Fp){
    __shared__ bf16 lds[2][56][258];
    int bx = blockIdx.x; int b = bx/HH, gy = bx%HH;
    int tid = threadIdx.x; int x = tid & 63; int cq = tid >> 6;
    if (x < 56){
        const float* frow = F + (size_t)b*CC_*HWSZ + gy*WW + x;
        float s0 = sc[(size_t)b*HWSZ + gy*WW + x];
        float s1 = sc[(size_t)BB*HWSZ + (size_t)b*HWSZ + gy*WW + x];
        for (int cc = 0; cc < 64; ++cc){
            int c = cc*4 + cq;
            float v = frow[(size_t)c*HWSZ];
            lds[0][x][c] = f2b(v*s0);
            lds[1][x][c] = f2b(v*s1);
        }
    }
    __syncthreads();
    for (int r = 0; r < 2; ++r){
        bf16* dst = Fp + (size_t)r*FPR + (((size_t)b*58 + gy+1)*58 + 1)*256 + tid;
        for (int x2 = 0; x2 < 56; ++x2) dst[(size_t)x2*256] = lds[r][x2][tid];
    }
}

// K1c: pack conv1 weights into MFMA B-fragment order.
__global__ void k_bprep(const float* __restrict__ w, bf16* __restrict__ Bp){
    int id = blockIdx.x;               // 2*9*8*4 = 576
    int nt = id & 3; id >>= 2; int icc = id & 7; id >>= 3; int t = id % 9; int r = id / 9;
    int L = threadIdx.x;               // 64
    int oc = nt*16 + (L&15);
    const float* wr = w + (size_t)r*HID*CC_*9;
    bf16* out = Bp + (((((size_t)r*9 + t)*8 + icc)*4 + nt)*64 + L)*8;
    #pragma unroll
    for (int j = 0; j < 8; ++j){
        int ic = icc*32 + (L>>4)*8 + j;
        out[j] = f2b(wr[((size_t)oc*CC_ + ic)*9 + t]);
    }
}

// K1d: pack pw2 weights (256 x 512) into B-frag order: Bpw[kk][nt][lane][j].
__global__ void k_bprep_pw(const float* __restrict__ w, bf16* __restrict__ Bpw){
    int id = blockIdx.x;               // 16*16 = 256
    int kk = id >> 4, nt = id & 15;
    int L = threadIdx.x;               // 64
    int oc = nt*16 + (L&15);
    bf16* out = Bpw + (((size_t)(kk*16+nt))*64 + L)*8;
    #pragma unroll
    for (int j = 0; j < 8; ++j){
        int ic = kk*32 + (L>>4)*8 + j;
        out[j] = f2b(w[(size_t)oc*512 + ic]);
    }
}

// K1e: pack conv2 weights into B-frag order, zero-padded to N=32.
__global__ void k_bprep_c2(const float* __restrict__ w, bf16* __restrict__ Bc){
    int id = blockIdx.x;               // 2*18*2 = 72
    int nt = id & 1; id >>= 1; int ks = id % 18; int r = id / 18;
    int t = ks >> 1, chunk = ks & 1;
    int L = threadIdx.x;               // 64
    int oc = nt*16 + (L&15);
    const float* wr = w + (size_t)r*18*HID*9;
    bf16* out = Bc + ((((size_t)r*18 + ks)*2 + nt)*64 + L)*8;
    #pragma unroll
    for (int j = 0; j < 8; ++j){
        int ic = chunk*32 + (L>>4)*8 + j;
        out[j] = (oc < 18) ? f2b(wr[((size_t)oc*HID + ic)*9 + t]) : f2b(0.f);
    }
}

// K2: conv3x3 256->64 via MFMA implicit GEMM, fused over regions.
// Grid 896: b=bx&7, rid=bx>>3, y=rid%56, r=rid/56. 4 waves = m-tiles x0 {0,16,32,40}.
__global__ __launch_bounds__(256) void k_conv1(const bf16* __restrict__ Fp, const bf16* __restrict__ Bp,
                                               const float* __restrict__ bias, bf16* __restrict__ hp){
    int bx = blockIdx.x; int b = bx & 7; int rid = bx >> 3; int y = rid % 56; int r = rid / 56;
    int tid = threadIdx.x; int wave = tid>>6, lane = tid&63;
    int m = lane&15, q = lane>>4;
    int x0 = (wave==3) ? 40 : wave*16;
    f32x4 acc0 = {0,0,0,0}, acc1 = {0,0,0,0}, acc2 = {0,0,0,0}, acc3 = {0,0,0,0};
    const bf16* Fb = Fp + (size_t)r*FPR + ((size_t)b*58*58)*256;
    const bf16* Bpr = Bp + (size_t)r*9*8*4*64*8;
    #pragma unroll
    for (int t = 0; t < 9; ++t){
        int ty = t/3, tx = t%3;
        const bf16* arow = Fb + ((size_t)(y+ty)*58 + (x0+m+tx))*256 + q*8;
        const bf16* brow = Bpr + ((size_t)t*8)*4*64*8 + lane*8;
        #pragma unroll
        for (int icc = 0; icc < 8; ++icc){
            short8 a  = *(const short8*)(arow + icc*32);
            const bf16* bb = brow + (size_t)icc*4*64*8;
            short8 b0 = *(const short8*)(bb);
            short8 b1 = *(const short8*)(bb + 64*8);
            short8 b2 = *(const short8*)(bb + 2*64*8);
            short8 b3 = *(const short8*)(bb + 3*64*8);
            acc0 = __builtin_amdgcn_mfma_f32_16x16x32_bf16(a, b0, acc0, 0, 0, 0);
            acc1 = __builtin_amdgcn_mfma_f32_16x16x32_bf16(a, b1, acc1, 0, 0, 0);
            acc2 = __builtin_amdgcn_mfma_f32_16x16x32_bf16(a, b2, acc2, 0, 0, 0);
            acc3 = __builtin_amdgcn_mfma_f32_16x16x32_bf16(a, b3, acc3, 0, 0, 0);
        }
    }
    f32x4 accs[4] = {acc0, acc1, acc2, acc3};
    const float* br = bias + r*HID;
    bf16* hrow = hp + (size_t)r*HPR + (((size_t)b*58 + y+1)*58 + 1)*64;
    #pragma unroll
    for (int nt = 0; nt < 4; ++nt){
        int oc = nt*16 + m;
        float bv = br[oc];
        #pragma unroll
        for (int r2 = 0; r2 < 4; ++r2){
            int x = x0 + q*4 + r2;
            hrow[(size_t)x*64 + oc] = f2b(fmaxf(accs[nt][r2] + bv, 0.f));
        }
    }
}

// K3: conv2 via MFMA implicit GEMM on padded NHWC hp, fused over regions. Grid 896.
__global__ __launch_bounds__(256) void k_conv2m(const bf16* __restrict__ hp, const bf16* __restrict__ Bc,
                                                const float* __restrict__ bias, float* __restrict__ p){
    int bx = blockIdx.x; int b = bx & 7; int rid = bx >> 3; int y = rid % 56; int r = rid / 56;
    int tid = threadIdx.x; int wave = tid>>6, lane = tid&63;
    int m = lane&15, q = lane>>4;
    int x0 = (wave==3) ? 40 : wave*16;
    f32x4 acc0 = {0,0,0,0}, acc1 = {0,0,0,0};
    const bf16* Hb = hp + (size_t)r*HPR + ((size_t)b*58 + y)*58*64;
    const bf16* Bcr = Bc + (size_t)r*18*2*64*8;
    #pragma unroll
    for (int t = 0; t < 9; ++t){
        int ty = t/3, tx = t%3;
        const bf16* arow = Hb + ((size_t)ty*58 + (x0+m+tx))*64 + q*8;
        #pragma unroll
        for (int chunk = 0; chunk < 2; ++chunk){
            short8 a = *(const short8*)(arow + chunk*32);
            const bf16* bb = Bcr + (((size_t)(t*2+chunk))*2*64 + lane)*8;
            short8 b0 = *(const short8*)(bb);
            short8 b1 = *(const short8*)(bb + 64*8);
            acc0 = __builtin_amdgcn_mfma_f32_16x16x32_bf16(a, b0, acc0, 0, 0, 0);
            acc1 = __builtin_amdgcn_mfma_f32_16x16x32_bf16(a, b1, acc1, 0, 0, 0);
        }
    }
    const float* br = bias + r*18;
    float* pr = p + (size_t)r*BB*18*HWSZ;
    #pragma unroll
    for (int r2 = 0; r2 < 4; ++r2){
        int x = x0 + q*4 + r2;
        {
            float v = acc0[r2] + br[m];
            pr[((size_t)b*18 + m)*HWSZ + y*WW + x] = v;
        }
        if (m < 2){
            float v = acc1[r2] + br[16+m];
            pr[((size_t)b*18 + 16+m)*HWSZ + y*WW + x] = v;
        }
    }
}

// K4a: 8x8 avg pool (56->7), depthwise 3x3 + relu, global mean -> s[r][b][c]. Fused: grid 4096.
__global__ void k_akg_pool(const float* __restrict__ Fc, const float* __restrict__ sc,
                           const float* __restrict__ dw, float* __restrict__ s){
    int gid = blockIdx.x; int r = gid >> 11; int bc = gid & 2047;
    int b = bc / CC_; int c = bc % CC_;
    int l = threadIdx.x; // 64
    __shared__ float sm[49];
    __shared__ float red[64];
    const float* fb = Fc + (size_t)bc*HWSZ;
    const float* si = sc + (size_t)r*NPIX + (size_t)b*HWSZ;
    const float* dwr = dw + (size_t)r*CC_*9;
    if (l < 49){
        int u = l/7, v = l%7;
        float sum = 0.f;
        for (int rr=0;rr<8;++rr){
            const float* rp = fb + (u*8+rr)*WW + v*8;
            const float* sp = si + (u*8+rr)*WW + v*8;
            #pragma unroll
            for (int q=0;q<8;++q) sum += rp[q] * sp[q];
        }
        sm[l] = sum * (1.f/64.f);
    }
    __syncthreads();
    float rv = 0.f;
    if (l < 49){
        float w[9];
        #pragma unroll
        for (int k=0;k<9;++k) w[k] = dwr[c*9+k];
        int u=l/7, v=l%7; float acc=0.f;
        #pragma unroll
        for (int ky=0;ky<3;++ky){ int uu=u+ky-1; if((unsigned)uu>=7u) continue;
            #pragma unroll
            for (int kx=0;kx<3;++kx){ int vv=v+kx-1; if((unsigned)vv>=7u) continue;
                acc += sm[uu*7+vv]*w[ky*3+kx]; } }
        rv = fmaxf(acc, 0.f);
    }
    red[l] = rv;
    __syncthreads();
    if (l==0){ float t=0.f; for(int i2=0;i2<64;++i2) t+=red[i2]; s[(size_t)r*BB*CC_ + bc] = t*(1.f/49.f); }
}

// K4b: head matvec + tanh -> Kw[r][b][t][c]. Fused: grid 144.
__global__ void k_akg_head(const float* __restrict__ s, const float* __restrict__ hw,
                           const float* __restrict__ hb, float* __restrict__ Kw){
    int gid = blockIdx.x; int r = gid / 72; int id = gid % 72;
    int b = id / 9; int og = id % 9;
    __shared__ float sv[CC_];
    int tid = threadIdx.x; // 256
    sv[tid] = s[(size_t)r*BB*CC_ + b*CC_ + tid];
    __syncthreads();
    int o = og*256 + tid;              // o = c*9 + t
    const float* wp = hw + (size_t)r*2304*CC_ + (size_t)o*CC_;
    float acc = hb[(size_t)r*2304 + o];
    for (int c2=0;c2<CC_;++c2) acc += wp[c2]*sv[c2];
    int c = o / 9, t = o - 9*c;
    Kw[((size_t)r*BB + b)*2304 + t*256 + c] = tanhf(acc);
}

// K5: deformable depthwise, fused over regions. Grid 896, 448 thr (7 waves, all active).
// b=bx&7 XCD pinning; rid=bx>>3: y=rid%56, creg=rid/56.
__global__ __launch_bounds__(448) void k_deform(const bf16* __restrict__ Fp, const float* __restrict__ p,
                                                const float* __restrict__ Kw, bf16* __restrict__ outsN){
    __shared__ int   so[504][4];
    __shared__ float swt[504][4];
    int bx = blockIdx.x; int b = bx & 7; int rid = bx >> 3; int y = rid % 56; int creg = rid / 56;
    int tid = threadIdx.x;
    const float* pr = p + (size_t)creg*BB*18*HWSZ;
    for (int e = tid; e < 504; e += 448){
        int t = e / 56, x = e % 56;
        int ky = t / 3, kx = t % 3;
        float dy = pr[((size_t)b*18 + 2*t  )*HWSZ + y*WW + x];
        float dx = pr[((size_t)b*18 + 2*t+1)*HWSZ + y*WW + x];
        float py = (float)(y - 1 + ky) + dy;
        float px = (float)(x - 1 + kx) + dx;
        float y0f = floorf(py), x0f = floorf(px);
        float wy1 = py - y0f, wx1 = px - x0f;
        float wy0 = 1.f - wy1, wx0 = 1.f - wx1;
        float vy0 = (y0f >= 0.f  && y0f <= 55.f) ? 1.f : 0.f;
        float vy1 = (y0f >= -1.f && y0f <= 54.f) ? 1.f : 0.f;
        float vx0 = (x0f >= 0.f  && x0f <= 55.f) ? 1.f : 0.f;
        float vx1 = (x0f >= -1.f && x0f <= 54.f) ? 1.f : 0.f;
        int y0 = (int)y0f, x0 = (int)x0f;
        int iy0 = min(max(y0,0),55),   iy1 = min(max(y0+1,0),55);
        int ix0 = min(max(x0,0),55),   ix1 = min(max(x0+1,0),55);
        so[e][0] = ((iy0+1)*58 + ix0+1)*256;
        so[e][1] = ((iy0+1)*58 + ix1+1)*256;
        so[e][2] = ((iy1+1)*58 + ix0+1)*256;
        so[e][3] = ((iy1+1)*58 + ix1+1)*256;
        swt[e][0] = wy0*wx0*vy0*vx0;
        swt[e][1] = wy0*wx1*vy0*vx1;
        swt[e][2] = wy1*wx0*vy1*vx0;
        swt[e][3] = wy1*wx1*vy1*vx1;
    }
    __syncthreads();
    int xl = tid % 56, cs = tid / 56; // cs 0..7, 32 channels each
    int c0 = cs*32;
    const bf16* Fb = Fp + (size_t)creg*FPR + (size_t)b*58*58*256;
    const float* Kb = Kw + ((size_t)creg*BB + b)*2304;
    float acc[32];
    #pragma unroll
    for (int j=0;j<32;++j) acc[j]=0.f;
    #pragma unroll 1
    for (int t=0;t<9;++t){
        int e = t*56+xl;
        int o00=so[e][0], o01=so[e][1], o10=so[e][2], o11=so[e][3];
        float w00=swt[e][0], w01=swt[e][1], w10=swt[e][2], w11=swt[e][3];
        const float* Kt = Kb + t*256 + c0;
        #pragma unroll
        for (int g=0; g<2; ++g){
            int cg = c0 + g*16;
            short8 a00 = *(const short8*)(Fb + o00 + cg);
            short8 a01 = *(const short8*)(Fb + o00 + cg + 8);
            short8 b00 = *(const short8*)(Fb + o01 + cg);
            short8 b01 = *(const short8*)(Fb + o01 + cg + 8);
            short8 c00 = *(const short8*)(Fb + o10 + cg);
            short8 c01 = *(const short8*)(Fb + o10 + cg + 8);
            short8 d00 = *(const short8*)(Fb + o11 + cg);
            short8 d01 = *(const short8*)(Fb + o11 + cg + 8);
            #pragma unroll
            for (int j=0;j<8;++j){
                float v = w00*bs2f(a00[j]) + w01*bs2f(b00[j]) + w10*bs2f(c00[j]) + w11*bs2f(d00[j]);
                acc[g*16+j] += Kt[g*16+j]*v;
            }
            #pragma unroll
            for (int j=0;j<8;++j){
                float v = w00*bs2f(a01[j]) + w01*bs2f(b01[j]) + w10*bs2f(c01[j]) + w11*bs2f(d01[j]);
                acc[g*16+8+j] += Kt[g*16+8+j]*v;
            }
        }
    }
    bf16* orow = outsN + ((size_t)b*HWSZ + y*WW + xl)*512 + creg*256 + c0;
    #pragma unroll
    for (int g=0; g<4; ++g){
        __attribute__((aligned(16))) bf16 tmp[8];
        #pragma unroll
        for (int j=0;j<8;++j) tmp[j] = f2b(acc[g*8+j]);
        *(short8*)(orow + g*8) = *(const short8*)tmp;
    }
}

// K6a: pw2 MFMA GEMM (M=25088,N=256,K=512), stats pass: per-block per-oc sum/sumsq partials.
__global__ __launch_bounds__(256) void k_pw2_mstats(const bf16* __restrict__ outsN, const bf16* __restrict__ Bpw,
                                                    const float* __restrict__ bias, float* __restrict__ partials){
    __shared__ float ls[2][2][256];
    int tid = threadIdx.x; int wave = tid>>6, lane = tid&63;
    int pixGroup = wave>>1, ntH = wave&1;
    int m = lane&15, q = lane>>4;
    size_t pb = (size_t)blockIdx.x*32 + pixGroup*16;
    const bf16* Ap = outsN + (pb + m)*512 + q*8;
    f32x4 acc[8];
    #pragma unroll
    for (int i=0;i<8;++i) acc[i] = (f32x4){0,0,0,0};
    #pragma unroll 1
    for (int kk = 0; kk < 16; ++kk){
        short8 a = *(const short8*)(Ap + kk*32);
        const bf16* Bk = Bpw + (((size_t)kk*16 + ntH*8)*64 + lane)*8;
        #pragma unroll
        for (int nt2 = 0; nt2 < 8; ++nt2){
            short8 b = *(const short8*)(Bk + (size_t)nt2*64*8);
            acc[nt2] = __builtin_amdgcn_mfma_f32_16x16x32_bf16(a, b, acc[nt2], 0, 0, 0);
        }
    }
    #pragma unroll
    for (int nt2 = 0; nt2 < 8; ++nt2){
        int oc = ntH*128 + nt2*16 + m;
        float bv = bias[oc];
        float s1 = 0.f, s2 = 0.f;
        #pragma unroll
        for (int r = 0; r < 4; ++r){ float v = acc[nt2][r] + bv; s1 += v; s2 += v*v; }
        s1 += __shfl_down(s1, 32); s1 += __shfl_down(s1, 16);
        s2 += __shfl_down(s2, 32); s2 += __shfl_down(s2, 16);
        if (q == 0){ ls[pixGroup][0][oc] = s1; ls[pixGroup][1][oc] = s2; }
    }
    __syncthreads();
    if (tid < 256){
        partials[(size_t)blockIdx.x*512 + tid]       = ls[0][0][tid] + ls[1][0][tid];
        partials[(size_t)blockIdx.x*512 + 256 + tid] = ls[0][1][tid] + ls[1][1][tid];
    }
}

// K6b: reduce partials -> bnp (mean, rsqrt).
__global__ void k_bnstat2(const float* __restrict__ partials, float* __restrict__ bnp){
    __shared__ float sm[512];
    int tid = threadIdx.x;           // 512
    float acc = 0.f;
    for (int blk = 0; blk < 784; ++blk) acc += partials[(size_t)blk*512 + tid];
    sm[tid] = acc;
    __syncthreads();
    if (tid < 256){
        float n = (float)NPIX;
        float mean = sm[tid] / n;
        float var = sm[256+tid] / n - mean*mean;
        var = fmaxf(var, 0.f);
        bnp[tid] = mean; bnp[256+tid] = rsqrtf(var + 1e-5f);
    }
}

// K6c: pw2 MFMA GEMM apply pass: recompute + BN, write fp32 NCHW out.
__global__ __launch_bounds__(256) void k_pw2_mapply(const bf16* __restrict__ outsN, const bf16* __restrict__ Bpw,
                                                    const float* __restrict__ bias, const float* __restrict__ bnp,
                                                    const float* __restrict__ gamma, const float* __restrict__ beta,
                                                    float* __restrict__ out){
    int tid = threadIdx.x; int wave = tid>>6, lane = tid&63;
    int pixGroup = wave>>1, ntH = wave&1;
    int m = lane&15, q = lane>>4;
    size_t pb = (size_t)blockIdx.x*32 + pixGroup*16;
    const bf16* Ap = outsN + (pb + m)*512 + q*8;
    f32x4 acc[8];
    #pragma unroll
    for (int i=0;i<8;++i) acc[i] = (f32x4){0,0,0,0};
    #pragma unroll 1
    for (int kk = 0; kk < 16; ++kk){
        short8 a = *(const short8*)(Ap + kk*32);
        const bf16* Bk = Bpw + (((size_t)kk*16 + ntH*8)*64 + lane)*8;
        #pragma unroll
        for (int nt2 = 0; nt2 < 8; ++nt2){
            short8 b = *(const short8*)(Bk + (size_t)nt2*64*8);
            acc[nt2] = __builtin_amdgcn_mfma_f32_16x16x32_bf16(a, b, acc[nt2], 0, 0, 0);
        }
    }
    int b_idx = (int)(pb / HWSZ);
    int yx0 = (int)(pb % HWSZ);
    #pragma unroll
    for (int nt2 = 0; nt2 < 8; ++nt2){
        int oc = ntH*128 + nt2*16 + m;
        float bv = bias[oc];
        float mean = bnp[oc], rsq = bnp[256+oc];
        float g = gamma[oc], be = beta[oc];
        float* op = out + ((size_t)b_idx*CC_ + oc)*HWSZ + yx0 + q*4;
        #pragma unroll
        for (int r = 0; r < 4; ++r){
            float v = acc[nt2][r] + bv;
            op[r] = (v - mean)*rsq*g + be;
        }
    }
}

extern "C" void kernel_launch(void* const* d_in, const int* in_sizes, int n_in,
                              void* d_out, int out_size, void* d_ws, size_t ws_size,
                              hipStream_t stream) {
    (void)in_sizes; (void)n_in; (void)out_size; (void)ws_size;
    const float* F_c    = (const float*)d_in[0];
    const float* dec_w  = (const float*)d_in[1];
    const float* dec_b  = (const float*)d_in[2];
    const float* off1_w = (const float*)d_in[3];
    const float* off1_b = (const float*)d_in[4];
    const float* off2_w = (const float*)d_in[5];
    const float* off2_b = (const float*)d_in[6];
    const float* akg_dw = (const float*)d_in[7];
    const float* akg_hw = (const float*)d_in[8];
    const float* akg_hb = (const float*)d_in[9];
    const float* pw2_w  = (const float*)d_in[10];
    const float* pw2_b  = (const float*)d_in[11];
    const float* gamma  = (const float*)d_in[12];
    const float* beta   = (const float*)d_in[13];
    float* out = (float*)d_out;

    char* ws = (char*)d_ws;
    size_t off = 0;
    auto alloc = [&](size_t bytes)->char*{
        char* r = ws + off;
        off = (off + bytes + 255) & ~(size_t)255;
        return r;
    };
    // Workspace ~67 MB.
    bf16*  Fp    = (bf16*) alloc(2*FPR*2);                 // padded NHWC F*sc, both regions
    bf16*  Bp    = (bf16*) alloc((size_t)2*9*8*4*64*8*2);  // conv1 weight frags
    bf16*  Bpw   = (bf16*) alloc((size_t)16*16*64*8*2);    // pw2 weight frags
    bf16*  Bc    = (bf16*) alloc((size_t)2*18*2*64*8*2);   // conv2 weight frags
    float* sc    = (float*)alloc((size_t)2*NPIX*4);
    bf16*  hp    = (bf16*) alloc(2*HPR*2);                 // padded NHWC hidden, both regions
    float* p     = (float*)alloc((size_t)2*BB*18*HWSZ*4);  // offsets, both regions
    float* s     = (float*)alloc((size_t)2*BB*CC_*4);
    float* Kw    = (float*)alloc((size_t)2*BB*CC_*9*4);
    bf16*  outsN = (bf16*) alloc(NPIX*512*2);              // NHWC, k = creg*256+c
    float* partials = (float*)alloc((size_t)784*512*4);
    float* bnp   = (float*)alloc(2*CC_*4);

    hipMemsetAsync(Fp, 0, 2*FPR*2, stream);                // zero borders for pad
    hipMemsetAsync(hp, 0, 2*HPR*2, stream);                // zero borders for conv2 pad

    k_scales<<<dim3((BB*HWSZ)/64), dim3(64), 0, stream>>>(F_c, dec_w, dec_b, sc);
    k_pack<<<dim3(BB*HH), dim3(256), 0, stream>>>(F_c, sc, Fp);
    k_bprep<<<dim3(576), dim3(64), 0, stream>>>(off1_w, Bp);
    k_bprep_pw<<<dim3(256), dim3(64), 0, stream>>>(pw2_w, Bpw);
    k_bprep_c2<<<dim3(72), dim3(64), 0, stream>>>(off2_w, Bc);

    // Region-fused pipeline.
    k_conv1<<<dim3(2*BB*HH), dim3(256), 0, stream>>>(Fp, Bp, off1_b, hp);
    k_conv2m<<<dim3(2*BB*HH), dim3(256), 0, stream>>>(hp, Bc, off2_b, p);
    k_akg_pool<<<dim3(2*BB*CC_), dim3(64), 0, stream>>>(F_c, sc, akg_dw, s);
    k_akg_head<<<dim3(2*BB*9), dim3(256), 0, stream>>>(s, akg_hw, akg_hb, Kw);
    k_deform<<<dim3(2*BB*HH), dim3(448), 0, stream>>>(Fp, p, Kw, outsN);

    k_pw2_mstats<<<dim3(784), dim3(256), 0, stream>>>(outsN, Bpw, pw2_b, partials);
    k_bnstat2<<<dim3(1), dim3(512), 0, stream>>>(partials, bnp);
    k_pw2_mapply<<<dim3(784), dim3(256), 0, stream>>>(outsN, Bpw, pw2_b, bnp, gamma, beta, out);
}

// Round 11
// 400.955 us; speedup vs baseline: 4.2019x; 1.1287x over previous
//
#include <hip/hip_runtime.h>
#include <hip/hip_bf16.h>

#define BB 8
#define CC_ 256
#define HH 56
#define WW 56
#define HWSZ (HH*WW)
#define RR_ 2
#define HID 64
#define FPR ((size_t)8*58*58*256)   // padded NHWC region elements
#define HPR ((size_t)8*58*58*64)    // padded NHWC hidden elements (per region)
#define NPIX ((size_t)BB*HWSZ)      // 25088

typedef __hip_bfloat16 bf16;
typedef __attribute__((ext_vector_type(8))) short short8;
typedef __attribute__((ext_vector_type(4))) short short4_t;
typedef __attribute__((ext_vector_type(4))) float f32x4;

__device__ __forceinline__ float b2f(bf16 v){ return __bfloat162float(v); }
__device__ __forceinline__ bf16 f2b(float v){ return __float2bfloat16(v); }
__device__ __forceinline__ float bs2f(short s){ return __uint_as_float(((unsigned)(unsigned short)s)<<16); }

// K1: decoupler 1x1 conv + softmax(R=2); writes scale factors sc[r][b][yx] = 1 + M_r.
__global__ void k_scales(const float* __restrict__ F, const float* __restrict__ dec_w,
                         const float* __restrict__ dec_b, float* __restrict__ sc){
    __shared__ float w0[CC_], w1[CC_];
    int tid = threadIdx.x; // 64
    for (int c = tid; c < CC_; c += 64){ w0[c] = dec_w[c]; w1[c] = dec_w[CC_+c]; }
    __syncthreads();
    int pid = blockIdx.x*64 + tid;
    int b = pid / HWSZ, yx = pid % HWSZ;
    const float* base = F + (size_t)b*CC_*HWSZ + yx;
    float a0 = dec_b[0], a1 = dec_b[1];
    for (int c = 0; c < CC_; ++c){ float v = base[(size_t)c*HWSZ]; a0 += v*w0[c]; a1 += v*w1[c]; }
    float m = fmaxf(a0,a1);
    float e0 = __expf(a0-m), e1 = __expf(a1-m);
    float inv = 1.0f/(e0+e1);
    sc[pid]                  = 1.0f + e0*inv;
    sc[(size_t)BB*HWSZ+pid]  = 1.0f + e1*inv;
}

// K1b: pack Fp[r][b][gy+1][gx+1][c] = bf16(F[b][c][gy][gx] * sc_r). Borders pre-zeroed by memset.
__global__ __launch_bounds__(256) void k_pack(const float* __restrict__ F, const float* __restrict__ sc,
                                              bf16* __restrict__ Fp){
    __shared__ bf16 lds[2][56][258];
    int bx = blockIdx.x; int b = bx/HH, gy = bx%HH;
    int tid = threadIdx.x; int x = tid & 63; int cq = tid >> 6;
    if (x < 56){
        const float* frow = F + (size_t)b*CC_*HWSZ + gy*WW + x;
        float s0 = sc[(size_t)b*HWSZ + gy*WW + x];
        float s1 = sc[(size_t)BB*HWSZ + (size_t)b*HWSZ + gy*WW + x];
        for (int cc = 0; cc < 64; ++cc){
            int c = cc*4 + cq;
            float v = frow[(size_t)c*HWSZ];
            lds[0][x][c] = f2b(v*s0);
            lds[1][x][c] = f2b(v*s1);
        }
    }
    __syncthreads();
    for (int r = 0; r < 2; ++r){
        bf16* dst = Fp + (size_t)r*FPR + (((size_t)b*58 + gy+1)*58 + 1)*256 + tid;
        for (int x2 = 0; x2 < 56; ++x2) dst[(size_t)x2*256] = lds[r][x2][tid];
    }
}

// K1c: pack conv1 weights into MFMA B-fragment order.
__global__ void k_bprep(const float* __restrict__ w, bf16* __restrict__ Bp){
    int id = blockIdx.x;               // 2*9*8*4 = 576
    int nt = id & 3; id >>= 2; int icc = id & 7; id >>= 3; int t = id % 9; int r = id / 9;
    int L = threadIdx.x;               // 64
    int oc = nt*16 + (L&15);
    const float* wr = w + (size_t)r*HID*CC_*9;
    bf16* out = Bp + (((((size_t)r*9 + t)*8 + icc)*4 + nt)*64 + L)*8;
    #pragma unroll
    for (int j = 0; j < 8; ++j){
        int ic = icc*32 + (L>>4)*8 + j;
        out[j] = f2b(wr[((size_t)oc*CC_ + ic)*9 + t]);
    }
}

// K1d: pack pw2 weights (256 x 512) into B-frag order: Bpw[kk][nt][lane][j].
__global__ void k_bprep_pw(const float* __restrict__ w, bf16* __restrict__ Bpw){
    int id = blockIdx.x;               // 16*16 = 256
    int kk = id >> 4, nt = id & 15;
    int L = threadIdx.x;               // 64
    int oc = nt*16 + (L&15);
    bf16* out = Bpw + (((size_t)(kk*16+nt))*64 + L)*8;
    #pragma unroll
    for (int j = 0; j < 8; ++j){
        int ic = kk*32 + (L>>4)*8 + j;
        out[j] = f2b(w[(size_t)oc*512 + ic]);
    }
}

// K1e: pack conv2 weights into B-frag order, zero-padded to N=32.
__global__ void k_bprep_c2(const float* __restrict__ w, bf16* __restrict__ Bc){
    int id = blockIdx.x;               // 2*18*2 = 72
    int nt = id & 1; id >>= 1; int ks = id % 18; int r = id / 18;
    int t = ks >> 1, chunk = ks & 1;
    int L = threadIdx.x;               // 64
    int oc = nt*16 + (L&15);
    const float* wr = w + (size_t)r*18*HID*9;
    bf16* out = Bc + ((((size_t)r*18 + ks)*2 + nt)*64 + L)*8;
    #pragma unroll
    for (int j = 0; j < 8; ++j){
        int ic = chunk*32 + (L>>4)*8 + j;
        out[j] = (oc < 18) ? f2b(wr[((size_t)oc*HID + ic)*9 + t]) : f2b(0.f);
    }
}

// K2: conv3x3 256->64 via MFMA implicit GEMM, fused over regions.
__global__ __launch_bounds__(256) void k_conv1(const bf16* __restrict__ Fp, const bf16* __restrict__ Bp,
                                               const float* __restrict__ bias, bf16* __restrict__ hp){
    int bx = blockIdx.x; int b = bx & 7; int rid = bx >> 3; int y = rid % 56; int r = rid / 56;
    int tid = threadIdx.x; int wave = tid>>6, lane = tid&63;
    int m = lane&15, q = lane>>4;
    int x0 = (wave==3) ? 40 : wave*16;
    f32x4 acc0 = {0,0,0,0}, acc1 = {0,0,0,0}, acc2 = {0,0,0,0}, acc3 = {0,0,0,0};
    const bf16* Fb = Fp + (size_t)r*FPR + ((size_t)b*58*58)*256;
    const bf16* Bpr = Bp + (size_t)r*9*8*4*64*8;
    #pragma unroll
    for (int t = 0; t < 9; ++t){
        int ty = t/3, tx = t%3;
        const bf16* arow = Fb + ((size_t)(y+ty)*58 + (x0+m+tx))*256 + q*8;
        const bf16* brow = Bpr + ((size_t)t*8)*4*64*8 + lane*8;
        #pragma unroll
        for (int icc = 0; icc < 8; ++icc){
            short8 a  = *(const short8*)(arow + icc*32);
            const bf16* bb = brow + (size_t)icc*4*64*8;
            short8 b0 = *(const short8*)(bb);
            short8 b1 = *(const short8*)(bb + 64*8);
            short8 b2 = *(const short8*)(bb + 2*64*8);
            short8 b3 = *(const short8*)(bb + 3*64*8);
            acc0 = __builtin_amdgcn_mfma_f32_16x16x32_bf16(a, b0, acc0, 0, 0, 0);
            acc1 = __builtin_amdgcn_mfma_f32_16x16x32_bf16(a, b1, acc1, 0, 0, 0);
            acc2 = __builtin_amdgcn_mfma_f32_16x16x32_bf16(a, b2, acc2, 0, 0, 0);
            acc3 = __builtin_amdgcn_mfma_f32_16x16x32_bf16(a, b3, acc3, 0, 0, 0);
        }
    }
    f32x4 accs[4] = {acc0, acc1, acc2, acc3};
    const float* br = bias + r*HID;
    bf16* hrow = hp + (size_t)r*HPR + (((size_t)b*58 + y+1)*58 + 1)*64;
    #pragma unroll
    for (int nt = 0; nt < 4; ++nt){
        int oc = nt*16 + m;
        float bv = br[oc];
        #pragma unroll
        for (int r2 = 0; r2 < 4; ++r2){
            int x = x0 + q*4 + r2;
            hrow[(size_t)x*64 + oc] = f2b(fmaxf(accs[nt][r2] + bv, 0.f));
        }
    }
}

// K3: conv2 via MFMA implicit GEMM on padded NHWC hp, fused over regions. Grid 896.
__global__ __launch_bounds__(256) void k_conv2m(const bf16* __restrict__ hp, const bf16* __restrict__ Bc,
                                                const float* __restrict__ bias, float* __restrict__ p){
    int bx = blockIdx.x; int b = bx & 7; int rid = bx >> 3; int y = rid % 56; int r = rid / 56;
    int tid = threadIdx.x; int wave = tid>>6, lane = tid&63;
    int m = lane&15, q = lane>>4;
    int x0 = (wave==3) ? 40 : wave*16;
    f32x4 acc0 = {0,0,0,0}, acc1 = {0,0,0,0};
    const bf16* Hb = hp + (size_t)r*HPR + ((size_t)b*58 + y)*58*64;
    const bf16* Bcr = Bc + (size_t)r*18*2*64*8;
    #pragma unroll
    for (int t = 0; t < 9; ++t){
        int ty = t/3, tx = t%3;
        const bf16* arow = Hb + ((size_t)ty*58 + (x0+m+tx))*64 + q*8;
        #pragma unroll
        for (int chunk = 0; chunk < 2; ++chunk){
            short8 a = *(const short8*)(arow + chunk*32);
            const bf16* bb = Bcr + (((size_t)(t*2+chunk))*2*64 + lane)*8;
            short8 b0 = *(const short8*)(bb);
            short8 b1 = *(const short8*)(bb + 64*8);
            acc0 = __builtin_amdgcn_mfma_f32_16x16x32_bf16(a, b0, acc0, 0, 0, 0);
            acc1 = __builtin_amdgcn_mfma_f32_16x16x32_bf16(a, b1, acc1, 0, 0, 0);
        }
    }
    const float* br = bias + r*18;
    float* pr = p + (size_t)r*BB*18*HWSZ;
    #pragma unroll
    for (int r2 = 0; r2 < 4; ++r2){
        int x = x0 + q*4 + r2;
        {
            float v = acc0[r2] + br[m];
            pr[((size_t)b*18 + m)*HWSZ + y*WW + x] = v;
        }
        if (m < 2){
            float v = acc1[r2] + br[16+m];
            pr[((size_t)b*18 + 16+m)*HWSZ + y*WW + x] = v;
        }
    }
}

// K4a: 8x8 avg pool (56->7), depthwise 3x3 + relu, global mean -> s[r][b][c]. Fused: grid 4096.
__global__ void k_akg_pool(const float* __restrict__ Fc, const float* __restrict__ sc,
                           const float* __restrict__ dw, float* __restrict__ s){
    int gid = blockIdx.x; int r = gid >> 11; int bc = gid & 2047;
    int b = bc / CC_; int c = bc % CC_;
    int l = threadIdx.x; // 64
    __shared__ float sm[49];
    __shared__ float red[64];
    const float* fb = Fc + (size_t)bc*HWSZ;
    const float* si = sc + (size_t)r*NPIX + (size_t)b*HWSZ;
    const float* dwr = dw + (size_t)r*CC_*9;
    if (l < 49){
        int u = l/7, v = l%7;
        float sum = 0.f;
        for (int rr=0;rr<8;++rr){
            const float* rp = fb + (u*8+rr)*WW + v*8;
            const float* sp = si + (u*8+rr)*WW + v*8;
            #pragma unroll
            for (int q=0;q<8;++q) sum += rp[q] * sp[q];
        }
        sm[l] = sum * (1.f/64.f);
    }
    __syncthreads();
    float rv = 0.f;
    if (l < 49){
        float w[9];
        #pragma unroll
        for (int k=0;k<9;++k) w[k] = dwr[c*9+k];
        int u=l/7, v=l%7; float acc=0.f;
        #pragma unroll
        for (int ky=0;ky<3;++ky){ int uu=u+ky-1; if((unsigned)uu>=7u) continue;
            #pragma unroll
            for (int kx=0;kx<3;++kx){ int vv=v+kx-1; if((unsigned)vv>=7u) continue;
                acc += sm[uu*7+vv]*w[ky*3+kx]; } }
        rv = fmaxf(acc, 0.f);
    }
    red[l] = rv;
    __syncthreads();
    if (l==0){ float t=0.f; for(int i2=0;i2<64;++i2) t+=red[i2]; s[(size_t)r*BB*CC_ + bc] = t*(1.f/49.f); }
}

// K4b: head matvec + tanh -> Kw[r][b][t][c]. Fused: grid 144.
__global__ void k_akg_head(const float* __restrict__ s, const float* __restrict__ hw,
                           const float* __restrict__ hb, float* __restrict__ Kw){
    int gid = blockIdx.x; int r = gid / 72; int id = gid % 72;
    int b = id / 9; int og = id % 9;
    __shared__ float sv[CC_];
    int tid = threadIdx.x; // 256
    sv[tid] = s[(size_t)r*BB*CC_ + b*CC_ + tid];
    __syncthreads();
    int o = og*256 + tid;              // o = c*9 + t
    const float* wp = hw + (size_t)r*2304*CC_ + (size_t)o*CC_;
    float acc = hb[(size_t)r*2304 + o];
    for (int c2=0;c2<CC_;++c2) acc += wp[c2]*sv[c2];
    int c = o / 9, t = o - 9*c;
    Kw[((size_t)r*BB + b)*2304 + t*256 + c] = tanhf(acc);
}

// K5: deformable depthwise — wave-per-pixel, channel dim spans lanes (all loads coalesced).
// Grid 12544: b=bx&7 (XCD pin); rid=bx>>3: xq=rid%14, y=(rid/14)%56, creg=rid/784.
// Wave w handles pixel x=xq*4+w; lane l covers channels 4l..4l+3 (8B loads, 512B/wave contiguous).
__global__ __launch_bounds__(256) void k_deform(const bf16* __restrict__ Fp, const float* __restrict__ p,
                                                const float* __restrict__ Kw, bf16* __restrict__ outsN){
    __shared__ int   so[4][9][4];
    __shared__ float swt[4][9][4];
    int bx = blockIdx.x; int b = bx & 7; int rid = bx >> 3;
    int xq = rid % 14; int y = (rid / 14) % 56; int creg = rid / 784;
    int tid = threadIdx.x; int w = tid >> 6, l = tid & 63;
    int x = xq*4 + w;
    const float* pr = p + (size_t)creg*BB*18*HWSZ;
    if (l < 9){
        int t = l;
        int ky = t / 3, kx = t % 3;
        float dy = pr[((size_t)b*18 + 2*t  )*HWSZ + y*WW + x];
        float dx = pr[((size_t)b*18 + 2*t+1)*HWSZ + y*WW + x];
        float py = (float)(y - 1 + ky) + dy;
        float px = (float)(x - 1 + kx) + dx;
        float y0f = floorf(py), x0f = floorf(px);
        float wy1 = py - y0f, wx1 = px - x0f;
        float wy0 = 1.f - wy1, wx0 = 1.f - wx1;
        float vy0 = (y0f >= 0.f  && y0f <= 55.f) ? 1.f : 0.f;
        float vy1 = (y0f >= -1.f && y0f <= 54.f) ? 1.f : 0.f;
        float vx0 = (x0f >= 0.f  && x0f <= 55.f) ? 1.f : 0.f;
        float vx1 = (x0f >= -1.f && x0f <= 54.f) ? 1.f : 0.f;
        int y0 = (int)y0f, x0i = (int)x0f;
        int iy0 = min(max(y0,0),55),    iy1 = min(max(y0+1,0),55);
        int ix0 = min(max(x0i,0),55),   ix1 = min(max(x0i+1,0),55);
        so[w][t][0] = ((iy0+1)*58 + ix0+1)*256;
        so[w][t][1] = ((iy0+1)*58 + ix1+1)*256;
        so[w][t][2] = ((iy1+1)*58 + ix0+1)*256;
        so[w][t][3] = ((iy1+1)*58 + ix1+1)*256;
        swt[w][t][0] = wy0*wx0*vy0*vx0;
        swt[w][t][1] = wy0*wx1*vy0*vx1;
        swt[w][t][2] = wy1*wx0*vy1*vx0;
        swt[w][t][3] = wy1*wx1*vy1*vx1;
    }
    __syncthreads();
    const bf16* Fb = Fp + (size_t)creg*FPR + (size_t)b*58*58*256;
    const float* Kb = Kw + ((size_t)creg*BB + b)*2304;
    int cl = 4*l;
    float acc[4] = {0.f, 0.f, 0.f, 0.f};
    #pragma unroll
    for (int t = 0; t < 9; ++t){
        int o00 = so[w][t][0], o01 = so[w][t][1], o10 = so[w][t][2], o11 = so[w][t][3];
        float w00 = swt[w][t][0], w01 = swt[w][t][1], w10 = swt[w][t][2], w11 = swt[w][t][3];
        short4_t f00 = *(const short4_t*)(Fb + o00 + cl);
        short4_t f01 = *(const short4_t*)(Fb + o01 + cl);
        short4_t f10 = *(const short4_t*)(Fb + o10 + cl);
        short4_t f11 = *(const short4_t*)(Fb + o11 + cl);
        f32x4 kt = *(const f32x4*)(Kb + t*256 + cl);
        #pragma unroll
        for (int j = 0; j < 4; ++j){
            float v = w00*bs2f(f00[j]) + w01*bs2f(f01[j]) + w10*bs2f(f10[j]) + w11*bs2f(f11[j]);
            acc[j] += kt[j]*v;
        }
    }
    __attribute__((aligned(8))) bf16 tmp[4];
    #pragma unroll
    for (int j = 0; j < 4; ++j) tmp[j] = f2b(acc[j]);
    *(short4_t*)(outsN + ((size_t)b*HWSZ + y*WW + x)*512 + creg*256 + cl) = *(const short4_t*)tmp;
}

// K6a: pw2 MFMA GEMM (M=25088,N=256,K=512), stats pass: per-block per-oc sum/sumsq partials.
__global__ __launch_bounds__(256) void k_pw2_mstats(const bf16* __restrict__ outsN, const bf16* __restrict__ Bpw,
                                                    const float* __restrict__ bias, float* __restrict__ partials){
    __shared__ float ls[2][2][256];
    int tid = threadIdx.x; int wave = tid>>6, lane = tid&63;
    int pixGroup = wave>>1, ntH = wave&1;
    int m = lane&15, q = lane>>4;
    size_t pb = (size_t)blockIdx.x*32 + pixGroup*16;
    const bf16* Ap = outsN + (pb + m)*512 + q*8;
    f32x4 acc[8];
    #pragma unroll
    for (int i=0;i<8;++i) acc[i] = (f32x4){0,0,0,0};
    #pragma unroll 1
    for (int kk = 0; kk < 16; ++kk){
        short8 a = *(const short8*)(Ap + kk*32);
        const bf16* Bk = Bpw + (((size_t)kk*16 + ntH*8)*64 + lane)*8;
        #pragma unroll
        for (int nt2 = 0; nt2 < 8; ++nt2){
            short8 b = *(const short8*)(Bk + (size_t)nt2*64*8);
            acc[nt2] = __builtin_amdgcn_mfma_f32_16x16x32_bf16(a, b, acc[nt2], 0, 0, 0);
        }
    }
    #pragma unroll
    for (int nt2 = 0; nt2 < 8; ++nt2){
        int oc = ntH*128 + nt2*16 + m;
        float bv = bias[oc];
        float s1 = 0.f, s2 = 0.f;
        #pragma unroll
        for (int r = 0; r < 4; ++r){ float v = acc[nt2][r] + bv; s1 += v; s2 += v*v; }
        s1 += __shfl_down(s1, 32); s1 += __shfl_down(s1, 16);
        s2 += __shfl_down(s2, 32); s2 += __shfl_down(s2, 16);
        if (q == 0){ ls[pixGroup][0][oc] = s1; ls[pixGroup][1][oc] = s2; }
    }
    __syncthreads();
    if (tid < 256){
        partials[(size_t)blockIdx.x*512 + tid]       = ls[0][0][tid] + ls[1][0][tid];
        partials[(size_t)blockIdx.x*512 + 256 + tid] = ls[0][1][tid] + ls[1][1][tid];
    }
}

// K6b: reduce partials -> bnp (mean, rsqrt).
__global__ void k_bnstat2(const float* __restrict__ partials, float* __restrict__ bnp){
    __shared__ float sm[512];
    int tid = threadIdx.x;           // 512
    float acc = 0.f;
    for (int blk = 0; blk < 784; ++blk) acc += partials[(size_t)blk*512 + tid];
    sm[tid] = acc;
    __syncthreads();
    if (tid < 256){
        float n = (float)NPIX;
        float mean = sm[tid] / n;
        float var = sm[256+tid] / n - mean*mean;
        var = fmaxf(var, 0.f);
        bnp[tid] = mean; bnp[256+tid] = rsqrtf(var + 1e-5f);
    }
}

// K6c: pw2 MFMA GEMM apply pass: recompute + BN, write fp32 NCHW out.
__global__ __launch_bounds__(256) void k_pw2_mapply(const bf16* __restrict__ outsN, const bf16* __restrict__ Bpw,
                                                    const float* __restrict__ bias, const float* __restrict__ bnp,
                                                    const float* __restrict__ gamma, const float* __restrict__ beta,
                                                    float* __restrict__ out){
    int tid = threadIdx.x; int wave = tid>>6, lane = tid&63;
    int pixGroup = wave>>1, ntH = wave&1;
    int m = lane&15, q = lane>>4;
    size_t pb = (size_t)blockIdx.x*32 + pixGroup*16;
    const bf16* Ap = outsN + (pb + m)*512 + q*8;
    f32x4 acc[8];
    #pragma unroll
    for (int i=0;i<8;++i) acc[i] = (f32x4){0,0,0,0};
    #pragma unroll 1
    for (int kk = 0; kk < 16; ++kk){
        short8 a = *(const short8*)(Ap + kk*32);
        const bf16* Bk = Bpw + (((size_t)kk*16 + ntH*8)*64 + lane)*8;
        #pragma unroll
        for (int nt2 = 0; nt2 < 8; ++nt2){
            short8 b = *(const short8*)(Bk + (size_t)nt2*64*8);
            acc[nt2] = __builtin_amdgcn_mfma_f32_16x16x32_bf16(a, b, acc[nt2], 0, 0, 0);
        }
    }
    int b_idx = (int)(pb / HWSZ);
    int yx0 = (int)(pb % HWSZ);
    #pragma unroll
    for (int nt2 = 0; nt2 < 8; ++nt2){
        int oc = ntH*128 + nt2*16 + m;
        float bv = bias[oc];
        float mean = bnp[oc], rsq = bnp[256+oc];
        float g = gamma[oc], be = beta[oc];
        float* op = out + ((size_t)b_idx*CC_ + oc)*HWSZ + yx0 + q*4;
        #pragma unroll
        for (int r = 0; r < 4; ++r){
            float v = acc[nt2][r] + bv;
            op[r] = (v - mean)*rsq*g + be;
        }
    }
}

extern "C" void kernel_launch(void* const* d_in, const int* in_sizes, int n_in,
                              void* d_out, int out_size, void* d_ws, size_t ws_size,
                              hipStream_t stream) {
    (void)in_sizes; (void)n_in; (void)out_size; (void)ws_size;
    const float* F_c    = (const float*)d_in[0];
    const float* dec_w  = (const float*)d_in[1];
    const float* dec_b  = (const float*)d_in[2];
    const float* off1_w = (const float*)d_in[3];
    const float* off1_b = (const float*)d_in[4];
    const float* off2_w = (const float*)d_in[5];
    const float* off2_b = (const float*)d_in[6];
    const float* akg_dw = (const float*)d_in[7];
    const float* akg_hw = (const float*)d_in[8];
    const float* akg_hb = (const float*)d_in[9];
    const float* pw2_w  = (const float*)d_in[10];
    const float* pw2_b  = (const float*)d_in[11];
    const float* gamma  = (const float*)d_in[12];
    const float* beta   = (const float*)d_in[13];
    float* out = (float*)d_out;

    char* ws = (char*)d_ws;
    size_t off = 0;
    auto alloc = [&](size_t bytes)->char*{
        char* r = ws + off;
        off = (off + bytes + 255) & ~(size_t)255;
        return r;
    };
    // Workspace ~67 MB.
    bf16*  Fp    = (bf16*) alloc(2*FPR*2);                 // padded NHWC F*sc, both regions
    bf16*  Bp    = (bf16*) alloc((size_t)2*9*8*4*64*8*2);  // conv1 weight frags
    bf16*  Bpw   = (bf16*) alloc((size_t)16*16*64*8*2);    // pw2 weight frags
    bf16*  Bc    = (bf16*) alloc((size_t)2*18*2*64*8*2);   // conv2 weight frags
    float* sc    = (float*)alloc((size_t)2*NPIX*4);
    bf16*  hp    = (bf16*) alloc(2*HPR*2);                 // padded NHWC hidden, both regions
    float* p     = (float*)alloc((size_t)2*BB*18*HWSZ*4);  // offsets, both regions
    float* s     = (float*)alloc((size_t)2*BB*CC_*4);
    float* Kw    = (float*)alloc((size_t)2*BB*CC_*9*4);
    bf16*  outsN = (bf16*) alloc(NPIX*512*2);              // NHWC, k = creg*256+c
    float* partials = (float*)alloc((size_t)784*512*4);
    float* bnp   = (float*)alloc(2*CC_*4);

    hipMemsetAsync(Fp, 0, 2*FPR*2, stream);                // zero borders for pad
    hipMemsetAsync(hp, 0, 2*HPR*2, stream);                // zero borders for conv2 pad

    k_scales<<<dim3((BB*HWSZ)/64), dim3(64), 0, stream>>>(F_c, dec_w, dec_b, sc);
    k_pack<<<dim3(BB*HH), dim3(256), 0, stream>>>(F_c, sc, Fp);
    k_bprep<<<dim3(576), dim3(64), 0, stream>>>(off1_w, Bp);
    k_bprep_pw<<<dim3(256), dim3(64), 0, stream>>>(pw2_w, Bpw);
    k_bprep_c2<<<dim3(72), dim3(64), 0, stream>>>(off2_w, Bc);

    // Region-fused pipeline.
    k_conv1<<<dim3(2*BB*HH), dim3(256), 0, stream>>>(Fp, Bp, off1_b, hp);
    k_conv2m<<<dim3(2*BB*HH), dim3(256), 0, stream>>>(hp, Bc, off2_b, p);
    k_akg_pool<<<dim3(2*BB*CC_), dim3(64), 0, stream>>>(F_c, sc, akg_dw, s);
    k_akg_head<<<dim3(2*BB*9), dim3(256), 0, stream>>>(s, akg_hw, akg_hb, Kw);
    k_deform<<<dim3(2*BB*HH*14), dim3(256), 0, stream>>>(Fp, p, Kw, outsN);

    k_pw2_mstats<<<dim3(784), dim3(256), 0, stream>>>(outsN, Bpw, pw2_b, partials);
    k_bnstat2<<<dim3(1), dim3(512), 0, stream>>>(partials, bnp);
    k_pw2_mapply<<<dim3(784), dim3(256), 0, stream>>>(outsN, Bpw, pw2_b, bnp, gamma, beta, out);
}

// Round 12
// 381.143 us; speedup vs baseline: 4.4203x; 1.0520x over previous
//
#include <hip/hip_runtime.h>
#include <hip/hip_bf16.h>

#define BB 8
#define CC_ 256
#define HH 56
#define WW 56
#define HWSZ (HH*WW)
#define RR_ 2
#define HID 64
#define FPR ((size_t)8*58*58*256)   // padded NHWC region elements
#define HPR ((size_t)8*58*58*64)    // padded NHWC hidden elements (per region)
#define NPIX ((size_t)BB*HWSZ)      // 25088

typedef __hip_bfloat16 bf16;
typedef __attribute__((ext_vector_type(8))) short short8;
typedef __attribute__((ext_vector_type(4))) short short4_t;
typedef __attribute__((ext_vector_type(4))) float f32x4;

__device__ __forceinline__ float b2f(bf16 v){ return __bfloat162float(v); }
__device__ __forceinline__ bf16 f2b(float v){ return __float2bfloat16(v); }
__device__ __forceinline__ float bs2f(short s){ return __uint_as_float(((unsigned)(unsigned short)s)<<16); }

// K1: decoupler 1x1 conv + softmax(R=2); writes scale factors sc[r][b][yx] = 1 + M_r.
__global__ void k_scales(const float* __restrict__ F, const float* __restrict__ dec_w,
                         const float* __restrict__ dec_b, float* __restrict__ sc){
    __shared__ float w0[CC_], w1[CC_];
    int tid = threadIdx.x; // 64
    for (int c = tid; c < CC_; c += 64){ w0[c] = dec_w[c]; w1[c] = dec_w[CC_+c]; }
    __syncthreads();
    int pid = blockIdx.x*64 + tid;
    int b = pid / HWSZ, yx = pid % HWSZ;
    const float* base = F + (size_t)b*CC_*HWSZ + yx;
    float a0 = dec_b[0], a1 = dec_b[1];
    for (int c = 0; c < CC_; ++c){ float v = base[(size_t)c*HWSZ]; a0 += v*w0[c]; a1 += v*w1[c]; }
    float m = fmaxf(a0,a1);
    float e0 = __expf(a0-m), e1 = __expf(a1-m);
    float inv = 1.0f/(e0+e1);
    sc[pid]                  = 1.0f + e0*inv;
    sc[(size_t)BB*HWSZ+pid]  = 1.0f + e1*inv;
}

// K1b: pack Fp[r][b][gy+1][gx+1][c] = bf16(F[b][c][gy][gx] * sc_r). Borders pre-zeroed by memset.
__global__ __launch_bounds__(256) void k_pack(const float* __restrict__ F, const float* __restrict__ sc,
                                              bf16* __restrict__ Fp){
    __shared__ bf16 lds[2][56][258];
    int bx = blockIdx.x; int b = bx/HH, gy = bx%HH;
    int tid = threadIdx.x; int x = tid & 63; int cq = tid >> 6;
    if (x < 56){
        const float* frow = F + (size_t)b*CC_*HWSZ + gy*WW + x;
        float s0 = sc[(size_t)b*HWSZ + gy*WW + x];
        float s1 = sc[(size_t)BB*HWSZ + (size_t)b*HWSZ + gy*WW + x];
        for (int cc = 0; cc < 64; ++cc){
            int c = cc*4 + cq;
            float v = frow[(size_t)c*HWSZ];
            lds[0][x][c] = f2b(v*s0);
            lds[1][x][c] = f2b(v*s1);
        }
    }
    __syncthreads();
    for (int r = 0; r < 2; ++r){
        bf16* dst = Fp + (size_t)r*FPR + (((size_t)b*58 + gy+1)*58 + 1)*256 + tid;
        for (int x2 = 0; x2 < 56; ++x2) dst[(size_t)x2*256] = lds[r][x2][tid];
    }
}

// K1c: pack conv1 weights into MFMA B-fragment order.
__global__ void k_bprep(const float* __restrict__ w, bf16* __restrict__ Bp){
    int id = blockIdx.x;               // 2*9*8*4 = 576
    int nt = id & 3; id >>= 2; int icc = id & 7; id >>= 3; int t = id % 9; int r = id / 9;
    int L = threadIdx.x;               // 64
    int oc = nt*16 + (L&15);
    const float* wr = w + (size_t)r*HID*CC_*9;
    bf16* out = Bp + (((((size_t)r*9 + t)*8 + icc)*4 + nt)*64 + L)*8;
    #pragma unroll
    for (int j = 0; j < 8; ++j){
        int ic = icc*32 + (L>>4)*8 + j;
        out[j] = f2b(wr[((size_t)oc*CC_ + ic)*9 + t]);
    }
}

// K1d: pack pw2 weights (256 x 512) into B-frag order: Bpw[kk][nt][lane][j].
__global__ void k_bprep_pw(const float* __restrict__ w, bf16* __restrict__ Bpw){
    int id = blockIdx.x;               // 16*16 = 256
    int kk = id >> 4, nt = id & 15;
    int L = threadIdx.x;               // 64
    int oc = nt*16 + (L&15);
    bf16* out = Bpw + (((size_t)(kk*16+nt))*64 + L)*8;
    #pragma unroll
    for (int j = 0; j < 8; ++j){
        int ic = kk*32 + (L>>4)*8 + j;
        out[j] = f2b(w[(size_t)oc*512 + ic]);
    }
}

// K1e: pack conv2 weights into B-frag order, zero-padded to N=32.
__global__ void k_bprep_c2(const float* __restrict__ w, bf16* __restrict__ Bc){
    int id = blockIdx.x;               // 2*18*2 = 72
    int nt = id & 1; id >>= 1; int ks = id % 18; int r = id / 18;
    int t = ks >> 1, chunk = ks & 1;
    int L = threadIdx.x;               // 64
    int oc = nt*16 + (L&15);
    const float* wr = w + (size_t)r*18*HID*9;
    bf16* out = Bc + ((((size_t)r*18 + ks)*2 + nt)*64 + L)*8;
    #pragma unroll
    for (int j = 0; j < 8; ++j){
        int ic = chunk*32 + (L>>4)*8 + j;
        out[j] = (oc < 18) ? f2b(wr[((size_t)oc*HID + ic)*9 + t]) : f2b(0.f);
    }
}

// K2: conv3x3 256->64 via MFMA implicit GEMM, fused over regions.
__global__ __launch_bounds__(256) void k_conv1(const bf16* __restrict__ Fp, const bf16* __restrict__ Bp,
                                               const float* __restrict__ bias, bf16* __restrict__ hp){
    int bx = blockIdx.x; int b = bx & 7; int rid = bx >> 3; int y = rid % 56; int r = rid / 56;
    int tid = threadIdx.x; int wave = tid>>6, lane = tid&63;
    int m = lane&15, q = lane>>4;
    int x0 = (wave==3) ? 40 : wave*16;
    f32x4 acc0 = {0,0,0,0}, acc1 = {0,0,0,0}, acc2 = {0,0,0,0}, acc3 = {0,0,0,0};
    const bf16* Fb = Fp + (size_t)r*FPR + ((size_t)b*58*58)*256;
    const bf16* Bpr = Bp + (size_t)r*9*8*4*64*8;
    #pragma unroll
    for (int t = 0; t < 9; ++t){
        int ty = t/3, tx = t%3;
        const bf16* arow = Fb + ((size_t)(y+ty)*58 + (x0+m+tx))*256 + q*8;
        const bf16* brow = Bpr + ((size_t)t*8)*4*64*8 + lane*8;
        #pragma unroll
        for (int icc = 0; icc < 8; ++icc){
            short8 a  = *(const short8*)(arow + icc*32);
            const bf16* bb = brow + (size_t)icc*4*64*8;
            short8 b0 = *(const short8*)(bb);
            short8 b1 = *(const short8*)(bb + 64*8);
            short8 b2 = *(const short8*)(bb + 2*64*8);
            short8 b3 = *(const short8*)(bb + 3*64*8);
            acc0 = __builtin_amdgcn_mfma_f32_16x16x32_bf16(a, b0, acc0, 0, 0, 0);
            acc1 = __builtin_amdgcn_mfma_f32_16x16x32_bf16(a, b1, acc1, 0, 0, 0);
            acc2 = __builtin_amdgcn_mfma_f32_16x16x32_bf16(a, b2, acc2, 0, 0, 0);
            acc3 = __builtin_amdgcn_mfma_f32_16x16x32_bf16(a, b3, acc3, 0, 0, 0);
        }
    }
    f32x4 accs[4] = {acc0, acc1, acc2, acc3};
    const float* br = bias + r*HID;
    bf16* hrow = hp + (size_t)r*HPR + (((size_t)b*58 + y+1)*58 + 1)*64;
    #pragma unroll
    for (int nt = 0; nt < 4; ++nt){
        int oc = nt*16 + m;
        float bv = br[oc];
        #pragma unroll
        for (int r2 = 0; r2 < 4; ++r2){
            int x = x0 + q*4 + r2;
            hrow[(size_t)x*64 + oc] = f2b(fmaxf(accs[nt][r2] + bv, 0.f));
        }
    }
}

// K3: conv2 via MFMA implicit GEMM on padded NHWC hp, fused over regions. Grid 896.
__global__ __launch_bounds__(256) void k_conv2m(const bf16* __restrict__ hp, const bf16* __restrict__ Bc,
                                                const float* __restrict__ bias, float* __restrict__ p){
    int bx = blockIdx.x; int b = bx & 7; int rid = bx >> 3; int y = rid % 56; int r = rid / 56;
    int tid = threadIdx.x; int wave = tid>>6, lane = tid&63;
    int m = lane&15, q = lane>>4;
    int x0 = (wave==3) ? 40 : wave*16;
    f32x4 acc0 = {0,0,0,0}, acc1 = {0,0,0,0};
    const bf16* Hb = hp + (size_t)r*HPR + ((size_t)b*58 + y)*58*64;
    const bf16* Bcr = Bc + (size_t)r*18*2*64*8;
    #pragma unroll
    for (int t = 0; t < 9; ++t){
        int ty = t/3, tx = t%3;
        const bf16* arow = Hb + ((size_t)ty*58 + (x0+m+tx))*64 + q*8;
        #pragma unroll
        for (int chunk = 0; chunk < 2; ++chunk){
            short8 a = *(const short8*)(arow + chunk*32);
            const bf16* bb = Bcr + (((size_t)(t*2+chunk))*2*64 + lane)*8;
            short8 b0 = *(const short8*)(bb);
            short8 b1 = *(const short8*)(bb + 64*8);
            acc0 = __builtin_amdgcn_mfma_f32_16x16x32_bf16(a, b0, acc0, 0, 0, 0);
            acc1 = __builtin_amdgcn_mfma_f32_16x16x32_bf16(a, b1, acc1, 0, 0, 0);
        }
    }
    const float* br = bias + r*18;
    float* pr = p + (size_t)r*BB*18*HWSZ;
    #pragma unroll
    for (int r2 = 0; r2 < 4; ++r2){
        int x = x0 + q*4 + r2;
        {
            float v = acc0[r2] + br[m];
            pr[((size_t)b*18 + m)*HWSZ + y*WW + x] = v;
        }
        if (m < 2){
            float v = acc1[r2] + br[16+m];
            pr[((size_t)b*18 + 16+m)*HWSZ + y*WW + x] = v;
        }
    }
}

// K4a: 8x8 avg pool (56->7), depthwise 3x3 + relu, global mean -> s[r][b][c]. Fused: grid 4096.
__global__ void k_akg_pool(const float* __restrict__ Fc, const float* __restrict__ sc,
                           const float* __restrict__ dw, float* __restrict__ s){
    int gid = blockIdx.x; int r = gid >> 11; int bc = gid & 2047;
    int b = bc / CC_; int c = bc % CC_;
    int l = threadIdx.x; // 64
    __shared__ float sm[49];
    __shared__ float red[64];
    const float* fb = Fc + (size_t)bc*HWSZ;
    const float* si = sc + (size_t)r*NPIX + (size_t)b*HWSZ;
    const float* dwr = dw + (size_t)r*CC_*9;
    if (l < 49){
        int u = l/7, v = l%7;
        float sum = 0.f;
        for (int rr=0;rr<8;++rr){
            const float* rp = fb + (u*8+rr)*WW + v*8;
            const float* sp = si + (u*8+rr)*WW + v*8;
            #pragma unroll
            for (int q=0;q<8;++q) sum += rp[q] * sp[q];
        }
        sm[l] = sum * (1.f/64.f);
    }
    __syncthreads();
    float rv = 0.f;
    if (l < 49){
        float w[9];
        #pragma unroll
        for (int k=0;k<9;++k) w[k] = dwr[c*9+k];
        int u=l/7, v=l%7; float acc=0.f;
        #pragma unroll
        for (int ky=0;ky<3;++ky){ int uu=u+ky-1; if((unsigned)uu>=7u) continue;
            #pragma unroll
            for (int kx=0;kx<3;++kx){ int vv=v+kx-1; if((unsigned)vv>=7u) continue;
                acc += sm[uu*7+vv]*w[ky*3+kx]; } }
        rv = fmaxf(acc, 0.f);
    }
    red[l] = rv;
    __syncthreads();
    if (l==0){ float t=0.f; for(int i2=0;i2<64;++i2) t+=red[i2]; s[(size_t)r*BB*CC_ + bc] = t*(1.f/49.f); }
}

// K4b: head matvec + tanh -> Kw[r][b][t][c]. Fused: grid 144.
__global__ void k_akg_head(const float* __restrict__ s, const float* __restrict__ hw,
                           const float* __restrict__ hb, float* __restrict__ Kw){
    int gid = blockIdx.x; int r = gid / 72; int id = gid % 72;
    int b = id / 9; int og = id % 9;
    __shared__ float sv[CC_];
    int tid = threadIdx.x; // 256
    sv[tid] = s[(size_t)r*BB*CC_ + b*CC_ + tid];
    __syncthreads();
    int o = og*256 + tid;              // o = c*9 + t
    const float* wp = hw + (size_t)r*2304*CC_ + (size_t)o*CC_;
    float acc = hb[(size_t)r*2304 + o];
    for (int c2=0;c2<CC_;++c2) acc += wp[c2]*sv[c2];
    int c = o / 9, t = o - 9*c;
    Kw[((size_t)r*BB + b)*2304 + t*256 + c] = tanhf(acc);
}

// K5: deformable depthwise — wave-per-pixel channel-spanning loads, setup amortized over 28 pixels.
// Grid 1792: b=bx&7 (XCD pin); rest=bx>>3: xh=rest&1, y=(rest>>1)%56, creg=(rest>>1)/56.
// Setup: 252 threads compute 28 pixels x 9 taps descriptors. Main: wave w does pixels w*7..w*7+6.
__global__ __launch_bounds__(256) void k_deform(const bf16* __restrict__ Fp, const float* __restrict__ p,
                                                const float* __restrict__ Kw, bf16* __restrict__ outsN){
    __shared__ int   so[28][9][4];
    __shared__ float swt[28][9][4];
    int bx = blockIdx.x; int b = bx & 7; int rest = bx >> 3;
    int xh = rest & 1; int rest2 = rest >> 1; int y = rest2 % 56; int creg = rest2 / 56;
    int tid = threadIdx.x;
    const float* pr = p + (size_t)creg*BB*18*HWSZ;
    if (tid < 252){
        int t = tid / 28, pix = tid % 28;   // t-major: 28 consecutive x per t -> coalesced
        int x = xh*28 + pix;
        int ky = t / 3, kx = t % 3;
        float dy = pr[((size_t)b*18 + 2*t  )*HWSZ + y*WW + x];
        float dx = pr[((size_t)b*18 + 2*t+1)*HWSZ + y*WW + x];
        float py = (float)(y - 1 + ky) + dy;
        float px = (float)(x - 1 + kx) + dx;
        float y0f = floorf(py), x0f = floorf(px);
        float wy1 = py - y0f, wx1 = px - x0f;
        float wy0 = 1.f - wy1, wx0 = 1.f - wx1;
        float vy0 = (y0f >= 0.f  && y0f <= 55.f) ? 1.f : 0.f;
        float vy1 = (y0f >= -1.f && y0f <= 54.f) ? 1.f : 0.f;
        float vx0 = (x0f >= 0.f  && x0f <= 55.f) ? 1.f : 0.f;
        float vx1 = (x0f >= -1.f && x0f <= 54.f) ? 1.f : 0.f;
        int y0 = (int)y0f, x0i = (int)x0f;
        int iy0 = min(max(y0,0),55),    iy1 = min(max(y0+1,0),55);
        int ix0 = min(max(x0i,0),55),   ix1 = min(max(x0i+1,0),55);
        so[pix][t][0] = ((iy0+1)*58 + ix0+1)*256;
        so[pix][t][1] = ((iy0+1)*58 + ix1+1)*256;
        so[pix][t][2] = ((iy1+1)*58 + ix0+1)*256;
        so[pix][t][3] = ((iy1+1)*58 + ix1+1)*256;
        swt[pix][t][0] = wy0*wx0*vy0*vx0;
        swt[pix][t][1] = wy0*wx1*vy0*vx1;
        swt[pix][t][2] = wy1*wx0*vy1*vx0;
        swt[pix][t][3] = wy1*wx1*vy1*vx1;
    }
    __syncthreads();
    int w = tid >> 6, l = tid & 63;
    int cl = 4*l;
    const bf16* Fb = Fp + (size_t)creg*FPR + (size_t)b*58*58*256;
    const float* Kb = Kw + ((size_t)creg*BB + b)*2304;
    #pragma unroll 1
    for (int pp = 0; pp < 7; ++pp){
        int pix = w*7 + pp;
        int x = xh*28 + pix;
        float acc[4] = {0.f, 0.f, 0.f, 0.f};
        #pragma unroll
        for (int t = 0; t < 9; ++t){
            int o00 = so[pix][t][0], o01 = so[pix][t][1], o10 = so[pix][t][2], o11 = so[pix][t][3];
            float w00 = swt[pix][t][0], w01 = swt[pix][t][1], w10 = swt[pix][t][2], w11 = swt[pix][t][3];
            short4_t f00 = *(const short4_t*)(Fb + o00 + cl);
            short4_t f01 = *(const short4_t*)(Fb + o01 + cl);
            short4_t f10 = *(const short4_t*)(Fb + o10 + cl);
            short4_t f11 = *(const short4_t*)(Fb + o11 + cl);
            f32x4 kt = *(const f32x4*)(Kb + t*256 + cl);
            #pragma unroll
            for (int j = 0; j < 4; ++j){
                float v = w00*bs2f(f00[j]) + w01*bs2f(f01[j]) + w10*bs2f(f10[j]) + w11*bs2f(f11[j]);
                acc[j] += kt[j]*v;
            }
        }
        __attribute__((aligned(8))) bf16 tmp[4];
        #pragma unroll
        for (int j = 0; j < 4; ++j) tmp[j] = f2b(acc[j]);
        *(short4_t*)(outsN + ((size_t)b*HWSZ + y*WW + x)*512 + creg*256 + cl) = *(const short4_t*)tmp;
    }
}

// K6a: pw2 MFMA GEMM, stats pass + O store (fp32 NCHW; O aliases Fp which is dead by now).
__global__ __launch_bounds__(256) void k_pw2_mstats(const bf16* __restrict__ outsN, const bf16* __restrict__ Bpw,
                                                    const float* __restrict__ bias, float* __restrict__ partials,
                                                    float* __restrict__ O){
    __shared__ float ls[2][2][256];
    int tid = threadIdx.x; int wave = tid>>6, lane = tid&63;
    int pixGroup = wave>>1, ntH = wave&1;
    int m = lane&15, q = lane>>4;
    size_t pb = (size_t)blockIdx.x*32 + pixGroup*16;
    const bf16* Ap = outsN + (pb + m)*512 + q*8;
    f32x4 acc[8];
    #pragma unroll
    for (int i=0;i<8;++i) acc[i] = (f32x4){0,0,0,0};
    #pragma unroll 1
    for (int kk = 0; kk < 16; ++kk){
        short8 a = *(const short8*)(Ap + kk*32);
        const bf16* Bk = Bpw + (((size_t)kk*16 + ntH*8)*64 + lane)*8;
        #pragma unroll
        for (int nt2 = 0; nt2 < 8; ++nt2){
            short8 b = *(const short8*)(Bk + (size_t)nt2*64*8);
            acc[nt2] = __builtin_amdgcn_mfma_f32_16x16x32_bf16(a, b, acc[nt2], 0, 0, 0);
        }
    }
    int b_idx = (int)(pb / HWSZ);
    int yx0 = (int)(pb % HWSZ);
    #pragma unroll
    for (int nt2 = 0; nt2 < 8; ++nt2){
        int oc = ntH*128 + nt2*16 + m;
        float bv = bias[oc];
        float s1 = 0.f, s2 = 0.f;
        float* op = O + ((size_t)b_idx*CC_ + oc)*HWSZ + yx0 + q*4;
        #pragma unroll
        for (int r = 0; r < 4; ++r){
            float v = acc[nt2][r] + bv;
            op[r] = v;
            s1 += v; s2 += v*v;
        }
        s1 += __shfl_down(s1, 32); s1 += __shfl_down(s1, 16);
        s2 += __shfl_down(s2, 32); s2 += __shfl_down(s2, 16);
        if (q == 0){ ls[pixGroup][0][oc] = s1; ls[pixGroup][1][oc] = s2; }
    }
    __syncthreads();
    if (tid < 256){
        partials[(size_t)blockIdx.x*512 + tid]       = ls[0][0][tid] + ls[1][0][tid];
        partials[(size_t)blockIdx.x*512 + 256 + tid] = ls[0][1][tid] + ls[1][1][tid];
    }
}

// K6b: reduce partials -> bnp (mean, rsqrt).
__global__ void k_bnstat2(const float* __restrict__ partials, float* __restrict__ bnp){
    __shared__ float sm[512];
    int tid = threadIdx.x;           // 512
    float acc = 0.f;
    for (int blk = 0; blk < 784; ++blk) acc += partials[(size_t)blk*512 + tid];
    sm[tid] = acc;
    __syncthreads();
    if (tid < 256){
        float n = (float)NPIX;
        float mean = sm[tid] / n;
        float var = sm[256+tid] / n - mean*mean;
        var = fmaxf(var, 0.f);
        bnp[tid] = mean; bnp[256+tid] = rsqrtf(var + 1e-5f);
    }
}

// K6c: BN apply (elementwise, float4): out = (O - mean)*rsq*gamma + beta. Grid 6272.
__global__ __launch_bounds__(256) void k_bnapply(const float* __restrict__ O, const float* __restrict__ bnp,
                                                 const float* __restrict__ gamma, const float* __restrict__ beta,
                                                 float* __restrict__ out){
    int n = (blockIdx.x*256 + threadIdx.x)*4;   // HWSZ divisible by 4 -> same channel
    int c = (n / HWSZ) % CC_;
    float mean = bnp[c], rsq = bnp[256+c];
    float g = gamma[c], be = beta[c];
    f32x4 v = *(const f32x4*)(O + n);
    f32x4 o;
    #pragma unroll
    for (int j = 0; j < 4; ++j) o[j] = (v[j] - mean)*rsq*g + be;
    *(f32x4*)(out + n) = o;
}

extern "C" void kernel_launch(void* const* d_in, const int* in_sizes, int n_in,
                              void* d_out, int out_size, void* d_ws, size_t ws_size,
                              hipStream_t stream) {
    (void)in_sizes; (void)n_in; (void)out_size; (void)ws_size;
    const float* F_c    = (const float*)d_in[0];
    const float* dec_w  = (const float*)d_in[1];
    const float* dec_b  = (const float*)d_in[2];
    const float* off1_w = (const float*)d_in[3];
    const float* off1_b = (const float*)d_in[4];
    const float* off2_w = (const float*)d_in[5];
    const float* off2_b = (const float*)d_in[6];
    const float* akg_dw = (const float*)d_in[7];
    const float* akg_hw = (const float*)d_in[8];
    const float* akg_hb = (const float*)d_in[9];
    const float* pw2_w  = (const float*)d_in[10];
    const float* pw2_b  = (const float*)d_in[11];
    const float* gamma  = (const float*)d_in[12];
    const float* beta   = (const float*)d_in[13];
    float* out = (float*)d_out;

    char* ws = (char*)d_ws;
    size_t off = 0;
    auto alloc = [&](size_t bytes)->char*{
        char* r = ws + off;
        off = (off + bytes + 255) & ~(size_t)255;
        return r;
    };
    // Workspace ~67 MB.
    bf16*  Fp    = (bf16*) alloc(2*FPR*2);                 // padded NHWC F*sc, both regions
    bf16*  Bp    = (bf16*) alloc((size_t)2*9*8*4*64*8*2);  // conv1 weight frags
    bf16*  Bpw   = (bf16*) alloc((size_t)16*16*64*8*2);    // pw2 weight frags
    bf16*  Bc    = (bf16*) alloc((size_t)2*18*2*64*8*2);   // conv2 weight frags
    float* sc    = (float*)alloc((size_t)2*NPIX*4);
    bf16*  hp    = (bf16*) alloc(2*HPR*2);                 // padded NHWC hidden, both regions
    float* p     = (float*)alloc((size_t)2*BB*18*HWSZ*4);  // offsets, both regions
    float* s     = (float*)alloc((size_t)2*BB*CC_*4);
    float* Kw    = (float*)alloc((size_t)2*BB*CC_*9*4);
    bf16*  outsN = (bf16*) alloc(NPIX*512*2);              // NHWC, k = creg*256+c
    float* partials = (float*)alloc((size_t)784*512*4);
    float* bnp   = (float*)alloc(2*CC_*4);
    // O (fp32, 25.7MB) aliases Fp (27.6MB): Fp is dead after k_deform, O written in k_pw2_mstats.
    float* O = (float*)Fp;

    hipMemsetAsync(Fp, 0, 2*FPR*2, stream);                // zero borders for pad
    hipMemsetAsync(hp, 0, 2*HPR*2, stream);                // zero borders for conv2 pad

    k_scales<<<dim3((BB*HWSZ)/64), dim3(64), 0, stream>>>(F_c, dec_w, dec_b, sc);
    k_pack<<<dim3(BB*HH), dim3(256), 0, stream>>>(F_c, sc, Fp);
    k_bprep<<<dim3(576), dim3(64), 0, stream>>>(off1_w, Bp);
    k_bprep_pw<<<dim3(256), dim3(64), 0, stream>>>(pw2_w, Bpw);
    k_bprep_c2<<<dim3(72), dim3(64), 0, stream>>>(off2_w, Bc);

    // Region-fused pipeline.
    k_conv1<<<dim3(2*BB*HH), dim3(256), 0, stream>>>(Fp, Bp, off1_b, hp);
    k_conv2m<<<dim3(2*BB*HH), dim3(256), 0, stream>>>(hp, Bc, off2_b, p);
    k_akg_pool<<<dim3(2*BB*CC_), dim3(64), 0, stream>>>(F_c, sc, akg_dw, s);
    k_akg_head<<<dim3(2*BB*9), dim3(256), 0, stream>>>(s, akg_hw, akg_hb, Kw);
    k_deform<<<dim3(2*BB*HH*2), dim3(256), 0, stream>>>(Fp, p, Kw, outsN);

    k_pw2_mstats<<<dim3(784), dim3(256), 0, stream>>>(outsN, Bpw, pw2_b, partials, O);
    k_bnstat2<<<dim3(1), dim3(512), 0, stream>>>(partials, bnp);
    k_bnapply<<<dim3((int)(NPIX*CC_/1024)), dim3(256), 0, stream>>>(O, bnp, gamma, beta, out);
}

// Round 13
// 380.135 us; speedup vs baseline: 4.4320x; 1.0027x over previous
//
#include <hip/hip_runtime.h>
#include <hip/hip_bf16.h>

#define BB 8
#define CC_ 256
#define HH 56
#define WW 56
#define HWSZ (HH*WW)
#define RR_ 2
#define HID 64
#define FPR ((size_t)8*58*58*256)   // padded NHWC region elements
#define HPR ((size_t)8*58*58*64)    // padded NHWC hidden elements (per region)
#define NPIX ((size_t)BB*HWSZ)      // 25088

typedef __hip_bfloat16 bf16;
typedef __attribute__((ext_vector_type(8))) short short8;
typedef __attribute__((ext_vector_type(4))) short short4_t;
typedef __attribute__((ext_vector_type(4))) float f32x4;

struct Tap { int o00, o01, o10, o11; float w00, w01, w10, w11; };  // 32B

__device__ __forceinline__ float b2f(bf16 v){ return __bfloat162float(v); }
__device__ __forceinline__ bf16 f2b(float v){ return __float2bfloat16(v); }
__device__ __forceinline__ float bs2f(short s){ return __uint_as_float(((unsigned)(unsigned short)s)<<16); }

// K1: decoupler 1x1 conv + softmax(R=2); writes scale factors sc[r][b][yx] = 1 + M_r.
__global__ void k_scales(const float* __restrict__ F, const float* __restrict__ dec_w,
                         const float* __restrict__ dec_b, float* __restrict__ sc){
    __shared__ float w0[CC_], w1[CC_];
    int tid = threadIdx.x; // 64
    for (int c = tid; c < CC_; c += 64){ w0[c] = dec_w[c]; w1[c] = dec_w[CC_+c]; }
    __syncthreads();
    int pid = blockIdx.x*64 + tid;
    int b = pid / HWSZ, yx = pid % HWSZ;
    const float* base = F + (size_t)b*CC_*HWSZ + yx;
    float a0 = dec_b[0], a1 = dec_b[1];
    for (int c = 0; c < CC_; ++c){ float v = base[(size_t)c*HWSZ]; a0 += v*w0[c]; a1 += v*w1[c]; }
    float m = fmaxf(a0,a1);
    float e0 = __expf(a0-m), e1 = __expf(a1-m);
    float inv = 1.0f/(e0+e1);
    sc[pid]                  = 1.0f + e0*inv;
    sc[(size_t)BB*HWSZ+pid]  = 1.0f + e1*inv;
}

// K1b: pack Fp[r][b][gy+1][gx+1][c] = bf16(F[b][c][gy][gx] * sc_r). Writes its own borders
// (zeros): cols 0/57 of row gy+1; rows 0/57 via gy==0/55 blocks. No memset needed.
__global__ __launch_bounds__(256) void k_pack(const float* __restrict__ F, const float* __restrict__ sc,
                                              bf16* __restrict__ Fp){
    __shared__ bf16 lds[2][56][258];
    int bx = blockIdx.x; int b = bx/HH, gy = bx%HH;
    int tid = threadIdx.x; int x = tid & 63; int cq = tid >> 6;
    if (x < 56){
        const float* frow = F + (size_t)b*CC_*HWSZ + gy*WW + x;
        float s0 = sc[(size_t)b*HWSZ + gy*WW + x];
        float s1 = sc[(size_t)BB*HWSZ + (size_t)b*HWSZ + gy*WW + x];
        for (int cc = 0; cc < 64; ++cc){
            int c = cc*4 + cq;
            float v = frow[(size_t)c*HWSZ];
            lds[0][x][c] = f2b(v*s0);
            lds[1][x][c] = f2b(v*s1);
        }
    }
    __syncthreads();
    bf16 z = f2b(0.f);
    for (int r = 0; r < 2; ++r){
        bf16* slab = Fp + (size_t)r*FPR + (size_t)b*58*58*256;
        bf16* dst = slab + ((size_t)(gy+1)*58 + 1)*256 + tid;
        for (int x2 = 0; x2 < 56; ++x2) dst[(size_t)x2*256] = lds[r][x2][tid];
        // borders of this row
        bf16* rowp = slab + (size_t)(gy+1)*58*256;
        rowp[tid] = z;                 // col 0
        rowp[57*256 + tid] = z;        // col 57
        if (gy == 0){ for (int cidx = 0; cidx < 58; ++cidx) slab[(size_t)cidx*256 + tid] = z; }
        if (gy == 55){ bf16* r57 = slab + (size_t)57*58*256;
                       for (int cidx = 0; cidx < 58; ++cidx) r57[(size_t)cidx*256 + tid] = z; }
    }
}

// K1c: pack conv1 weights into MFMA B-fragment order.
__global__ void k_bprep(const float* __restrict__ w, bf16* __restrict__ Bp){
    int id = blockIdx.x;               // 2*9*8*4 = 576
    int nt = id & 3; id >>= 2; int icc = id & 7; id >>= 3; int t = id % 9; int r = id / 9;
    int L = threadIdx.x;               // 64
    int oc = nt*16 + (L&15);
    const float* wr = w + (size_t)r*HID*CC_*9;
    bf16* out = Bp + (((((size_t)r*9 + t)*8 + icc)*4 + nt)*64 + L)*8;
    #pragma unroll
    for (int j = 0; j < 8; ++j){
        int ic = icc*32 + (L>>4)*8 + j;
        out[j] = f2b(wr[((size_t)oc*CC_ + ic)*9 + t]);
    }
}

// K1d: pack pw2 weights (256 x 512) into B-frag order: Bpw[kk][nt][lane][j].
__global__ void k_bprep_pw(const float* __restrict__ w, bf16* __restrict__ Bpw){
    int id = blockIdx.x;               // 16*16 = 256
    int kk = id >> 4, nt = id & 15;
    int L = threadIdx.x;               // 64
    int oc = nt*16 + (L&15);
    bf16* out = Bpw + (((size_t)(kk*16+nt))*64 + L)*8;
    #pragma unroll
    for (int j = 0; j < 8; ++j){
        int ic = kk*32 + (L>>4)*8 + j;
        out[j] = f2b(w[(size_t)oc*512 + ic]);
    }
}

// K1e: pack conv2 weights into B-frag order, zero-padded to N=32.
__global__ void k_bprep_c2(const float* __restrict__ w, bf16* __restrict__ Bc){
    int id = blockIdx.x;               // 2*18*2 = 72
    int nt = id & 1; id >>= 1; int ks = id % 18; int r = id / 18;
    int t = ks >> 1, chunk = ks & 1;
    int L = threadIdx.x;               // 64
    int oc = nt*16 + (L&15);
    const float* wr = w + (size_t)r*18*HID*9;
    bf16* out = Bc + ((((size_t)r*18 + ks)*2 + nt)*64 + L)*8;
    #pragma unroll
    for (int j = 0; j < 8; ++j){
        int ic = chunk*32 + (L>>4)*8 + j;
        out[j] = (oc < 18) ? f2b(wr[((size_t)oc*HID + ic)*9 + t]) : f2b(0.f);
    }
}

// K2: conv3x3 256->64 via MFMA implicit GEMM, fused over regions. Writes hp borders (zeros).
__global__ __launch_bounds__(256) void k_conv1(const bf16* __restrict__ Fp, const bf16* __restrict__ Bp,
                                               const float* __restrict__ bias, bf16* __restrict__ hp){
    int bx = blockIdx.x; int b = bx & 7; int rid = bx >> 3; int y = rid % 56; int r = rid / 56;
    int tid = threadIdx.x; int wave = tid>>6, lane = tid&63;
    int m = lane&15, q = lane>>4;
    int x0 = (wave==3) ? 40 : wave*16;
    f32x4 acc0 = {0,0,0,0}, acc1 = {0,0,0,0}, acc2 = {0,0,0,0}, acc3 = {0,0,0,0};
    const bf16* Fb = Fp + (size_t)r*FPR + ((size_t)b*58*58)*256;
    const bf16* Bpr = Bp + (size_t)r*9*8*4*64*8;
    #pragma unroll
    for (int t = 0; t < 9; ++t){
        int ty = t/3, tx = t%3;
        const bf16* arow = Fb + ((size_t)(y+ty)*58 + (x0+m+tx))*256 + q*8;
        const bf16* brow = Bpr + ((size_t)t*8)*4*64*8 + lane*8;
        #pragma unroll
        for (int icc = 0; icc < 8; ++icc){
            short8 a  = *(const short8*)(arow + icc*32);
            const bf16* bb = brow + (size_t)icc*4*64*8;
            short8 b0 = *(const short8*)(bb);
            short8 b1 = *(const short8*)(bb + 64*8);
            short8 b2 = *(const short8*)(bb + 2*64*8);
            short8 b3 = *(const short8*)(bb + 3*64*8);
            acc0 = __builtin_amdgcn_mfma_f32_16x16x32_bf16(a, b0, acc0, 0, 0, 0);
            acc1 = __builtin_amdgcn_mfma_f32_16x16x32_bf16(a, b1, acc1, 0, 0, 0);
            acc2 = __builtin_amdgcn_mfma_f32_16x16x32_bf16(a, b2, acc2, 0, 0, 0);
            acc3 = __builtin_amdgcn_mfma_f32_16x16x32_bf16(a, b3, acc3, 0, 0, 0);
        }
    }
    f32x4 accs[4] = {acc0, acc1, acc2, acc3};
    const float* br = bias + r*HID;
    bf16* slab = hp + (size_t)r*HPR + (size_t)b*58*58*64;
    bf16* hrow = slab + ((size_t)(y+1)*58 + 1)*64;
    #pragma unroll
    for (int nt = 0; nt < 4; ++nt){
        int oc = nt*16 + m;
        float bv = br[oc];
        #pragma unroll
        for (int r2 = 0; r2 < 4; ++r2){
            int x = x0 + q*4 + r2;
            hrow[(size_t)x*64 + oc] = f2b(fmaxf(accs[nt][r2] + bv, 0.f));
        }
    }
    // borders (zeros)
    bf16 z = f2b(0.f);
    bf16* rowp = slab + (size_t)(y+1)*58*64;
    if (tid < 64) rowp[tid] = z;                        // col 0
    else if (tid < 128) rowp[57*64 + (tid-64)] = z;     // col 57
    if (y == 0){ for (int idx = tid; idx < 58*64; idx += 256) slab[idx] = z; }
    if (y == 55){ bf16* r57 = slab + (size_t)57*58*64;
                  for (int idx = tid; idx < 58*64; idx += 256) r57[idx] = z; }
}

// K3: conv2 via MFMA implicit GEMM on padded NHWC hp, fused over regions. Grid 896.
__global__ __launch_bounds__(256) void k_conv2m(const bf16* __restrict__ hp, const bf16* __restrict__ Bc,
                                                const float* __restrict__ bias, float* __restrict__ p){
    int bx = blockIdx.x; int b = bx & 7; int rid = bx >> 3; int y = rid % 56; int r = rid / 56;
    int tid = threadIdx.x; int wave = tid>>6, lane = tid&63;
    int m = lane&15, q = lane>>4;
    int x0 = (wave==3) ? 40 : wave*16;
    f32x4 acc0 = {0,0,0,0}, acc1 = {0,0,0,0};
    const bf16* Hb = hp + (size_t)r*HPR + ((size_t)b*58 + y)*58*64;
    const bf16* Bcr = Bc + (size_t)r*18*2*64*8;
    #pragma unroll
    for (int t = 0; t < 9; ++t){
        int ty = t/3, tx = t%3;
        const bf16* arow = Hb + ((size_t)ty*58 + (x0+m+tx))*64 + q*8;
        #pragma unroll
        for (int chunk = 0; chunk < 2; ++chunk){
            short8 a = *(const short8*)(arow + chunk*32);
            const bf16* bb = Bcr + (((size_t)(t*2+chunk))*2*64 + lane)*8;
            short8 b0 = *(const short8*)(bb);
            short8 b1 = *(const short8*)(bb + 64*8);
            acc0 = __builtin_amdgcn_mfma_f32_16x16x32_bf16(a, b0, acc0, 0, 0, 0);
            acc1 = __builtin_amdgcn_mfma_f32_16x16x32_bf16(a, b1, acc1, 0, 0, 0);
        }
    }
    const float* br = bias + r*18;
    float* pr = p + (size_t)r*BB*18*HWSZ;
    #pragma unroll
    for (int r2 = 0; r2 < 4; ++r2){
        int x = x0 + q*4 + r2;
        {
            float v = acc0[r2] + br[m];
            pr[((size_t)b*18 + m)*HWSZ + y*WW + x] = v;
        }
        if (m < 2){
            float v = acc1[r2] + br[16+m];
            pr[((size_t)b*18 + 16+m)*HWSZ + y*WW + x] = v;
        }
    }
}

// K4a: 8x8 avg pool (56->7), depthwise 3x3 + relu, global mean -> s[r][b][c]. Fused: grid 4096.
__global__ void k_akg_pool(const float* __restrict__ Fc, const float* __restrict__ sc,
                           const float* __restrict__ dw, float* __restrict__ s){
    int gid = blockIdx.x; int r = gid >> 11; int bc = gid & 2047;
    int b = bc / CC_; int c = bc % CC_;
    int l = threadIdx.x; // 64
    __shared__ float sm[49];
    __shared__ float red[64];
    const float* fb = Fc + (size_t)bc*HWSZ;
    const float* si = sc + (size_t)r*NPIX + (size_t)b*HWSZ;
    const float* dwr = dw + (size_t)r*CC_*9;
    if (l < 49){
        int u = l/7, v = l%7;
        float sum = 0.f;
        for (int rr=0;rr<8;++rr){
            const float* rp = fb + (u*8+rr)*WW + v*8;
            const float* sp = si + (u*8+rr)*WW + v*8;
            #pragma unroll
            for (int q=0;q<8;++q) sum += rp[q] * sp[q];
        }
        sm[l] = sum * (1.f/64.f);
    }
    __syncthreads();
    float rv = 0.f;
    if (l < 49){
        float w[9];
        #pragma unroll
        for (int k=0;k<9;++k) w[k] = dwr[c*9+k];
        int u=l/7, v=l%7; float acc=0.f;
        #pragma unroll
        for (int ky=0;ky<3;++ky){ int uu=u+ky-1; if((unsigned)uu>=7u) continue;
            #pragma unroll
            for (int kx=0;kx<3;++kx){ int vv=v+kx-1; if((unsigned)vv>=7u) continue;
                acc += sm[uu*7+vv]*w[ky*3+kx]; } }
        rv = fmaxf(acc, 0.f);
    }
    red[l] = rv;
    __syncthreads();
    if (l==0){ float t=0.f; for(int i2=0;i2<64;++i2) t+=red[i2]; s[(size_t)r*BB*CC_ + bc] = t*(1.f/49.f); }
}

// K4b: head matvec + tanh -> Kw[r][b][t][c]. Fused: grid 144.
__global__ void k_akg_head(const float* __restrict__ s, const float* __restrict__ hw,
                           const float* __restrict__ hb, float* __restrict__ Kw){
    int gid = blockIdx.x; int r = gid / 72; int id = gid % 72;
    int b = id / 9; int og = id % 9;
    __shared__ float sv[CC_];
    int tid = threadIdx.x; // 256
    sv[tid] = s[(size_t)r*BB*CC_ + b*CC_ + tid];
    __syncthreads();
    int o = og*256 + tid;              // o = c*9 + t
    const float* wp = hw + (size_t)r*2304*CC_ + (size_t)o*CC_;
    float acc = hb[(size_t)r*2304 + o];
    for (int c2=0;c2<CC_;++c2) acc += wp[c2]*sv[c2];
    int c = o / 9, t = o - 9*c;
    Kw[((size_t)r*BB + b)*2304 + t*256 + c] = tanhf(acc);
}

// K5a: tap descriptor precompute. Thread per pixel (n = (creg*8+b)*3136 + yx), 9 taps each.
// Coalesced p reads; 288B contiguous descriptor writes per thread.
__global__ __launch_bounds__(256) void k_tapprep(const float* __restrict__ p, Tap* __restrict__ tap){
    int n = blockIdx.x*256 + threadIdx.x;   // 50176 total, grid 196
    int cb = n / 3136; int yx = n - cb*3136;
    int creg = cb >> 3; int b = cb & 7;
    int y = yx / 56, x = yx - (yx/56)*56;
    const float* pr = p + (size_t)creg*BB*18*HWSZ + (size_t)b*18*HWSZ;
    Tap* out = tap + (size_t)n*9;
    #pragma unroll
    for (int t = 0; t < 9; ++t){
        int ky = t / 3, kx = t % 3;
        float dy = pr[(size_t)(2*t)*HWSZ + yx];
        float dx = pr[(size_t)(2*t+1)*HWSZ + yx];
        float py = (float)(y - 1 + ky) + dy;
        float px = (float)(x - 1 + kx) + dx;
        float y0f = floorf(py), x0f = floorf(px);
        float wy1 = py - y0f, wx1 = px - x0f;
        float wy0 = 1.f - wy1, wx0 = 1.f - wx1;
        float vy0 = (y0f >= 0.f  && y0f <= 55.f) ? 1.f : 0.f;
        float vy1 = (y0f >= -1.f && y0f <= 54.f) ? 1.f : 0.f;
        float vx0 = (x0f >= 0.f  && x0f <= 55.f) ? 1.f : 0.f;
        float vx1 = (x0f >= -1.f && x0f <= 54.f) ? 1.f : 0.f;
        int y0 = (int)y0f, x0i = (int)x0f;
        int iy0 = min(max(y0,0),55),    iy1 = min(max(y0+1,0),55);
        int ix0 = min(max(x0i,0),55),   ix1 = min(max(x0i+1,0),55);
        Tap td;
        td.o00 = ((iy0+1)*58 + ix0+1)*256;
        td.o01 = ((iy0+1)*58 + ix1+1)*256;
        td.o10 = ((iy1+1)*58 + ix0+1)*256;
        td.o11 = ((iy1+1)*58 + ix1+1)*256;
        td.w00 = wy0*wx0*vy0*vx0;
        td.w01 = wy0*wx1*vy0*vx1;
        td.w10 = wy1*wx0*vy1*vx0;
        td.w11 = wy1*wx1*vy1*vx1;
        out[t] = td;
    }
}

// K5b: deformable depthwise — wave per pixel, no LDS, no sync. Descriptors via wave-uniform
// (scalar) loads; 9 taps unrolled -> 45 independent VMEM loads in flight. Grid 12544, b=bx&7.
__global__ __launch_bounds__(256) void k_deform(const bf16* __restrict__ Fp, const Tap* __restrict__ tap,
                                                const float* __restrict__ Kw, bf16* __restrict__ outsN){
    int bx = blockIdx.x; int b = bx & 7; int rest = bx >> 3;  // rest = creg*784 + pg
    int pg = rest % 784; int creg = rest / 784;
    int tid = threadIdx.x; int w = tid >> 6, l = tid & 63;
    int wu = __builtin_amdgcn_readfirstlane(w);               // wave-uniform -> scalar addressing
    int yx = pg*4 + wu;
    size_t pid = ((size_t)(creg*8 + b))*3136 + yx;
    const Tap* td = tap + pid*9;
    const bf16* Fb = Fp + (size_t)creg*FPR + (size_t)b*58*58*256;
    const float* Kb = Kw + ((size_t)creg*8 + b)*2304;
    int cl = 4*l;
    float acc[4] = {0.f, 0.f, 0.f, 0.f};
    #pragma unroll
    for (int t = 0; t < 9; ++t){
        Tap d = td[t];
        short4_t f00 = *(const short4_t*)(Fb + d.o00 + cl);
        short4_t f01 = *(const short4_t*)(Fb + d.o01 + cl);
        short4_t f10 = *(const short4_t*)(Fb + d.o10 + cl);
        short4_t f11 = *(const short4_t*)(Fb + d.o11 + cl);
        f32x4 kt = *(const f32x4*)(Kb + t*256 + cl);
        #pragma unroll
        for (int j = 0; j < 4; ++j){
            float v = d.w00*bs2f(f00[j]) + d.w01*bs2f(f01[j]) + d.w10*bs2f(f10[j]) + d.w11*bs2f(f11[j]);
            acc[j] += kt[j]*v;
        }
    }
    __attribute__((aligned(8))) bf16 tmp[4];
    #pragma unroll
    for (int j = 0; j < 4; ++j) tmp[j] = f2b(acc[j]);
    *(short4_t*)(outsN + ((size_t)b*HWSZ + yx)*512 + creg*256 + cl) = *(const short4_t*)tmp;
}

// K6a: pw2 MFMA GEMM, stats pass + O store (fp32 NCHW; O aliases Fp which is dead by now).
__global__ __launch_bounds__(256) void k_pw2_mstats(const bf16* __restrict__ outsN, const bf16* __restrict__ Bpw,
                                                    const float* __restrict__ bias, float* __restrict__ partials,
                                                    float* __restrict__ O){
    __shared__ float ls[2][2][256];
    int tid = threadIdx.x; int wave = tid>>6, lane = tid&63;
    int pixGroup = wave>>1, ntH = wave&1;
    int m = lane&15, q = lane>>4;
    size_t pb = (size_t)blockIdx.x*32 + pixGroup*16;
    const bf16* Ap = outsN + (pb + m)*512 + q*8;
    f32x4 acc[8];
    #pragma unroll
    for (int i=0;i<8;++i) acc[i] = (f32x4){0,0,0,0};
    #pragma unroll 1
    for (int kk = 0; kk < 16; ++kk){
        short8 a = *(const short8*)(Ap + kk*32);
        const bf16* Bk = Bpw + (((size_t)kk*16 + ntH*8)*64 + lane)*8;
        #pragma unroll
        for (int nt2 = 0; nt2 < 8; ++nt2){
            short8 b = *(const short8*)(Bk + (size_t)nt2*64*8);
            acc[nt2] = __builtin_amdgcn_mfma_f32_16x16x32_bf16(a, b, acc[nt2], 0, 0, 0);
        }
    }
    int b_idx = (int)(pb / HWSZ);
    int yx0 = (int)(pb % HWSZ);
    #pragma unroll
    for (int nt2 = 0; nt2 < 8; ++nt2){
        int oc = ntH*128 + nt2*16 + m;
        float bv = bias[oc];
        float s1 = 0.f, s2 = 0.f;
        float* op = O + ((size_t)b_idx*CC_ + oc)*HWSZ + yx0 + q*4;
        #pragma unroll
        for (int r = 0; r < 4; ++r){
            float v = acc[nt2][r] + bv;
            op[r] = v;
            s1 += v; s2 += v*v;
        }
        s1 += __shfl_down(s1, 32); s1 += __shfl_down(s1, 16);
        s2 += __shfl_down(s2, 32); s2 += __shfl_down(s2, 16);
        if (q == 0){ ls[pixGroup][0][oc] = s1; ls[pixGroup][1][oc] = s2; }
    }
    __syncthreads();
    if (tid < 256){
        partials[(size_t)blockIdx.x*512 + tid]       = ls[0][0][tid] + ls[1][0][tid];
        partials[(size_t)blockIdx.x*512 + 256 + tid] = ls[0][1][tid] + ls[1][1][tid];
    }
}

// K6b: reduce partials -> bnp (mean, rsqrt).
__global__ void k_bnstat2(const float* __restrict__ partials, float* __restrict__ bnp){
    __shared__ float sm[512];
    int tid = threadIdx.x;           // 512
    float acc = 0.f;
    for (int blk = 0; blk < 784; ++blk) acc += partials[(size_t)blk*512 + tid];
    sm[tid] = acc;
    __syncthreads();
    if (tid < 256){
        float n = (float)NPIX;
        float mean = sm[tid] / n;
        float var = sm[256+tid] / n - mean*mean;
        var = fmaxf(var, 0.f);
        bnp[tid] = mean; bnp[256+tid] = rsqrtf(var + 1e-5f);
    }
}

// K6c: BN apply (elementwise, float4): out = (O - mean)*rsq*gamma + beta. Grid 6272.
__global__ __launch_bounds__(256) void k_bnapply(const float* __restrict__ O, const float* __restrict__ bnp,
                                                 const float* __restrict__ gamma, const float* __restrict__ beta,
                                                 float* __restrict__ out){
    int n = (blockIdx.x*256 + threadIdx.x)*4;   // HWSZ divisible by 4 -> same channel
    int c = (n / HWSZ) % CC_;
    float mean = bnp[c], rsq = bnp[256+c];
    float g = gamma[c], be = beta[c];
    f32x4 v = *(const f32x4*)(O + n);
    f32x4 o;
    #pragma unroll
    for (int j = 0; j < 4; ++j) o[j] = (v[j] - mean)*rsq*g + be;
    *(f32x4*)(out + n) = o;
}

extern "C" void kernel_launch(void* const* d_in, const int* in_sizes, int n_in,
                              void* d_out, int out_size, void* d_ws, size_t ws_size,
                              hipStream_t stream) {
    (void)in_sizes; (void)n_in; (void)out_size; (void)ws_size;
    const float* F_c    = (const float*)d_in[0];
    const float* dec_w  = (const float*)d_in[1];
    const float* dec_b  = (const float*)d_in[2];
    const float* off1_w = (const float*)d_in[3];
    const float* off1_b = (const float*)d_in[4];
    const float* off2_w = (const float*)d_in[5];
    const float* off2_b = (const float*)d_in[6];
    const float* akg_dw = (const float*)d_in[7];
    const float* akg_hw = (const float*)d_in[8];
    const float* akg_hb = (const float*)d_in[9];
    const float* pw2_w  = (const float*)d_in[10];
    const float* pw2_b  = (const float*)d_in[11];
    const float* gamma  = (const float*)d_in[12];
    const float* beta   = (const float*)d_in[13];
    float* out = (float*)d_out;

    char* ws = (char*)d_ws;
    size_t off = 0;
    auto alloc = [&](size_t bytes)->char*{
        char* r = ws + off;
        off = (off + bytes + 255) & ~(size_t)255;
        return r;
    };
    // Workspace ~82 MB.
    bf16*  Fp    = (bf16*) alloc(2*FPR*2);                 // padded NHWC F*sc, both regions
    bf16*  Bp    = (bf16*) alloc((size_t)2*9*8*4*64*8*2);  // conv1 weight frags
    bf16*  Bpw   = (bf16*) alloc((size_t)16*16*64*8*2);    // pw2 weight frags
    bf16*  Bc    = (bf16*) alloc((size_t)2*18*2*64*8*2);   // conv2 weight frags
    float* sc    = (float*)alloc((size_t)2*NPIX*4);
    bf16*  hp    = (bf16*) alloc(2*HPR*2);                 // padded NHWC hidden, both regions
    float* p     = (float*)alloc((size_t)2*BB*18*HWSZ*4);  // offsets, both regions
    float* s     = (float*)alloc((size_t)2*BB*CC_*4);
    float* Kw    = (float*)alloc((size_t)2*BB*CC_*9*4);
    bf16*  outsN = (bf16*) alloc(NPIX*512*2);              // NHWC, k = creg*256+c
    Tap*   tap   = (Tap*)  alloc((size_t)2*NPIX*9*sizeof(Tap));
    float* partials = (float*)alloc((size_t)784*512*4);
    float* bnp   = (float*)alloc(2*CC_*4);
    // O (fp32, 25.7MB) aliases Fp (27.6MB): Fp is dead after k_deform, O written in k_pw2_mstats.
    float* O = (float*)Fp;

    k_scales<<<dim3((BB*HWSZ)/64), dim3(64), 0, stream>>>(F_c, dec_w, dec_b, sc);
    k_pack<<<dim3(BB*HH), dim3(256), 0, stream>>>(F_c, sc, Fp);
    k_bprep<<<dim3(576), dim3(64), 0, stream>>>(off1_w, Bp);
    k_bprep_pw<<<dim3(256), dim3(64), 0, stream>>>(pw2_w, Bpw);
    k_bprep_c2<<<dim3(72), dim3(64), 0, stream>>>(off2_w, Bc);

    // Region-fused pipeline.
    k_conv1<<<dim3(2*BB*HH), dim3(256), 0, stream>>>(Fp, Bp, off1_b, hp);
    k_conv2m<<<dim3(2*BB*HH), dim3(256), 0, stream>>>(hp, Bc, off2_b, p);
    k_akg_pool<<<dim3(2*BB*CC_), dim3(64), 0, stream>>>(F_c, sc, akg_dw, s);
    k_akg_head<<<dim3(2*BB*9), dim3(256), 0, stream>>>(s, akg_hw, akg_hb, Kw);
    k_tapprep<<<dim3(196), dim3(256), 0, stream>>>(p, tap);
    k_deform<<<dim3(2*BB*784), dim3(256), 0, stream>>>(Fp, tap, Kw, outsN);

    k_pw2_mstats<<<dim3(784), dim3(256), 0, stream>>>(outsN, Bpw, pw2_b, partials, O);
    k_bnstat2<<<dim3(1), dim3(512), 0, stream>>>(partials, bnp);
    k_bnapply<<<dim3((int)(NPIX*CC_/1024)), dim3(256), 0, stream>>>(O, bnp, gamma, beta, out);
}

// Round 14
// 369.809 us; speedup vs baseline: 4.5558x; 1.0279x over previous
//
#include <hip/hip_runtime.h>
#include <hip/hip_bf16.h>

#define BB 8
#define CC_ 256
#define HH 56
#define WW 56
#define HWSZ (HH*WW)
#define RR_ 2
#define HID 64
#define FPR ((size_t)8*58*58*256)   // padded NHWC region elements
#define HPR ((size_t)8*58*58*64)    // padded NHWC hidden elements (per region)
#define NPIX ((size_t)BB*HWSZ)      // 25088

typedef __hip_bfloat16 bf16;
typedef __attribute__((ext_vector_type(8))) short short8;
typedef __attribute__((ext_vector_type(4))) short short4_t;
typedef __attribute__((ext_vector_type(4))) float f32x4;
typedef __attribute__((ext_vector_type(4))) int i32x4;

struct Tap { int o00, o01, o10, o11; float w00, w01, w10, w11; };  // 32B

__device__ __forceinline__ float b2f(bf16 v){ return __bfloat162float(v); }
__device__ __forceinline__ bf16 f2b(float v){ return __float2bfloat16(v); }
__device__ __forceinline__ float bs2f(short s){ return __uint_as_float(((unsigned)(unsigned short)s)<<16); }

// K1: fused decoupler (1x1 conv + softmax) + NHWC bf16 pack of both F_i = F*sc_r regions.
// Block per (b,gy). LDS fp32 row-tile read once; F_c is streamed exactly once.
// Writes Fp borders (zeros) itself; also writes sc (used by akg_pool).
__global__ __launch_bounds__(256) void k_scalepack(const float* __restrict__ F, const float* __restrict__ dec_w,
                                                   const float* __restrict__ dec_b, float* __restrict__ sc,
                                                   bf16* __restrict__ Fp){
    __shared__ float lds_f[256][57];   // [c][x], pad 57 -> conflict-free both phases
    __shared__ float lw0[256], lw1[256];
    __shared__ float ls0[56], ls1[56];
    int bx = blockIdx.x; int b = bx/HH, gy = bx%HH;
    int tid = threadIdx.x;
    lw0[tid] = dec_w[tid]; lw1[tid] = dec_w[CC_+tid];
    const float* Fb = F + (size_t)b*CC_*HWSZ + gy*WW;
    for (int it = 0; it < 56; ++it){
        int idx = it*256 + tid;
        int c = idx / 56, x = idx - c*56;
        lds_f[c][x] = Fb[(size_t)c*HWSZ + x];
    }
    __syncthreads();
    if (tid < 56){
        float a0 = dec_b[0], a1 = dec_b[1];
        for (int c = 0; c < CC_; ++c){ float v = lds_f[c][tid]; a0 += v*lw0[c]; a1 += v*lw1[c]; }
        float m = fmaxf(a0,a1);
        float e0 = __expf(a0-m), e1 = __expf(a1-m);
        float inv = 1.0f/(e0+e1);
        float s0 = 1.0f + e0*inv, s1 = 1.0f + e1*inv;
        ls0[tid] = s0; ls1[tid] = s1;
        sc[(size_t)b*HWSZ + gy*WW + tid] = s0;
        sc[(size_t)BB*HWSZ + (size_t)b*HWSZ + gy*WW + tid] = s1;
    }
    __syncthreads();
    bf16 z = f2b(0.f);
    for (int r = 0; r < 2; ++r){
        const float* lsr = r ? ls1 : ls0;
        bf16* slab = Fp + (size_t)r*FPR + (size_t)b*58*58*256;
        bf16* dst = slab + ((size_t)(gy+1)*58 + 1)*256 + tid;
        for (int x2 = 0; x2 < 56; ++x2) dst[(size_t)x2*256] = f2b(lds_f[tid][x2] * lsr[x2]);
        bf16* rowp = slab + (size_t)(gy+1)*58*256;
        rowp[tid] = z;                 // col 0
        rowp[57*256 + tid] = z;        // col 57
        if (gy == 0){ for (int cidx = 0; cidx < 58; ++cidx) slab[(size_t)cidx*256 + tid] = z; }
        if (gy == 55){ bf16* r57 = slab + (size_t)57*58*256;
                       for (int cidx = 0; cidx < 58; ++cidx) r57[(size_t)cidx*256 + tid] = z; }
    }
}

// K1c: pack conv1 weights into MFMA B-fragment order.
__global__ void k_bprep(const float* __restrict__ w, bf16* __restrict__ Bp){
    int id = blockIdx.x;               // 2*9*8*4 = 576
    int nt = id & 3; id >>= 2; int icc = id & 7; id >>= 3; int t = id % 9; int r = id / 9;
    int L = threadIdx.x;               // 64
    int oc = nt*16 + (L&15);
    const float* wr = w + (size_t)r*HID*CC_*9;
    bf16* out = Bp + (((((size_t)r*9 + t)*8 + icc)*4 + nt)*64 + L)*8;
    #pragma unroll
    for (int j = 0; j < 8; ++j){
        int ic = icc*32 + (L>>4)*8 + j;
        out[j] = f2b(wr[((size_t)oc*CC_ + ic)*9 + t]);
    }
}

// K1d: pack pw2 weights (256 x 512) into B-frag order: Bpw[kk][nt][lane][j].
__global__ void k_bprep_pw(const float* __restrict__ w, bf16* __restrict__ Bpw){
    int id = blockIdx.x;               // 16*16 = 256
    int kk = id >> 4, nt = id & 15;
    int L = threadIdx.x;               // 64
    int oc = nt*16 + (L&15);
    bf16* out = Bpw + (((size_t)(kk*16+nt))*64 + L)*8;
    #pragma unroll
    for (int j = 0; j < 8; ++j){
        int ic = kk*32 + (L>>4)*8 + j;
        out[j] = f2b(w[(size_t)oc*512 + ic]);
    }
}

// K1e: pack conv2 weights into B-frag order, zero-padded to N=32.
__global__ void k_bprep_c2(const float* __restrict__ w, bf16* __restrict__ Bc){
    int id = blockIdx.x;               // 2*18*2 = 72
    int nt = id & 1; id >>= 1; int ks = id % 18; int r = id / 18;
    int t = ks >> 1, chunk = ks & 1;
    int L = threadIdx.x;               // 64
    int oc = nt*16 + (L&15);
    const float* wr = w + (size_t)r*18*HID*9;
    bf16* out = Bc + ((((size_t)r*18 + ks)*2 + nt)*64 + L)*8;
    #pragma unroll
    for (int j = 0; j < 8; ++j){
        int ic = chunk*32 + (L>>4)*8 + j;
        out[j] = (oc < 18) ? f2b(wr[((size_t)oc*HID + ic)*9 + t]) : f2b(0.f);
    }
}

// K2: conv3x3 256->64 via MFMA implicit GEMM, fused over regions. Writes hp borders (zeros).
__global__ __launch_bounds__(256) void k_conv1(const bf16* __restrict__ Fp, const bf16* __restrict__ Bp,
                                               const float* __restrict__ bias, bf16* __restrict__ hp){
    int bx = blockIdx.x; int b = bx & 7; int rid = bx >> 3; int y = rid % 56; int r = rid / 56;
    int tid = threadIdx.x; int wave = tid>>6, lane = tid&63;
    int m = lane&15, q = lane>>4;
    int x0 = (wave==3) ? 40 : wave*16;
    f32x4 acc0 = {0,0,0,0}, acc1 = {0,0,0,0}, acc2 = {0,0,0,0}, acc3 = {0,0,0,0};
    const bf16* Fb = Fp + (size_t)r*FPR + ((size_t)b*58*58)*256;
    const bf16* Bpr = Bp + (size_t)r*9*8*4*64*8;
    #pragma unroll
    for (int t = 0; t < 9; ++t){
        int ty = t/3, tx = t%3;
        const bf16* arow = Fb + ((size_t)(y+ty)*58 + (x0+m+tx))*256 + q*8;
        const bf16* brow = Bpr + ((size_t)t*8)*4*64*8 + lane*8;
        #pragma unroll
        for (int icc = 0; icc < 8; ++icc){
            short8 a  = *(const short8*)(arow + icc*32);
            const bf16* bb = brow + (size_t)icc*4*64*8;
            short8 b0 = *(const short8*)(bb);
            short8 b1 = *(const short8*)(bb + 64*8);
            short8 b2 = *(const short8*)(bb + 2*64*8);
            short8 b3 = *(const short8*)(bb + 3*64*8);
            acc0 = __builtin_amdgcn_mfma_f32_16x16x32_bf16(a, b0, acc0, 0, 0, 0);
            acc1 = __builtin_amdgcn_mfma_f32_16x16x32_bf16(a, b1, acc1, 0, 0, 0);
            acc2 = __builtin_amdgcn_mfma_f32_16x16x32_bf16(a, b2, acc2, 0, 0, 0);
            acc3 = __builtin_amdgcn_mfma_f32_16x16x32_bf16(a, b3, acc3, 0, 0, 0);
        }
    }
    f32x4 accs[4] = {acc0, acc1, acc2, acc3};
    const float* br = bias + r*HID;
    bf16* slab = hp + (size_t)r*HPR + (size_t)b*58*58*64;
    bf16* hrow = slab + ((size_t)(y+1)*58 + 1)*64;
    #pragma unroll
    for (int nt = 0; nt < 4; ++nt){
        int oc = nt*16 + m;
        float bv = br[oc];
        #pragma unroll
        for (int r2 = 0; r2 < 4; ++r2){
            int x = x0 + q*4 + r2;
            hrow[(size_t)x*64 + oc] = f2b(fmaxf(accs[nt][r2] + bv, 0.f));
        }
    }
    // borders (zeros)
    bf16 z = f2b(0.f);
    bf16* rowp = slab + (size_t)(y+1)*58*64;
    if (tid < 64) rowp[tid] = z;                        // col 0
    else if (tid < 128) rowp[57*64 + (tid-64)] = z;     // col 57
    if (y == 0){ for (int idx = tid; idx < 58*64; idx += 256) slab[idx] = z; }
    if (y == 55){ bf16* r57 = slab + (size_t)57*58*64;
                  for (int idx = tid; idx < 58*64; idx += 256) r57[idx] = z; }
}

// K3: conv2 via MFMA implicit GEMM on padded NHWC hp, fused over regions. Grid 896.
__global__ __launch_bounds__(256) void k_conv2m(const bf16* __restrict__ hp, const bf16* __restrict__ Bc,
                                                const float* __restrict__ bias, float* __restrict__ p){
    int bx = blockIdx.x; int b = bx & 7; int rid = bx >> 3; int y = rid % 56; int r = rid / 56;
    int tid = threadIdx.x; int wave = tid>>6, lane = tid&63;
    int m = lane&15, q = lane>>4;
    int x0 = (wave==3) ? 40 : wave*16;
    f32x4 acc0 = {0,0,0,0}, acc1 = {0,0,0,0};
    const bf16* Hb = hp + (size_t)r*HPR + ((size_t)b*58 + y)*58*64;
    const bf16* Bcr = Bc + (size_t)r*18*2*64*8;
    #pragma unroll
    for (int t = 0; t < 9; ++t){
        int ty = t/3, tx = t%3;
        const bf16* arow = Hb + ((size_t)ty*58 + (x0+m+tx))*64 + q*8;
        #pragma unroll
        for (int chunk = 0; chunk < 2; ++chunk){
            short8 a = *(const short8*)(arow + chunk*32);
            const bf16* bb = Bcr + (((size_t)(t*2+chunk))*2*64 + lane)*8;
            short8 b0 = *(const short8*)(bb);
            short8 b1 = *(const short8*)(bb + 64*8);
            acc0 = __builtin_amdgcn_mfma_f32_16x16x32_bf16(a, b0, acc0, 0, 0, 0);
            acc1 = __builtin_amdgcn_mfma_f32_16x16x32_bf16(a, b1, acc1, 0, 0, 0);
        }
    }
    const float* br = bias + r*18;
    float* pr = p + (size_t)r*BB*18*HWSZ;
    #pragma unroll
    for (int r2 = 0; r2 < 4; ++r2){
        int x = x0 + q*4 + r2;
        {
            float v = acc0[r2] + br[m];
            pr[((size_t)b*18 + m)*HWSZ + y*WW + x] = v;
        }
        if (m < 2){
            float v = acc1[r2] + br[16+m];
            pr[((size_t)b*18 + 16+m)*HWSZ + y*WW + x] = v;
        }
    }
}

// K4a: 8x8 avg pool (56->7), depthwise 3x3 + relu, global mean -> s[r][b][c]. Fused: grid 4096.
__global__ void k_akg_pool(const float* __restrict__ Fc, const float* __restrict__ sc,
                           const float* __restrict__ dw, float* __restrict__ s){
    int gid = blockIdx.x; int r = gid >> 11; int bc = gid & 2047;
    int b = bc / CC_; int c = bc % CC_;
    int l = threadIdx.x; // 64
    __shared__ float sm[49];
    __shared__ float red[64];
    const float* fb = Fc + (size_t)bc*HWSZ;
    const float* si = sc + (size_t)r*NPIX + (size_t)b*HWSZ;
    const float* dwr = dw + (size_t)r*CC_*9;
    if (l < 49){
        int u = l/7, v = l%7;
        float sum = 0.f;
        for (int rr=0;rr<8;++rr){
            const float* rp = fb + (u*8+rr)*WW + v*8;
            const float* sp = si + (u*8+rr)*WW + v*8;
            #pragma unroll
            for (int q=0;q<8;++q) sum += rp[q] * sp[q];
        }
        sm[l] = sum * (1.f/64.f);
    }
    __syncthreads();
    float rv = 0.f;
    if (l < 49){
        float w[9];
        #pragma unroll
        for (int k=0;k<9;++k) w[k] = dwr[c*9+k];
        int u=l/7, v=l%7; float acc=0.f;
        #pragma unroll
        for (int ky=0;ky<3;++ky){ int uu=u+ky-1; if((unsigned)uu>=7u) continue;
            #pragma unroll
            for (int kx=0;kx<3;++kx){ int vv=v+kx-1; if((unsigned)vv>=7u) continue;
                acc += sm[uu*7+vv]*w[ky*3+kx]; } }
        rv = fmaxf(acc, 0.f);
    }
    red[l] = rv;
    __syncthreads();
    if (l==0){ float t=0.f; for(int i2=0;i2<64;++i2) t+=red[i2]; s[(size_t)r*BB*CC_ + bc] = t*(1.f/49.f); }
}

// K4b: head matvec + tanh -> Kwb (bf16) [r][b][t][c]. Fused: grid 144.
__global__ void k_akg_head(const float* __restrict__ s, const float* __restrict__ hw,
                           const float* __restrict__ hb, bf16* __restrict__ Kwb){
    int gid = blockIdx.x; int r = gid / 72; int id = gid % 72;
    int b = id / 9; int og = id % 9;
    __shared__ float sv[CC_];
    int tid = threadIdx.x; // 256
    sv[tid] = s[(size_t)r*BB*CC_ + b*CC_ + tid];
    __syncthreads();
    int o = og*256 + tid;              // o = c*9 + t
    const float* wp = hw + (size_t)r*2304*CC_ + (size_t)o*CC_;
    float acc = hb[(size_t)r*2304 + o];
    for (int c2=0;c2<CC_;++c2) acc += wp[c2]*sv[c2];
    int c = o / 9, t = o - 9*c;
    Kwb[((size_t)r*BB + b)*2304 + t*256 + c] = f2b(tanhf(acc));
}

// K5a: tap descriptor precompute. Thread per pixel (n = (creg*8+b)*3136 + yx), 9 taps each.
__global__ __launch_bounds__(256) void k_tapprep(const float* __restrict__ p, Tap* __restrict__ tap){
    int n = blockIdx.x*256 + threadIdx.x;   // 50176 total, grid 196
    int cb = n / 3136; int yx = n - cb*3136;
    int creg = cb >> 3; int b = cb & 7;
    int y = yx / 56, x = yx - (yx/56)*56;
    const float* pr = p + (size_t)creg*BB*18*HWSZ + (size_t)b*18*HWSZ;
    Tap* out = tap + (size_t)n*9;
    #pragma unroll
    for (int t = 0; t < 9; ++t){
        int ky = t / 3, kx = t % 3;
        float dy = pr[(size_t)(2*t)*HWSZ + yx];
        float dx = pr[(size_t)(2*t+1)*HWSZ + yx];
        float py = (float)(y - 1 + ky) + dy;
        float px = (float)(x - 1 + kx) + dx;
        float y0f = floorf(py), x0f = floorf(px);
        float wy1 = py - y0f, wx1 = px - x0f;
        float wy0 = 1.f - wy1, wx0 = 1.f - wx1;
        float vy0 = (y0f >= 0.f  && y0f <= 55.f) ? 1.f : 0.f;
        float vy1 = (y0f >= -1.f && y0f <= 54.f) ? 1.f : 0.f;
        float vx0 = (x0f >= 0.f  && x0f <= 55.f) ? 1.f : 0.f;
        float vx1 = (x0f >= -1.f && x0f <= 54.f) ? 1.f : 0.f;
        int y0 = (int)y0f, x0i = (int)x0f;
        int iy0 = min(max(y0,0),55),    iy1 = min(max(y0+1,0),55);
        int ix0 = min(max(x0i,0),55),   ix1 = min(max(x0i+1,0),55);
        Tap td;
        td.o00 = ((iy0+1)*58 + ix0+1)*256;
        td.o01 = ((iy0+1)*58 + ix1+1)*256;
        td.o10 = ((iy1+1)*58 + ix0+1)*256;
        td.o11 = ((iy1+1)*58 + ix1+1)*256;
        td.w00 = wy0*wx0*vy0*vx0;
        td.w01 = wy0*wx1*vy0*vx1;
        td.w10 = wy1*wx0*vy1*vx0;
        td.w11 = wy1*wx1*vy1*vx1;
        out[t] = td;
    }
}

// K5b: deformable depthwise v4 — wave = 2 pixels (half-wave each), lane = 8 channels -> 16B loads.
// No LDS/sync. Kw (bf16) loads are identical across halves (1 instr). Grid 6272, b=bx&7 XCD pin.
__global__ __launch_bounds__(256) void k_deform(const bf16* __restrict__ Fp, const Tap* __restrict__ tap,
                                                const bf16* __restrict__ Kwb, bf16* __restrict__ outsN){
    int bx = blockIdx.x; int b = bx & 7; int rest = bx >> 3;  // rest = creg*392 + pg
    int pg = rest % 392; int creg = rest / 392;
    int tid = threadIdx.x; int w = tid >> 6, l = tid & 63;
    int h = l >> 5;                 // pixel within pair
    int lc = l & 31;                // channel lane
    int cl = lc*8;
    int yx = pg*8 + w*2 + h;
    size_t pid = ((size_t)(creg*8 + b))*3136 + yx;
    const Tap* td = tap + pid*9;
    const bf16* Fb = Fp + (size_t)creg*FPR + (size_t)b*58*58*256;
    const bf16* Kb = Kwb + ((size_t)creg*8 + b)*2304;
    float acc[8] = {0.f,0.f,0.f,0.f,0.f,0.f,0.f,0.f};
    #pragma unroll
    for (int t = 0; t < 9; ++t){
        i32x4 off = *(const i32x4*)(&td[t].o00);
        f32x4 wt  = *(const f32x4*)(&td[t].w00);
        short8 f00 = *(const short8*)(Fb + off.x + cl);
        short8 f01 = *(const short8*)(Fb + off.y + cl);
        short8 f10 = *(const short8*)(Fb + off.z + cl);
        short8 f11 = *(const short8*)(Fb + off.w + cl);
        short8 kb  = *(const short8*)(Kb + t*256 + cl);
        #pragma unroll
        for (int j = 0; j < 8; ++j){
            float v = wt.x*bs2f(f00[j]) + wt.y*bs2f(f01[j]) + wt.z*bs2f(f10[j]) + wt.w*bs2f(f11[j]);
            acc[j] += bs2f(kb[j])*v;
        }
    }
    __attribute__((aligned(16))) bf16 tmp[8];
    #pragma unroll
    for (int j = 0; j < 8; ++j) tmp[j] = f2b(acc[j]);
    *(short8*)(outsN + ((size_t)b*HWSZ + yx)*512 + creg*256 + cl) = *(const short8*)tmp;
}

// K6a: pw2 MFMA GEMM, stats pass + O store (fp32 NCHW; O aliases Fp which is dead by now).
__global__ __launch_bounds__(256) void k_pw2_mstats(const bf16* __restrict__ outsN, const bf16* __restrict__ Bpw,
                                                    const float* __restrict__ bias, float* __restrict__ partials,
                                                    float* __restrict__ O){
    __shared__ float ls[2][2][256];
    int tid = threadIdx.x; int wave = tid>>6, lane = tid&63;
    int pixGroup = wave>>1, ntH = wave&1;
    int m = lane&15, q = lane>>4;
    size_t pb = (size_t)blockIdx.x*32 + pixGroup*16;
    const bf16* Ap = outsN + (pb + m)*512 + q*8;
    f32x4 acc[8];
    #pragma unroll
    for (int i=0;i<8;++i) acc[i] = (f32x4){0,0,0,0};
    #pragma unroll 1
    for (int kk = 0; kk < 16; ++kk){
        short8 a = *(const short8*)(Ap + kk*32);
        const bf16* Bk = Bpw + (((size_t)kk*16 + ntH*8)*64 + lane)*8;
        #pragma unroll
        for (int nt2 = 0; nt2 < 8; ++nt2){
            short8 b = *(const short8*)(Bk + (size_t)nt2*64*8);
            acc[nt2] = __builtin_amdgcn_mfma_f32_16x16x32_bf16(a, b, acc[nt2], 0, 0, 0);
        }
    }
    int b_idx = (int)(pb / HWSZ);
    int yx0 = (int)(pb % HWSZ);
    #pragma unroll
    for (int nt2 = 0; nt2 < 8; ++nt2){
        int oc = ntH*128 + nt2*16 + m;
        float bv = bias[oc];
        float s1 = 0.f, s2 = 0.f;
        float* op = O + ((size_t)b_idx*CC_ + oc)*HWSZ + yx0 + q*4;
        #pragma unroll
        for (int r = 0; r < 4; ++r){
            float v = acc[nt2][r] + bv;
            op[r] = v;
            s1 += v; s2 += v*v;
        }
        s1 += __shfl_down(s1, 32); s1 += __shfl_down(s1, 16);
        s2 += __shfl_down(s2, 32); s2 += __shfl_down(s2, 16);
        if (q == 0){ ls[pixGroup][0][oc] = s1; ls[pixGroup][1][oc] = s2; }
    }
    __syncthreads();
    if (tid < 256){
        partials[(size_t)blockIdx.x*512 + tid]       = ls[0][0][tid] + ls[1][0][tid];
        partials[(size_t)blockIdx.x*512 + 256 + tid] = ls[0][1][tid] + ls[1][1][tid];
    }
}

// K6b: reduce partials -> bnp (mean, rsqrt).
__global__ void k_bnstat2(const float* __restrict__ partials, float* __restrict__ bnp){
    __shared__ float sm[512];
    int tid = threadIdx.x;           // 512
    float acc = 0.f;
    for (int blk = 0; blk < 784; ++blk) acc += partials[(size_t)blk*512 + tid];
    sm[tid] = acc;
    __syncthreads();
    if (tid < 256){
        float n = (float)NPIX;
        float mean = sm[tid] / n;
        float var = sm[256+tid] / n - mean*mean;
        var = fmaxf(var, 0.f);
        bnp[tid] = mean; bnp[256+tid] = rsqrtf(var + 1e-5f);
    }
}

// K6c: BN apply (elementwise, float4): out = (O - mean)*rsq*gamma + beta. Grid 6272.
__global__ __launch_bounds__(256) void k_bnapply(const float* __restrict__ O, const float* __restrict__ bnp,
                                                 const float* __restrict__ gamma, const float* __restrict__ beta,
                                                 float* __restrict__ out){
    int n = (blockIdx.x*256 + threadIdx.x)*4;   // HWSZ divisible by 4 -> same channel
    int c = (n / HWSZ) % CC_;
    float mean = bnp[c], rsq = bnp[256+c];
    float g = gamma[c], be = beta[c];
    f32x4 v = *(const f32x4*)(O + n);
    f32x4 o;
    #pragma unroll
    for (int j = 0; j < 4; ++j) o[j] = (v[j] - mean)*rsq*g + be;
    *(f32x4*)(out + n) = o;
}

extern "C" void kernel_launch(void* const* d_in, const int* in_sizes, int n_in,
                              void* d_out, int out_size, void* d_ws, size_t ws_size,
                              hipStream_t stream) {
    (void)in_sizes; (void)n_in; (void)out_size; (void)ws_size;
    const float* F_c    = (const float*)d_in[0];
    const float* dec_w  = (const float*)d_in[1];
    const float* dec_b  = (const float*)d_in[2];
    const float* off1_w = (const float*)d_in[3];
    const float* off1_b = (const float*)d_in[4];
    const float* off2_w = (const float*)d_in[5];
    const float* off2_b = (const float*)d_in[6];
    const float* akg_dw = (const float*)d_in[7];
    const float* akg_hw = (const float*)d_in[8];
    const float* akg_hb = (const float*)d_in[9];
    const float* pw2_w  = (const float*)d_in[10];
    const float* pw2_b  = (const float*)d_in[11];
    const float* gamma  = (const float*)d_in[12];
    const float* beta   = (const float*)d_in[13];
    float* out = (float*)d_out;

    char* ws = (char*)d_ws;
    size_t off = 0;
    auto alloc = [&](size_t bytes)->char*{
        char* r = ws + off;
        off = (off + bytes + 255) & ~(size_t)255;
        return r;
    };
    // Workspace ~82 MB.
    bf16*  Fp    = (bf16*) alloc(2*FPR*2);                 // padded NHWC F*sc, both regions
    bf16*  Bp    = (bf16*) alloc((size_t)2*9*8*4*64*8*2);  // conv1 weight frags
    bf16*  Bpw   = (bf16*) alloc((size_t)16*16*64*8*2);    // pw2 weight frags
    bf16*  Bc    = (bf16*) alloc((size_t)2*18*2*64*8*2);   // conv2 weight frags
    float* sc    = (float*)alloc((size_t)2*NPIX*4);
    bf16*  hp    = (bf16*) alloc(2*HPR*2);                 // padded NHWC hidden, both regions
    float* p     = (float*)alloc((size_t)2*BB*18*HWSZ*4);  // offsets, both regions
    float* s     = (float*)alloc((size_t)2*BB*CC_*4);
    bf16*  Kwb   = (bf16*) alloc((size_t)2*BB*CC_*9*2);    // dyn depthwise weights, bf16 [r][b][t][c]
    bf16*  outsN = (bf16*) alloc(NPIX*512*2);              // NHWC, k = creg*256+c
    Tap*   tap   = (Tap*)  alloc((size_t)2*NPIX*9*sizeof(Tap));
    float* partials = (float*)alloc((size_t)784*512*4);
    float* bnp   = (float*)alloc(2*CC_*4);
    // O (fp32, 25.7MB) aliases Fp (27.6MB): Fp is dead after k_deform, O written in k_pw2_mstats.
    float* O = (float*)Fp;

    k_scalepack<<<dim3(BB*HH), dim3(256), 0, stream>>>(F_c, dec_w, dec_b, sc, Fp);
    k_bprep<<<dim3(576), dim3(64), 0, stream>>>(off1_w, Bp);
    k_bprep_pw<<<dim3(256), dim3(64), 0, stream>>>(pw2_w, Bpw);
    k_bprep_c2<<<dim3(72), dim3(64), 0, stream>>>(off2_w, Bc);

    // Region-fused pipeline.
    k_conv1<<<dim3(2*BB*HH), dim3(256), 0, stream>>>(Fp, Bp, off1_b, hp);
    k_conv2m<<<dim3(2*BB*HH), dim3(256), 0, stream>>>(hp, Bc, off2_b, p);
    k_akg_pool<<<dim3(2*BB*CC_), dim3(64), 0, stream>>>(F_c, sc, akg_dw, s);
    k_akg_head<<<dim3(2*BB*9), dim3(256), 0, stream>>>(s, akg_hw, akg_hb, Kwb);
    k_tapprep<<<dim3(196), dim3(256), 0, stream>>>(p, tap);
    k_deform<<<dim3(2*BB*392), dim3(256), 0, stream>>>(Fp, tap, Kwb, outsN);

    k_pw2_mstats<<<dim3(784), dim3(256), 0, stream>>>(outsN, Bpw, pw2_b, partials, O);
    k_bnstat2<<<dim3(1), dim3(512), 0, stream>>>(partials, bnp);
    k_bnapply<<<dim3((int)(NPIX*CC_/1024)), dim3(256), 0, stream>>>(O, bnp, gamma, beta, out);
}

// Round 15
// 321.371 us; speedup vs baseline: 5.2424x; 1.1507x over previous
//
#include <hip/hip_runtime.h>
#include <hip/hip_bf16.h>

#define BB 8
#define CC_ 256
#define HH 56
#define WW 56
#define HWSZ (HH*WW)
#define RR_ 2
#define HID 64
#define FPR ((size_t)8*58*58*256)   // padded NHWC region elements
#define HPR ((size_t)8*58*58*64)    // padded NHWC hidden elements (per region)
#define NPIX ((size_t)BB*HWSZ)      // 25088

typedef __hip_bfloat16 bf16;
typedef __attribute__((ext_vector_type(8))) short short8;
typedef __attribute__((ext_vector_type(4))) short short4_t;
typedef __attribute__((ext_vector_type(4))) float f32x4;

struct Tap { int o00, o01, o10, o11; float w00, w01, w10, w11; };  // 32B

__device__ __forceinline__ float b2f(bf16 v){ return __bfloat162float(v); }
__device__ __forceinline__ bf16 f2b(float v){ return __float2bfloat16(v); }
__device__ __forceinline__ float bs2f(short s){ return __uint_as_float(((unsigned)(unsigned short)s)<<16); }

// K1: fused decoupler (1x1 conv + softmax) + NHWC bf16 pack of both F_i = F*sc_r regions.
__global__ __launch_bounds__(256) void k_scalepack(const float* __restrict__ F, const float* __restrict__ dec_w,
                                                   const float* __restrict__ dec_b, float* __restrict__ sc,
                                                   bf16* __restrict__ Fp){
    __shared__ float lds_f[256][57];
    __shared__ float lw0[256], lw1[256];
    __shared__ float ls0[56], ls1[56];
    int bx = blockIdx.x; int b = bx/HH, gy = bx%HH;
    int tid = threadIdx.x;
    lw0[tid] = dec_w[tid]; lw1[tid] = dec_w[CC_+tid];
    const float* Fb = F + (size_t)b*CC_*HWSZ + gy*WW;
    for (int it = 0; it < 56; ++it){
        int idx = it*256 + tid;
        int c = idx / 56, x = idx - c*56;
        lds_f[c][x] = Fb[(size_t)c*HWSZ + x];
    }
    __syncthreads();
    if (tid < 56){
        float a0 = dec_b[0], a1 = dec_b[1];
        for (int c = 0; c < CC_; ++c){ float v = lds_f[c][tid]; a0 += v*lw0[c]; a1 += v*lw1[c]; }
        float m = fmaxf(a0,a1);
        float e0 = __expf(a0-m), e1 = __expf(a1-m);
        float inv = 1.0f/(e0+e1);
        float s0 = 1.0f + e0*inv, s1 = 1.0f + e1*inv;
        ls0[tid] = s0; ls1[tid] = s1;
        sc[(size_t)b*HWSZ + gy*WW + tid] = s0;
        sc[(size_t)BB*HWSZ + (size_t)b*HWSZ + gy*WW + tid] = s1;
    }
    __syncthreads();
    bf16 z = f2b(0.f);
    for (int r = 0; r < 2; ++r){
        const float* lsr = r ? ls1 : ls0;
        bf16* slab = Fp + (size_t)r*FPR + (size_t)b*58*58*256;
        bf16* dst = slab + ((size_t)(gy+1)*58 + 1)*256 + tid;
        for (int x2 = 0; x2 < 56; ++x2) dst[(size_t)x2*256] = f2b(lds_f[tid][x2] * lsr[x2]);
        bf16* rowp = slab + (size_t)(gy+1)*58*256;
        rowp[tid] = z;                 // col 0
        rowp[57*256 + tid] = z;        // col 57
        if (gy == 0){ for (int cidx = 0; cidx < 58; ++cidx) slab[(size_t)cidx*256 + tid] = z; }
        if (gy == 55){ bf16* r57 = slab + (size_t)57*58*256;
                       for (int cidx = 0; cidx < 58; ++cidx) r57[(size_t)cidx*256 + tid] = z; }
    }
}

// K1c: pack conv1 weights into MFMA B-fragment order.
__global__ void k_bprep(const float* __restrict__ w, bf16* __restrict__ Bp){
    int id = blockIdx.x;               // 2*9*8*4 = 576
    int nt = id & 3; id >>= 2; int icc = id & 7; id >>= 3; int t = id % 9; int r = id / 9;
    int L = threadIdx.x;               // 64
    int oc = nt*16 + (L&15);
    const float* wr = w + (size_t)r*HID*CC_*9;
    bf16* out = Bp + (((((size_t)r*9 + t)*8 + icc)*4 + nt)*64 + L)*8;
    #pragma unroll
    for (int j = 0; j < 8; ++j){
        int ic = icc*32 + (L>>4)*8 + j;
        out[j] = f2b(wr[((size_t)oc*CC_ + ic)*9 + t]);
    }
}

// K1d: pack pw2 weights (256 x 512) into B-frag order: Bpw[kk][nt][lane][j].
__global__ void k_bprep_pw(const float* __restrict__ w, bf16* __restrict__ Bpw){
    int id = blockIdx.x;               // 16*16 = 256
    int kk = id >> 4, nt = id & 15;
    int L = threadIdx.x;               // 64
    int oc = nt*16 + (L&15);
    bf16* out = Bpw + (((size_t)(kk*16+nt))*64 + L)*8;
    #pragma unroll
    for (int j = 0; j < 8; ++j){
        int ic = kk*32 + (L>>4)*8 + j;
        out[j] = f2b(w[(size_t)oc*512 + ic]);
    }
}

// K1e: pack conv2 weights into B-frag order, zero-padded to N=32.
__global__ void k_bprep_c2(const float* __restrict__ w, bf16* __restrict__ Bc){
    int id = blockIdx.x;               // 2*18*2 = 72
    int nt = id & 1; id >>= 1; int ks = id % 18; int r = id / 18;
    int t = ks >> 1, chunk = ks & 1;
    int L = threadIdx.x;               // 64
    int oc = nt*16 + (L&15);
    const float* wr = w + (size_t)r*18*HID*9;
    bf16* out = Bc + ((((size_t)r*18 + ks)*2 + nt)*64 + L)*8;
    #pragma unroll
    for (int j = 0; j < 8; ++j){
        int ic = chunk*32 + (L>>4)*8 + j;
        out[j] = (oc < 18) ? f2b(wr[((size_t)oc*HID + ic)*9 + t]) : f2b(0.f);
    }
}

// K2: conv3x3 256->64 MFMA implicit GEMM, 2 rows per wave (B-frag reuse: 2A+4B per 8 MFMAs).
// Grid 448: b=bx&7, rid=bx>>3, yp=rid%28 (y0=2*yp), r=rid/28. Waves = x0 {0,16,32,40}.
__global__ __launch_bounds__(256) void k_conv1(const bf16* __restrict__ Fp, const bf16* __restrict__ Bp,
                                               const float* __restrict__ bias, bf16* __restrict__ hp){
    int bx = blockIdx.x; int b = bx & 7; int rid = bx >> 3; int yp = rid % 28; int r = rid / 28;
    int y0 = yp*2;
    int tid = threadIdx.x; int wave = tid>>6, lane = tid&63;
    int m = lane&15, q = lane>>4;
    int x0 = (wave==3) ? 40 : wave*16;
    f32x4 acc[2][4];
    #pragma unroll
    for (int i=0;i<2;++i)
        #pragma unroll
        for (int j=0;j<4;++j) acc[i][j] = (f32x4){0,0,0,0};
    const bf16* Fb = Fp + (size_t)r*FPR + ((size_t)b*58*58)*256;
    const bf16* Bpr = Bp + (size_t)r*9*8*4*64*8;
    #pragma unroll
    for (int t = 0; t < 9; ++t){
        int ty = t/3, tx = t%3;
        const bf16* arow = Fb + ((size_t)(y0+ty)*58 + (x0+m+tx))*256 + q*8;
        const bf16* brow = Bpr + ((size_t)t*8)*4*64*8 + lane*8;
        #pragma unroll
        for (int icc = 0; icc < 8; ++icc){
            short8 a0 = *(const short8*)(arow + icc*32);
            short8 a1 = *(const short8*)(arow + 58*256 + icc*32);
            const bf16* bb = brow + (size_t)icc*4*64*8;
            short8 b0 = *(const short8*)(bb);
            short8 b1 = *(const short8*)(bb + 64*8);
            short8 b2 = *(const short8*)(bb + 2*64*8);
            short8 b3 = *(const short8*)(bb + 3*64*8);
            acc[0][0] = __builtin_amdgcn_mfma_f32_16x16x32_bf16(a0, b0, acc[0][0], 0, 0, 0);
            acc[1][0] = __builtin_amdgcn_mfma_f32_16x16x32_bf16(a1, b0, acc[1][0], 0, 0, 0);
            acc[0][1] = __builtin_amdgcn_mfma_f32_16x16x32_bf16(a0, b1, acc[0][1], 0, 0, 0);
            acc[1][1] = __builtin_amdgcn_mfma_f32_16x16x32_bf16(a1, b1, acc[1][1], 0, 0, 0);
            acc[0][2] = __builtin_amdgcn_mfma_f32_16x16x32_bf16(a0, b2, acc[0][2], 0, 0, 0);
            acc[1][2] = __builtin_amdgcn_mfma_f32_16x16x32_bf16(a1, b2, acc[1][2], 0, 0, 0);
            acc[0][3] = __builtin_amdgcn_mfma_f32_16x16x32_bf16(a0, b3, acc[0][3], 0, 0, 0);
            acc[1][3] = __builtin_amdgcn_mfma_f32_16x16x32_bf16(a1, b3, acc[1][3], 0, 0, 0);
        }
    }
    const float* br = bias + r*HID;
    bf16* slab = hp + (size_t)r*HPR + (size_t)b*58*58*64;
    bf16 z = f2b(0.f);
    #pragma unroll
    for (int rr = 0; rr < 2; ++rr){
        int y = y0 + rr;
        bf16* hrow = slab + ((size_t)(y+1)*58 + 1)*64;
        #pragma unroll
        for (int nt = 0; nt < 4; ++nt){
            int oc = nt*16 + m;
            float bv = br[oc];
            #pragma unroll
            for (int r2 = 0; r2 < 4; ++r2){
                int x = x0 + q*4 + r2;
                hrow[(size_t)x*64 + oc] = f2b(fmaxf(acc[rr][nt][r2] + bv, 0.f));
            }
        }
        // borders of this row (zeros)
        bf16* rowp = slab + (size_t)(y+1)*58*64;
        if (tid < 64) rowp[tid] = z;
        else if (tid < 128) rowp[57*64 + (tid-64)] = z;
        if (y == 0){ for (int idx = tid; idx < 58*64; idx += 256) slab[idx] = z; }
        if (y == 55){ bf16* r57 = slab + (size_t)57*58*64;
                      for (int idx = tid; idx < 58*64; idx += 256) r57[idx] = z; }
    }
}

// K3: conv2 via MFMA implicit GEMM on padded NHWC hp, fused over regions. Grid 896.
__global__ __launch_bounds__(256) void k_conv2m(const bf16* __restrict__ hp, const bf16* __restrict__ Bc,
                                                const float* __restrict__ bias, float* __restrict__ p){
    int bx = blockIdx.x; int b = bx & 7; int rid = bx >> 3; int y = rid % 56; int r = rid / 56;
    int tid = threadIdx.x; int wave = tid>>6, lane = tid&63;
    int m = lane&15, q = lane>>4;
    int x0 = (wave==3) ? 40 : wave*16;
    f32x4 acc0 = {0,0,0,0}, acc1 = {0,0,0,0};
    const bf16* Hb = hp + (size_t)r*HPR + ((size_t)b*58 + y)*58*64;
    const bf16* Bcr = Bc + (size_t)r*18*2*64*8;
    #pragma unroll
    for (int t = 0; t < 9; ++t){
        int ty = t/3, tx = t%3;
        const bf16* arow = Hb + ((size_t)ty*58 + (x0+m+tx))*64 + q*8;
        #pragma unroll
        for (int chunk = 0; chunk < 2; ++chunk){
            short8 a = *(const short8*)(arow + chunk*32);
            const bf16* bb = Bcr + (((size_t)(t*2+chunk))*2*64 + lane)*8;
            short8 b0 = *(const short8*)(bb);
            short8 b1 = *(const short8*)(bb + 64*8);
            acc0 = __builtin_amdgcn_mfma_f32_16x16x32_bf16(a, b0, acc0, 0, 0, 0);
            acc1 = __builtin_amdgcn_mfma_f32_16x16x32_bf16(a, b1, acc1, 0, 0, 0);
        }
    }
    const float* br = bias + r*18;
    float* pr = p + (size_t)r*BB*18*HWSZ;
    #pragma unroll
    for (int r2 = 0; r2 < 4; ++r2){
        int x = x0 + q*4 + r2;
        {
            float v = acc0[r2] + br[m];
            pr[((size_t)b*18 + m)*HWSZ + y*WW + x] = v;
        }
        if (m < 2){
            float v = acc1[r2] + br[16+m];
            pr[((size_t)b*18 + 16+m)*HWSZ + y*WW + x] = v;
        }
    }
}

// K4a: 8x8 avg pool (56->7), depthwise 3x3 + relu, global mean -> s[r][b][c]. Fused: grid 4096.
__global__ void k_akg_pool(const float* __restrict__ Fc, const float* __restrict__ sc,
                           const float* __restrict__ dw, float* __restrict__ s){
    int gid = blockIdx.x; int r = gid >> 11; int bc = gid & 2047;
    int b = bc / CC_; int c = bc % CC_;
    int l = threadIdx.x; // 64
    __shared__ float sm[49];
    __shared__ float red[64];
    const float* fb = Fc + (size_t)bc*HWSZ;
    const float* si = sc + (size_t)r*NPIX + (size_t)b*HWSZ;
    const float* dwr = dw + (size_t)r*CC_*9;
    if (l < 49){
        int u = l/7, v = l%7;
        float sum = 0.f;
        for (int rr=0;rr<8;++rr){
            const float* rp = fb + (u*8+rr)*WW + v*8;
            const float* sp = si + (u*8+rr)*WW + v*8;
            #pragma unroll
            for (int q=0;q<8;++q) sum += rp[q] * sp[q];
        }
        sm[l] = sum * (1.f/64.f);
    }
    __syncthreads();
    float rv = 0.f;
    if (l < 49){
        float w[9];
        #pragma unroll
        for (int k=0;k<9;++k) w[k] = dwr[c*9+k];
        int u=l/7, v=l%7; float acc=0.f;
        #pragma unroll
        for (int ky=0;ky<3;++ky){ int uu=u+ky-1; if((unsigned)uu>=7u) continue;
            #pragma unroll
            for (int kx=0;kx<3;++kx){ int vv=v+kx-1; if((unsigned)vv>=7u) continue;
                acc += sm[uu*7+vv]*w[ky*3+kx]; } }
        rv = fmaxf(acc, 0.f);
    }
    red[l] = rv;
    __syncthreads();
    if (l==0){ float t=0.f; for(int i2=0;i2<64;++i2) t+=red[i2]; s[(size_t)r*BB*CC_ + bc] = t*(1.f/49.f); }
}

// K4b: head matvec + tanh -> Kw (fp32) [r][b][t][c]. Fused: grid 144.
__global__ void k_akg_head(const float* __restrict__ s, const float* __restrict__ hw,
                           const float* __restrict__ hb, float* __restrict__ Kw){
    int gid = blockIdx.x; int r = gid / 72; int id = gid % 72;
    int b = id / 9; int og = id % 9;
    __shared__ float sv[CC_];
    int tid = threadIdx.x; // 256
    sv[tid] = s[(size_t)r*BB*CC_ + b*CC_ + tid];
    __syncthreads();
    int o = og*256 + tid;              // o = c*9 + t
    const float* wp = hw + (size_t)r*2304*CC_ + (size_t)o*CC_;
    float acc = hb[(size_t)r*2304 + o];
    for (int c2=0;c2<CC_;++c2) acc += wp[c2]*sv[c2];
    int c = o / 9, t = o - 9*c;
    Kw[((size_t)r*BB + b)*2304 + t*256 + c] = tanhf(acc);
}

// K5a: tap descriptor precompute. Thread per pixel, 9 taps each.
__global__ __launch_bounds__(256) void k_tapprep(const float* __restrict__ p, Tap* __restrict__ tap){
    int n = blockIdx.x*256 + threadIdx.x;   // 50176 total, grid 196
    int cb = n / 3136; int yx = n - cb*3136;
    int creg = cb >> 3; int b = cb & 7;
    int y = yx / 56, x = yx - (yx/56)*56;
    const float* pr = p + (size_t)creg*BB*18*HWSZ + (size_t)b*18*HWSZ;
    Tap* out = tap + (size_t)n*9;
    #pragma unroll
    for (int t = 0; t < 9; ++t){
        int ky = t / 3, kx = t % 3;
        float dy = pr[(size_t)(2*t)*HWSZ + yx];
        float dx = pr[(size_t)(2*t+1)*HWSZ + yx];
        float py = (float)(y - 1 + ky) + dy;
        float px = (float)(x - 1 + kx) + dx;
        float y0f = floorf(py), x0f = floorf(px);
        float wy1 = py - y0f, wx1 = px - x0f;
        float wy0 = 1.f - wy1, wx0 = 1.f - wx1;
        float vy0 = (y0f >= 0.f  && y0f <= 55.f) ? 1.f : 0.f;
        float vy1 = (y0f >= -1.f && y0f <= 54.f) ? 1.f : 0.f;
        float vx0 = (x0f >= 0.f  && x0f <= 55.f) ? 1.f : 0.f;
        float vx1 = (x0f >= -1.f && x0f <= 54.f) ? 1.f : 0.f;
        int y0 = (int)y0f, x0i = (int)x0f;
        int iy0 = min(max(y0,0),55),    iy1 = min(max(y0+1,0),55);
        int ix0 = min(max(x0i,0),55),   ix1 = min(max(x0i+1,0),55);
        Tap td;
        td.o00 = ((iy0+1)*58 + ix0+1)*256;
        td.o01 = ((iy0+1)*58 + ix1+1)*256;
        td.o10 = ((iy1+1)*58 + ix0+1)*256;
        td.o11 = ((iy1+1)*58 + ix1+1)*256;
        td.w00 = wy0*wx0*vy0*vx0;
        td.w01 = wy0*wx1*vy0*vx1;
        td.w10 = wy1*wx0*vy1*vx0;
        td.w11 = wy1*wx1*vy1*vx1;
        out[t] = td;
    }
}

// K5b: deformable depthwise (r13-v3, best measured) — wave per pixel, no LDS/sync, scalar
// descriptor loads via wave-uniform address. Grid 12544, b=bx&7 XCD pin.
__global__ __launch_bounds__(256) void k_deform(const bf16* __restrict__ Fp, const Tap* __restrict__ tap,
                                                const float* __restrict__ Kw, bf16* __restrict__ outsN){
    int bx = blockIdx.x; int b = bx & 7; int rest = bx >> 3;  // rest = creg*784 + pg
    int pg = rest % 784; int creg = rest / 784;
    int tid = threadIdx.x; int w = tid >> 6, l = tid & 63;
    int wu = __builtin_amdgcn_readfirstlane(w);               // wave-uniform -> scalar addressing
    int yx = pg*4 + wu;
    size_t pid = ((size_t)(creg*8 + b))*3136 + yx;
    const Tap* td = tap + pid*9;
    const bf16* Fb = Fp + (size_t)creg*FPR + (size_t)b*58*58*256;
    const float* Kb = Kw + ((size_t)creg*8 + b)*2304;
    int cl = 4*l;
    float acc[4] = {0.f, 0.f, 0.f, 0.f};
    #pragma unroll
    for (int t = 0; t < 9; ++t){
        Tap d = td[t];
        short4_t f00 = *(const short4_t*)(Fb + d.o00 + cl);
        short4_t f01 = *(const short4_t*)(Fb + d.o01 + cl);
        short4_t f10 = *(const short4_t*)(Fb + d.o10 + cl);
        short4_t f11 = *(const short4_t*)(Fb + d.o11 + cl);
        f32x4 kt = *(const f32x4*)(Kb + t*256 + cl);
        #pragma unroll
        for (int j = 0; j < 4; ++j){
            float v = d.w00*bs2f(f00[j]) + d.w01*bs2f(f01[j]) + d.w10*bs2f(f10[j]) + d.w11*bs2f(f11[j]);
            acc[j] += kt[j]*v;
        }
    }
    __attribute__((aligned(8))) bf16 tmp[4];
    #pragma unroll
    for (int j = 0; j < 4; ++j) tmp[j] = f2b(acc[j]);
    *(short4_t*)(outsN + ((size_t)b*HWSZ + yx)*512 + creg*256 + cl) = *(const short4_t*)tmp;
}

// K6a: pw2 MFMA GEMM, 2 pixel-tiles per wave (B-frag reuse), stats via LDS reduce + atomics,
// O store (fp32 NCHW; O aliases Fp which is dead by now). Grid 392 (64 pixels/block).
__global__ __launch_bounds__(256) void k_pw2_mstats(const bf16* __restrict__ outsN, const bf16* __restrict__ Bpw,
                                                    const float* __restrict__ bias, float* __restrict__ stats,
                                                    float* __restrict__ O){
    __shared__ float ls[2][2][256];
    int tid = threadIdx.x; int wave = tid>>6, lane = tid&63;
    int pixGroup = wave>>1, ntH = wave&1;
    int m = lane&15, q = lane>>4;
    size_t pb = (size_t)blockIdx.x*64 + pixGroup*32;
    const bf16* Ap0 = outsN + (pb + m)*512 + q*8;
    const bf16* Ap1 = Ap0 + (size_t)16*512;
    f32x4 acc[2][8];
    #pragma unroll
    for (int g=0;g<2;++g)
        #pragma unroll
        for (int i=0;i<8;++i) acc[g][i] = (f32x4){0,0,0,0};
    #pragma unroll 1
    for (int kk = 0; kk < 16; ++kk){
        short8 a0 = *(const short8*)(Ap0 + kk*32);
        short8 a1 = *(const short8*)(Ap1 + kk*32);
        const bf16* Bk = Bpw + (((size_t)kk*16 + ntH*8)*64 + lane)*8;
        #pragma unroll
        for (int nt2 = 0; nt2 < 8; ++nt2){
            short8 b = *(const short8*)(Bk + (size_t)nt2*64*8);
            acc[0][nt2] = __builtin_amdgcn_mfma_f32_16x16x32_bf16(a0, b, acc[0][nt2], 0, 0, 0);
            acc[1][nt2] = __builtin_amdgcn_mfma_f32_16x16x32_bf16(a1, b, acc[1][nt2], 0, 0, 0);
        }
    }
    #pragma unroll
    for (int nt2 = 0; nt2 < 8; ++nt2){
        int oc = ntH*128 + nt2*16 + m;
        float bv = bias[oc];
        float s1 = 0.f, s2 = 0.f;
        #pragma unroll
        for (int g = 0; g < 2; ++g){
            size_t pbg = pb + g*16;
            int b_idx = (int)(pbg / HWSZ);
            int yx0 = (int)(pbg % HWSZ);
            float* op = O + ((size_t)b_idx*CC_ + oc)*HWSZ + yx0 + q*4;
            #pragma unroll
            for (int r = 0; r < 4; ++r){
                float v = acc[g][nt2][r] + bv;
                op[r] = v;
                s1 += v; s2 += v*v;
            }
        }
        s1 += __shfl_down(s1, 32); s1 += __shfl_down(s1, 16);
        s2 += __shfl_down(s2, 32); s2 += __shfl_down(s2, 16);
        if (q == 0){ ls[pixGroup][0][oc] = s1; ls[pixGroup][1][oc] = s2; }
    }
    __syncthreads();
    if (tid < 256){
        atomicAdd(&stats[tid],       ls[0][0][tid] + ls[1][0][tid]);
        atomicAdd(&stats[256 + tid], ls[0][1][tid] + ls[1][1][tid]);
    }
}

// K6b: finalize BN stats.
__global__ void k_bnstat(const float* __restrict__ stats, float* __restrict__ bnp){
    int c = threadIdx.x;   // 256
    float n = (float)NPIX;
    float mean = stats[c]/n;
    float var = stats[256+c]/n - mean*mean;
    var = fmaxf(var, 0.f);
    bnp[c] = mean; bnp[256+c] = rsqrtf(var + 1e-5f);
}

// K6c: BN apply (elementwise, float4): out = (O - mean)*rsq*gamma + beta. Grid 6272.
__global__ __launch_bounds__(256) void k_bnapply(const float* __restrict__ O, const float* __restrict__ bnp,
                                                 const float* __restrict__ gamma, const float* __restrict__ beta,
                                                 float* __restrict__ out){
    int n = (blockIdx.x*256 + threadIdx.x)*4;   // HWSZ divisible by 4 -> same channel
    int c = (n / HWSZ) % CC_;
    float mean = bnp[c], rsq = bnp[256+c];
    float g = gamma[c], be = beta[c];
    f32x4 v = *(const f32x4*)(O + n);
    f32x4 o;
    #pragma unroll
    for (int j = 0; j < 4; ++j) o[j] = (v[j] - mean)*rsq*g + be;
    *(f32x4*)(out + n) = o;
}

extern "C" void kernel_launch(void* const* d_in, const int* in_sizes, int n_in,
                              void* d_out, int out_size, void* d_ws, size_t ws_size,
                              hipStream_t stream) {
    (void)in_sizes; (void)n_in; (void)out_size; (void)ws_size;
    const float* F_c    = (const float*)d_in[0];
    const float* dec_w  = (const float*)d_in[1];
    const float* dec_b  = (const float*)d_in[2];
    const float* off1_w = (const float*)d_in[3];
    const float* off1_b = (const float*)d_in[4];
    const float* off2_w = (const float*)d_in[5];
    const float* off2_b = (const float*)d_in[6];
    const float* akg_dw = (const float*)d_in[7];
    const float* akg_hw = (const float*)d_in[8];
    const float* akg_hb = (const float*)d_in[9];
    const float* pw2_w  = (const float*)d_in[10];
    const float* pw2_b  = (const float*)d_in[11];
    const float* gamma  = (const float*)d_in[12];
    const float* beta   = (const float*)d_in[13];
    float* out = (float*)d_out;

    char* ws = (char*)d_ws;
    size_t off = 0;
    auto alloc = [&](size_t bytes)->char*{
        char* r = ws + off;
        off = (off + bytes + 255) & ~(size_t)255;
        return r;
    };
    // Workspace ~82 MB.
    bf16*  Fp    = (bf16*) alloc(2*FPR*2);                 // padded NHWC F*sc, both regions
    bf16*  Bp    = (bf16*) alloc((size_t)2*9*8*4*64*8*2);  // conv1 weight frags
    bf16*  Bpw   = (bf16*) alloc((size_t)16*16*64*8*2);    // pw2 weight frags
    bf16*  Bc    = (bf16*) alloc((size_t)2*18*2*64*8*2);   // conv2 weight frags
    float* sc    = (float*)alloc((size_t)2*NPIX*4);
    bf16*  hp    = (bf16*) alloc(2*HPR*2);                 // padded NHWC hidden, both regions
    float* p     = (float*)alloc((size_t)2*BB*18*HWSZ*4);  // offsets, both regions
    float* s     = (float*)alloc((size_t)2*BB*CC_*4);
    float* Kw    = (float*)alloc((size_t)2*BB*CC_*9*4);
    bf16*  outsN = (bf16*) alloc(NPIX*512*2);              // NHWC, k = creg*256+c
    Tap*   tap   = (Tap*)  alloc((size_t)2*NPIX*9*sizeof(Tap));
    float* stats = (float*)alloc(2*CC_*4);
    float* bnp   = (float*)alloc(2*CC_*4);
    // O (fp32, 25.7MB) aliases Fp (27.6MB): Fp is dead after k_deform, O written in k_pw2_mstats.
    float* O = (float*)Fp;

    hipMemsetAsync(stats, 0, 2*CC_*sizeof(float), stream);

    k_scalepack<<<dim3(BB*HH), dim3(256), 0, stream>>>(F_c, dec_w, dec_b, sc, Fp);
    k_bprep<<<dim3(576), dim3(64), 0, stream>>>(off1_w, Bp);
    k_bprep_pw<<<dim3(256), dim3(64), 0, stream>>>(pw2_w, Bpw);
    k_bprep_c2<<<dim3(72), dim3(64), 0, stream>>>(off2_w, Bc);

    // Region-fused pipeline.
    k_conv1<<<dim3(2*BB*28), dim3(256), 0, stream>>>(Fp, Bp, off1_b, hp);
    k_conv2m<<<dim3(2*BB*HH), dim3(256), 0, stream>>>(hp, Bc, off2_b, p);
    k_akg_pool<<<dim3(2*BB*CC_), dim3(64), 0, stream>>>(F_c, sc, akg_dw, s);
    k_akg_head<<<dim3(2*BB*9), dim3(256), 0, stream>>>(s, akg_hw, akg_hb, Kw);
    k_tapprep<<<dim3(196), dim3(256), 0, stream>>>(p, tap);
    k_deform<<<dim3(2*BB*784), dim3(256), 0, stream>>>(Fp, tap, Kw, outsN);

    k_pw2_mstats<<<dim3(392), dim3(256), 0, stream>>>(outsN, Bpw, pw2_b, stats, O);
    k_bnstat<<<dim3(1), dim3(256), 0, stream>>>(stats, bnp);
    k_bnapply<<<dim3((int)(NPIX*CC_/1024)), dim3(256), 0, stream>>>(O, bnp, gamma, beta, out);
}

// Round 16
// 311.521 us; speedup vs baseline: 5.4082x; 1.0316x over previous
//
#include <hip/hip_runtime.h>
#include <hip/hip_bf16.h>

#define BB 8
#define CC_ 256
#define HH 56
#define WW 56
#define HWSZ (HH*WW)
#define RR_ 2
#define HID 64
#define FPR ((size_t)8*58*58*256)   // padded NHWC region elements
#define HPR ((size_t)8*58*58*64)    // padded NHWC hidden elements (per region)
#define NPIX ((size_t)BB*HWSZ)      // 25088

typedef __hip_bfloat16 bf16;
typedef __attribute__((ext_vector_type(8))) short short8;
typedef __attribute__((ext_vector_type(4))) short short4_t;
typedef __attribute__((ext_vector_type(4))) float f32x4;

struct Tap { int o00, o01, o10, o11; float w00, w01, w10, w11; };  // 32B

__device__ __forceinline__ float b2f(bf16 v){ return __bfloat162float(v); }
__device__ __forceinline__ bf16 f2b(float v){ return __float2bfloat16(v); }
__device__ __forceinline__ float bs2f(short s){ return __uint_as_float(((unsigned)(unsigned short)s)<<16); }

// K1: fused decoupler (1x1 conv + softmax) + NHWC bf16 pack of both F_i regions
// + 8-wide row partial sums for the AKG pool (rowsum[r][b][gy][v][c]).
__global__ __launch_bounds__(256) void k_scalepack(const float* __restrict__ F, const float* __restrict__ dec_w,
                                                   const float* __restrict__ dec_b,
                                                   bf16* __restrict__ Fp, float* __restrict__ rowsum){
    __shared__ float lds_f[256][57];
    __shared__ float lw0[256], lw1[256];
    __shared__ float ls0[56], ls1[56];
    int bx = blockIdx.x; int b = bx/HH, gy = bx%HH;
    int tid = threadIdx.x;
    lw0[tid] = dec_w[tid]; lw1[tid] = dec_w[CC_+tid];
    const float* Fb = F + (size_t)b*CC_*HWSZ + gy*WW;
    for (int it = 0; it < 56; ++it){
        int idx = it*256 + tid;
        int c = idx / 56, x = idx - c*56;
        lds_f[c][x] = Fb[(size_t)c*HWSZ + x];
    }
    __syncthreads();
    if (tid < 56){
        float a0 = dec_b[0], a1 = dec_b[1];
        for (int c = 0; c < CC_; ++c){ float v = lds_f[c][tid]; a0 += v*lw0[c]; a1 += v*lw1[c]; }
        float m = fmaxf(a0,a1);
        float e0 = __expf(a0-m), e1 = __expf(a1-m);
        float inv = 1.0f/(e0+e1);
        ls0[tid] = 1.0f + e0*inv; ls1[tid] = 1.0f + e1*inv;
    }
    __syncthreads();
    bf16 z = f2b(0.f);
    for (int r = 0; r < 2; ++r){
        const float* lsr = r ? ls1 : ls0;
        bf16* slab = Fp + (size_t)r*FPR + (size_t)b*58*58*256;
        bf16* dst = slab + ((size_t)(gy+1)*58 + 1)*256 + tid;
        for (int x2 = 0; x2 < 56; ++x2) dst[(size_t)x2*256] = f2b(lds_f[tid][x2] * lsr[x2]);
        // AKG pool row partials: rowsum[((r*8+b)*56+gy)*7+v)*256 + c]
        float* rs = rowsum + ((((size_t)(r*8+b)*56 + gy)*7))*256 + tid;
        #pragma unroll
        for (int v = 0; v < 7; ++v){
            float sum = 0.f;
            #pragma unroll
            for (int k = 0; k < 8; ++k) sum += lds_f[tid][v*8+k] * lsr[v*8+k];
            rs[(size_t)v*256] = sum;
        }
        bf16* rowp = slab + (size_t)(gy+1)*58*256;
        rowp[tid] = z;                 // col 0
        rowp[57*256 + tid] = z;        // col 57
        if (gy == 0){ for (int cidx = 0; cidx < 58; ++cidx) slab[(size_t)cidx*256 + tid] = z; }
        if (gy == 55){ bf16* r57 = slab + (size_t)57*58*256;
                       for (int cidx = 0; cidx < 58; ++cidx) r57[(size_t)cidx*256 + tid] = z; }
    }
}

// K1b: all weight prep in one launch. id<576: conv1; id<832: pw2; else conv2.
__global__ void k_bprep_all(const float* __restrict__ w1, const float* __restrict__ wpw,
                            const float* __restrict__ wc2,
                            bf16* __restrict__ Bp, bf16* __restrict__ Bpw, bf16* __restrict__ Bc){
    int id = blockIdx.x;
    int L = threadIdx.x;               // 64
    if (id < 576){
        int nt = id & 3; id >>= 2; int icc = id & 7; id >>= 3; int t = id % 9; int r = id / 9;
        int oc = nt*16 + (L&15);
        const float* wr = w1 + (size_t)r*HID*CC_*9;
        bf16* out = Bp + (((((size_t)r*9 + t)*8 + icc)*4 + nt)*64 + L)*8;
        #pragma unroll
        for (int j = 0; j < 8; ++j){
            int ic = icc*32 + (L>>4)*8 + j;
            out[j] = f2b(wr[((size_t)oc*CC_ + ic)*9 + t]);
        }
    } else if (id < 832){
        id -= 576;                     // 256
        int kk = id >> 4, nt = id & 15;
        int oc = nt*16 + (L&15);
        bf16* out = Bpw + (((size_t)(kk*16+nt))*64 + L)*8;
        #pragma unroll
        for (int j = 0; j < 8; ++j){
            int ic = kk*32 + (L>>4)*8 + j;
            out[j] = f2b(wpw[(size_t)oc*512 + ic]);
        }
    } else {
        id -= 832;                     // 72
        int nt = id & 1; id >>= 1; int ks = id % 18; int r = id / 18;
        int t = ks >> 1, chunk = ks & 1;
        int oc = nt*16 + (L&15);
        const float* wr = wc2 + (size_t)r*18*HID*9;
        bf16* out = Bc + ((((size_t)r*18 + ks)*2 + nt)*64 + L)*8;
        #pragma unroll
        for (int j = 0; j < 8; ++j){
            int ic = chunk*32 + (L>>4)*8 + j;
            out[j] = (oc < 18) ? f2b(wr[((size_t)oc*HID + ic)*9 + t]) : f2b(0.f);
        }
    }
}

// K2: conv3x3 256->64 MFMA implicit GEMM, 2 rows per wave (B-frag reuse). Grid 448.
__global__ __launch_bounds__(256) void k_conv1(const bf16* __restrict__ Fp, const bf16* __restrict__ Bp,
                                               const float* __restrict__ bias, bf16* __restrict__ hp){
    int bx = blockIdx.x; int b = bx & 7; int rid = bx >> 3; int yp = rid % 28; int r = rid / 28;
    int y0 = yp*2;
    int tid = threadIdx.x; int wave = tid>>6, lane = tid&63;
    int m = lane&15, q = lane>>4;
    int x0 = (wave==3) ? 40 : wave*16;
    f32x4 acc[2][4];
    #pragma unroll
    for (int i=0;i<2;++i)
        #pragma unroll
        for (int j=0;j<4;++j) acc[i][j] = (f32x4){0,0,0,0};
    const bf16* Fb = Fp + (size_t)r*FPR + ((size_t)b*58*58)*256;
    const bf16* Bpr = Bp + (size_t)r*9*8*4*64*8;
    #pragma unroll
    for (int t = 0; t < 9; ++t){
        int ty = t/3, tx = t%3;
        const bf16* arow = Fb + ((size_t)(y0+ty)*58 + (x0+m+tx))*256 + q*8;
        const bf16* brow = Bpr + ((size_t)t*8)*4*64*8 + lane*8;
        #pragma unroll
        for (int icc = 0; icc < 8; ++icc){
            short8 a0 = *(const short8*)(arow + icc*32);
            short8 a1 = *(const short8*)(arow + 58*256 + icc*32);
            const bf16* bb = brow + (size_t)icc*4*64*8;
            short8 b0 = *(const short8*)(bb);
            short8 b1 = *(const short8*)(bb + 64*8);
            short8 b2 = *(const short8*)(bb + 2*64*8);
            short8 b3 = *(const short8*)(bb + 3*64*8);
            acc[0][0] = __builtin_amdgcn_mfma_f32_16x16x32_bf16(a0, b0, acc[0][0], 0, 0, 0);
            acc[1][0] = __builtin_amdgcn_mfma_f32_16x16x32_bf16(a1, b0, acc[1][0], 0, 0, 0);
            acc[0][1] = __builtin_amdgcn_mfma_f32_16x16x32_bf16(a0, b1, acc[0][1], 0, 0, 0);
            acc[1][1] = __builtin_amdgcn_mfma_f32_16x16x32_bf16(a1, b1, acc[1][1], 0, 0, 0);
            acc[0][2] = __builtin_amdgcn_mfma_f32_16x16x32_bf16(a0, b2, acc[0][2], 0, 0, 0);
            acc[1][2] = __builtin_amdgcn_mfma_f32_16x16x32_bf16(a1, b2, acc[1][2], 0, 0, 0);
            acc[0][3] = __builtin_amdgcn_mfma_f32_16x16x32_bf16(a0, b3, acc[0][3], 0, 0, 0);
            acc[1][3] = __builtin_amdgcn_mfma_f32_16x16x32_bf16(a1, b3, acc[1][3], 0, 0, 0);
        }
    }
    const float* br = bias + r*HID;
    bf16* slab = hp + (size_t)r*HPR + (size_t)b*58*58*64;
    bf16 z = f2b(0.f);
    #pragma unroll
    for (int rr = 0; rr < 2; ++rr){
        int y = y0 + rr;
        bf16* hrow = slab + ((size_t)(y+1)*58 + 1)*64;
        #pragma unroll
        for (int nt = 0; nt < 4; ++nt){
            int oc = nt*16 + m;
            float bv = br[oc];
            #pragma unroll
            for (int r2 = 0; r2 < 4; ++r2){
                int x = x0 + q*4 + r2;
                hrow[(size_t)x*64 + oc] = f2b(fmaxf(acc[rr][nt][r2] + bv, 0.f));
            }
        }
        bf16* rowp = slab + (size_t)(y+1)*58*64;
        if (tid < 64) rowp[tid] = z;
        else if (tid < 128) rowp[57*64 + (tid-64)] = z;
        if (y == 0){ for (int idx = tid; idx < 58*64; idx += 256) slab[idx] = z; }
        if (y == 55){ bf16* r57 = slab + (size_t)57*58*64;
                      for (int idx = tid; idx < 58*64; idx += 256) r57[idx] = z; }
    }
}

// K3: conv2 MFMA implicit GEMM + fused tap-descriptor computation (offsets never touch HBM
// as a separate pass). Grid 896: block = (b, y, r), 18 offset channels -> LDS -> taps.
__global__ __launch_bounds__(256) void k_conv2m(const bf16* __restrict__ hp, const bf16* __restrict__ Bc,
                                                const float* __restrict__ bias, Tap* __restrict__ tap){
    __shared__ float pld[18][56];
    int bx = blockIdx.x; int b = bx & 7; int rid = bx >> 3; int y = rid % 56; int r = rid / 56;
    int tid = threadIdx.x; int wave = tid>>6, lane = tid&63;
    int m = lane&15, q = lane>>4;
    int x0 = (wave==3) ? 40 : wave*16;
    f32x4 acc0 = {0,0,0,0}, acc1 = {0,0,0,0};
    const bf16* Hb = hp + (size_t)r*HPR + ((size_t)b*58 + y)*58*64;
    const bf16* Bcr = Bc + (size_t)r*18*2*64*8;
    #pragma unroll
    for (int t = 0; t < 9; ++t){
        int ty = t/3, tx = t%3;
        const bf16* arow = Hb + ((size_t)ty*58 + (x0+m+tx))*64 + q*8;
        #pragma unroll
        for (int chunk = 0; chunk < 2; ++chunk){
            short8 a = *(const short8*)(arow + chunk*32);
            const bf16* bb = Bcr + (((size_t)(t*2+chunk))*2*64 + lane)*8;
            short8 b0 = *(const short8*)(bb);
            short8 b1 = *(const short8*)(bb + 64*8);
            acc0 = __builtin_amdgcn_mfma_f32_16x16x32_bf16(a, b0, acc0, 0, 0, 0);
            acc1 = __builtin_amdgcn_mfma_f32_16x16x32_bf16(a, b1, acc1, 0, 0, 0);
        }
    }
    const float* br = bias + r*18;
    #pragma unroll
    for (int r2 = 0; r2 < 4; ++r2){
        int x = x0 + q*4 + r2;
        pld[m][x] = acc0[r2] + br[m];                       // overlap x=40..47 writes identical values
        if (m < 2) pld[16+m][x] = acc1[r2] + br[16+m];
    }
    __syncthreads();
    // tap phase: 504 = 9 taps x 56 px
    for (int e = tid; e < 504; e += 256){
        int t = e / 56, x = e % 56;
        int ky = t / 3, kx = t % 3;
        float dy = pld[2*t][x];
        float dx = pld[2*t+1][x];
        float py = (float)(y - 1 + ky) + dy;
        float px = (float)(x - 1 + kx) + dx;
        float y0f = floorf(py), x0f = floorf(px);
        float wy1 = py - y0f, wx1 = px - x0f;
        float wy0 = 1.f - wy1, wx0 = 1.f - wx1;
        float vy0 = (y0f >= 0.f  && y0f <= 55.f) ? 1.f : 0.f;
        float vy1 = (y0f >= -1.f && y0f <= 54.f) ? 1.f : 0.f;
        float vx0 = (x0f >= 0.f  && x0f <= 55.f) ? 1.f : 0.f;
        float vx1 = (x0f >= -1.f && x0f <= 54.f) ? 1.f : 0.f;
        int yy0 = (int)y0f, x0i = (int)x0f;
        int iy0 = min(max(yy0,0),55),   iy1 = min(max(yy0+1,0),55);
        int ix0 = min(max(x0i,0),55),   ix1 = min(max(x0i+1,0),55);
        Tap td;
        td.o00 = ((iy0+1)*58 + ix0+1)*256;
        td.o01 = ((iy0+1)*58 + ix1+1)*256;
        td.o10 = ((iy1+1)*58 + ix0+1)*256;
        td.o11 = ((iy1+1)*58 + ix1+1)*256;
        td.w00 = wy0*wx0*vy0*vx0;
        td.w01 = wy0*wx1*vy0*vx1;
        td.w10 = wy1*wx0*vy1*vx0;
        td.w11 = wy1*wx1*vy1*vx1;
        size_t pid = ((size_t)(r*8 + b))*3136 + y*56 + x;
        tap[pid*9 + t] = td;
    }
}

// K4a: finish AKG pool from row partials: d[7][7] = (1/64)*sum_8gy rowsum; dwconv3x3 pad1 +
// relu; mean/49 -> s[(r*8+b)*256+c]. Grid 16 blocks (r*8+b), 256 thr (c).
__global__ __launch_bounds__(256) void k_akg_s(const float* __restrict__ rowsum, const float* __restrict__ dw,
                                               float* __restrict__ s){
    int rb = blockIdx.x; int r = rb >> 3;
    int c = threadIdx.x;
    const float* rs = rowsum + ((size_t)rb*56*7)*256 + c;
    float d[7][7];
    #pragma unroll
    for (int u = 0; u < 7; ++u)
        #pragma unroll
        for (int v = 0; v < 7; ++v){
            float acc = 0.f;
            #pragma unroll
            for (int k = 0; k < 8; ++k) acc += rs[(size_t)((u*8+k)*7 + v)*256];
            d[u][v] = acc * (1.f/64.f);
        }
    const float* wp = dw + (size_t)r*CC_*9 + c*9;
    float w[9];
    #pragma unroll
    for (int k = 0; k < 9; ++k) w[k] = wp[k];
    float tot = 0.f;
    #pragma unroll
    for (int u = 0; u < 7; ++u)
        #pragma unroll
        for (int v = 0; v < 7; ++v){
            float acc = 0.f;
            #pragma unroll
            for (int ky = 0; ky < 3; ++ky){
                int uu = u+ky-1; if ((unsigned)uu >= 7u) continue;
                #pragma unroll
                for (int kx = 0; kx < 3; ++kx){
                    int vv = v+kx-1; if ((unsigned)vv >= 7u) continue;
                    acc += d[uu][vv]*w[ky*3+kx];
                }
            }
            tot += fmaxf(acc, 0.f);
        }
    s[(size_t)rb*CC_ + c] = tot * (1.f/49.f);
}

// K4b: head matvec + tanh -> Kw (fp32) [r][b][t][c]. Grid 144.
__global__ void k_akg_head(const float* __restrict__ s, const float* __restrict__ hw,
                           const float* __restrict__ hb, float* __restrict__ Kw){
    int gid = blockIdx.x; int r = gid / 72; int id = gid % 72;
    int b = id / 9; int og = id % 9;
    __shared__ float sv[CC_];
    int tid = threadIdx.x; // 256
    sv[tid] = s[(size_t)(r*8+b)*CC_ + tid];
    __syncthreads();
    int o = og*256 + tid;              // o = c*9 + t
    const float* wp = hw + (size_t)r*2304*CC_ + (size_t)o*CC_;
    float acc = hb[(size_t)r*2304 + o];
    for (int c2=0;c2<CC_;++c2) acc += wp[c2]*sv[c2];
    int c = o / 9, t = o - 9*c;
    Kw[((size_t)r*BB + b)*2304 + t*256 + c] = tanhf(acc);
}

// K5: deformable depthwise (plateau version) — wave per pixel, scalar tap loads. Grid 12544.
__global__ __launch_bounds__(256) void k_deform(const bf16* __restrict__ Fp, const Tap* __restrict__ tap,
                                                const float* __restrict__ Kw, bf16* __restrict__ outsN){
    int bx = blockIdx.x; int b = bx & 7; int rest = bx >> 3;  // rest = creg*784 + pg
    int pg = rest % 784; int creg = rest / 784;
    int tid = threadIdx.x; int w = tid >> 6, l = tid & 63;
    int wu = __builtin_amdgcn_readfirstlane(w);
    int yx = pg*4 + wu;
    size_t pid = ((size_t)(creg*8 + b))*3136 + yx;
    const Tap* td = tap + pid*9;
    const bf16* Fb = Fp + (size_t)creg*FPR + (size_t)b*58*58*256;
    const float* Kb = Kw + ((size_t)creg*8 + b)*2304;
    int cl = 4*l;
    float acc[4] = {0.f, 0.f, 0.f, 0.f};
    #pragma unroll
    for (int t = 0; t < 9; ++t){
        Tap d = td[t];
        short4_t f00 = *(const short4_t*)(Fb + d.o00 + cl);
        short4_t f01 = *(const short4_t*)(Fb + d.o01 + cl);
        short4_t f10 = *(const short4_t*)(Fb + d.o10 + cl);
        short4_t f11 = *(const short4_t*)(Fb + d.o11 + cl);
        f32x4 kt = *(const f32x4*)(Kb + t*256 + cl);
        #pragma unroll
        for (int j = 0; j < 4; ++j){
            float v = d.w00*bs2f(f00[j]) + d.w01*bs2f(f01[j]) + d.w10*bs2f(f10[j]) + d.w11*bs2f(f11[j]);
            acc[j] += kt[j]*v;
        }
    }
    __attribute__((aligned(8))) bf16 tmp[4];
    #pragma unroll
    for (int j = 0; j < 4; ++j) tmp[j] = f2b(acc[j]);
    *(short4_t*)(outsN + ((size_t)b*HWSZ + yx)*512 + creg*256 + cl) = *(const short4_t*)tmp;
}

// K6a: pw2 MFMA GEMM, 2 pixel-tiles per wave, stats via LDS reduce + atomics, O store. Grid 392.
__global__ __launch_bounds__(256) void k_pw2_mstats(const bf16* __restrict__ outsN, const bf16* __restrict__ Bpw,
                                                    const float* __restrict__ bias, float* __restrict__ stats,
                                                    float* __restrict__ O){
    __shared__ float ls[2][2][256];
    int tid = threadIdx.x; int wave = tid>>6, lane = tid&63;
    int pixGroup = wave>>1, ntH = wave&1;
    int m = lane&15, q = lane>>4;
    size_t pb = (size_t)blockIdx.x*64 + pixGroup*32;
    const bf16* Ap0 = outsN + (pb + m)*512 + q*8;
    const bf16* Ap1 = Ap0 + (size_t)16*512;
    f32x4 acc[2][8];
    #pragma unroll
    for (int g=0;g<2;++g)
        #pragma unroll
        for (int i=0;i<8;++i) acc[g][i] = (f32x4){0,0,0,0};
    #pragma unroll 1
    for (int kk = 0; kk < 16; ++kk){
        short8 a0 = *(const short8*)(Ap0 + kk*32);
        short8 a1 = *(const short8*)(Ap1 + kk*32);
        const bf16* Bk = Bpw + (((size_t)kk*16 + ntH*8)*64 + lane)*8;
        #pragma unroll
        for (int nt2 = 0; nt2 < 8; ++nt2){
            short8 b = *(const short8*)(Bk + (size_t)nt2*64*8);
            acc[0][nt2] = __builtin_amdgcn_mfma_f32_16x16x32_bf16(a0, b, acc[0][nt2], 0, 0, 0);
            acc[1][nt2] = __builtin_amdgcn_mfma_f32_16x16x32_bf16(a1, b, acc[1][nt2], 0, 0, 0);
        }
    }
    #pragma unroll
    for (int nt2 = 0; nt2 < 8; ++nt2){
        int oc = ntH*128 + nt2*16 + m;
        float bv = bias[oc];
        float s1 = 0.f, s2 = 0.f;
        #pragma unroll
        for (int g = 0; g < 2; ++g){
            size_t pbg = pb + g*16;
            int b_idx = (int)(pbg / HWSZ);
            int yx0 = (int)(pbg % HWSZ);
            float* op = O + ((size_t)b_idx*CC_ + oc)*HWSZ + yx0 + q*4;
            #pragma unroll
            for (int r = 0; r < 4; ++r){
                float v = acc[g][nt2][r] + bv;
                op[r] = v;
                s1 += v; s2 += v*v;
            }
        }
        s1 += __shfl_down(s1, 32); s1 += __shfl_down(s1, 16);
        s2 += __shfl_down(s2, 32); s2 += __shfl_down(s2, 16);
        if (q == 0){ ls[pixGroup][0][oc] = s1; ls[pixGroup][1][oc] = s2; }
    }
    __syncthreads();
    if (tid < 256){
        atomicAdd(&stats[tid],       ls[0][0][tid] + ls[1][0][tid]);
        atomicAdd(&stats[256 + tid], ls[0][1][tid] + ls[1][1][tid]);
    }
}

// K6b: BN finalize (inline) + apply (elementwise, float4). Grid 6272.
__global__ __launch_bounds__(256) void k_bnapply(const float* __restrict__ O, const float* __restrict__ stats,
                                                 const float* __restrict__ gamma, const float* __restrict__ beta,
                                                 float* __restrict__ out){
    int n = (blockIdx.x*256 + threadIdx.x)*4;   // HWSZ divisible by 4 -> same channel
    int c = (n / HWSZ) % CC_;
    float ninv = 1.f/(float)NPIX;
    float mean = stats[c]*ninv;
    float var = fmaxf(stats[256+c]*ninv - mean*mean, 0.f);
    float rsq = rsqrtf(var + 1e-5f);
    float g = gamma[c], be = beta[c];
    f32x4 v = *(const f32x4*)(O + n);
    f32x4 o;
    #pragma unroll
    for (int j = 0; j < 4; ++j) o[j] = (v[j] - mean)*rsq*g + be;
    *(f32x4*)(out + n) = o;
}

extern "C" void kernel_launch(void* const* d_in, const int* in_sizes, int n_in,
                              void* d_out, int out_size, void* d_ws, size_t ws_size,
                              hipStream_t stream) {
    (void)in_sizes; (void)n_in; (void)out_size; (void)ws_size;
    const float* F_c    = (const float*)d_in[0];
    const float* dec_w  = (const float*)d_in[1];
    const float* dec_b  = (const float*)d_in[2];
    const float* off1_w = (const float*)d_in[3];
    const float* off1_b = (const float*)d_in[4];
    const float* off2_w = (const float*)d_in[5];
    const float* off2_b = (const float*)d_in[6];
    const float* akg_dw = (const float*)d_in[7];
    const float* akg_hw = (const float*)d_in[8];
    const float* akg_hb = (const float*)d_in[9];
    const float* pw2_w  = (const float*)d_in[10];
    const float* pw2_b  = (const float*)d_in[11];
    const float* gamma  = (const float*)d_in[12];
    const float* beta   = (const float*)d_in[13];
    float* out = (float*)d_out;

    char* ws = (char*)d_ws;
    size_t off = 0;
    auto alloc = [&](size_t bytes)->char*{
        char* r = ws + off;
        off = (off + bytes + 255) & ~(size_t)255;
        return r;
    };
    // Workspace ~85 MB.
    bf16*  Fp    = (bf16*) alloc(2*FPR*2);                 // padded NHWC F*sc, both regions
    bf16*  Bp    = (bf16*) alloc((size_t)2*9*8*4*64*8*2);  // conv1 weight frags
    bf16*  Bpw   = (bf16*) alloc((size_t)16*16*64*8*2);    // pw2 weight frags
    bf16*  Bc    = (bf16*) alloc((size_t)2*18*2*64*8*2);   // conv2 weight frags
    float* rowsum= (float*)alloc((size_t)2*8*56*7*256*4);  // AKG pool row partials
    bf16*  hp    = (bf16*) alloc(2*HPR*2);                 // padded NHWC hidden, both regions
    float* s     = (float*)alloc((size_t)2*BB*CC_*4);
    float* Kw    = (float*)alloc((size_t)2*BB*CC_*9*4);
    bf16*  outsN = (bf16*) alloc(NPIX*512*2);              // NHWC, k = creg*256+c
    Tap*   tap   = (Tap*)  alloc((size_t)2*NPIX*9*sizeof(Tap));
    float* stats = (float*)alloc(2*CC_*4);
    // O (fp32, 25.7MB) aliases Fp (27.6MB): Fp is dead after k_deform, O written in k_pw2_mstats.
    float* O = (float*)Fp;

    hipMemsetAsync(stats, 0, 2*CC_*sizeof(float), stream);

    k_scalepack<<<dim3(BB*HH), dim3(256), 0, stream>>>(F_c, dec_w, dec_b, Fp, rowsum);
    k_bprep_all<<<dim3(904), dim3(64), 0, stream>>>(off1_w, pw2_w, off2_w, Bp, Bpw, Bc);

    k_conv1<<<dim3(2*BB*28), dim3(256), 0, stream>>>(Fp, Bp, off1_b, hp);
    k_conv2m<<<dim3(2*BB*HH), dim3(256), 0, stream>>>(hp, Bc, off2_b, tap);
    k_akg_s<<<dim3(16), dim3(256), 0, stream>>>(rowsum, akg_dw, s);
    k_akg_head<<<dim3(2*BB*9), dim3(256), 0, stream>>>(s, akg_hw, akg_hb, Kw);
    k_deform<<<dim3(2*BB*784), dim3(256), 0, stream>>>(Fp, tap, Kw, outsN);

    k_pw2_mstats<<<dim3(392), dim3(256), 0, stream>>>(outsN, Bpw, pw2_b, stats, O);
    k_bnapply<<<dim3((int)(NPIX*CC_/1024)), dim3(256), 0, stream>>>(O, stats, gamma, beta, out);
}